// Round 1
// 519.305 us; speedup vs baseline: 1.0871x; 1.0871x over previous
//
#include <hip/hip_runtime.h>
#include <hip/hip_bf16.h>
#include <math.h>

#define S 2048
#define D 1024
#define NH 16
#define NKV 4
#define HD 64
#define QKV_N 1536          // (NH + 2*NKV) * HD
#define NE 8
#define NI 1024
#define EPS 1e-6f

typedef __bf16 bf16_t;
typedef __bf16 __attribute__((may_alias)) abf16;
typedef __attribute__((ext_vector_type(8))) __bf16 bf16x8;
typedef __attribute__((ext_vector_type(4))) float f32x4;
union I4B8 { int4 i; bf16x8 v; bf16_t e[8]; };

// ---------------------------------------------------------------- rmsnorm(D)
__global__ void rmsnorm_kernel(const float* __restrict__ in, const float* __restrict__ w,
                               float* __restrict__ out32, __hip_bfloat16* __restrict__ out16) {
  int t = blockIdx.x;
  int tid = threadIdx.x;
  const float* row = in + (size_t)t * D;
  float v[4];
  float ss = 0.f;
#pragma unroll
  for (int i = 0; i < 4; ++i) {
    v[i] = row[tid + i * 256];
    ss += v[i] * v[i];
  }
#pragma unroll
  for (int off = 32; off; off >>= 1) ss += __shfl_xor(ss, off);
  __shared__ float wsum[4];
  int wave = tid >> 6;
  if ((tid & 63) == 0) wsum[wave] = ss;
  __syncthreads();
  float tot = wsum[0] + wsum[1] + wsum[2] + wsum[3];
  float r = rsqrtf(tot / (float)D + EPS);
#pragma unroll
  for (int i = 0; i < 4; ++i) {
    int d = tid + i * 256;
    float val = v[i] * r * w[d];
    if (out32) out32[(size_t)t * D + d] = val;
    if (out16) out16[(size_t)t * D + d] = __float2bfloat16(val);
  }
}

// ------------------------------------------- weight transpose + bf16 cast
__global__ void transpose_cast_kernel(const float* __restrict__ W,
                                      __hip_bfloat16* __restrict__ WT, int Kd, int Nd) {
  __shared__ float tile[32][33];
  int e = blockIdx.z;
  const float* Wp = W + (size_t)e * Kd * Nd;
  __hip_bfloat16* WTp = WT + (size_t)e * Kd * Nd;
  int n0 = blockIdx.x * 32, k0 = blockIdx.y * 32;
  int tx = threadIdx.x & 31, ty = threadIdx.x >> 5;
#pragma unroll
  for (int i = 0; i < 4; ++i)
    tile[ty + i * 8][tx] = Wp[(size_t)(k0 + ty + i * 8) * Nd + n0 + tx];
  __syncthreads();
#pragma unroll
  for (int i = 0; i < 4; ++i)
    WTp[(size_t)(n0 + ty + i * 8) * Kd + k0 + tx] = __float2bfloat16(tile[tx][ty + i * 8]);
}

// ------------------------------------------- V transpose (fp32 qkv slice -> bf16 vT[256][2048])
__global__ void v_transpose_kernel(const float* __restrict__ qkv, __hip_bfloat16* __restrict__ vT) {
  __shared__ float tile[32][33];
  int t0 = blockIdx.x * 32;            // token
  int c0 = blockIdx.y * 32;            // v channel (0..255)
  int tx = threadIdx.x & 31, ty = threadIdx.x >> 5;
#pragma unroll
  for (int i = 0; i < 4; ++i)
    tile[ty + i * 8][tx] = qkv[(size_t)(t0 + ty + i * 8) * QKV_N + (NH + NKV) * HD + c0 + tx];
  __syncthreads();
#pragma unroll
  for (int i = 0; i < 4; ++i)
    vT[(size_t)(c0 + ty + i * 8) * S + t0 + tx] = __float2bfloat16(tile[tx][ty + i * 8]);
}

// ------------------------------------------- MFMA bf16 GEMM, 64x128 tile
__global__ __launch_bounds__(256) void mgemm_kernel(
    const __hip_bfloat16* __restrict__ A, const __hip_bfloat16* __restrict__ BT,
    const float* __restrict__ Cadd, float* __restrict__ C,
    int M, int N, int K,
    const int* __restrict__ counts, const int* __restrict__ offsets,
    const int* __restrict__ tok, int a_comp,
    const __hip_bfloat16* __restrict__ As2, const __hip_bfloat16* __restrict__ BTs2,
    float* __restrict__ Cs2) {
  __shared__ int AsI[64 * 20];
  __shared__ int BsI[128 * 20];
  __shared__ int rowmap[64];
  int e = blockIdx.z;
  bool sh = (counts != nullptr) && (e == NE);
  int cnt = sh ? M : (counts ? counts[e] : M);
  int bm = blockIdx.y * 64;
  if (bm >= cnt) return;
  int bn = blockIdx.x * 128;
  int obase = sh ? 0 : (offsets ? offsets[e] : 0);
  const bf16_t* Ab = sh ? (const bf16_t*)As2 : (const bf16_t*)A;
  const bf16_t* BTe = sh ? (const bf16_t*)BTs2 : ((const bf16_t*)BT + (size_t)e * N * K);
  float* Cp = sh ? Cs2 : C;
  const int* toke = (!sh && tok) ? tok + e * S : nullptr;
  int acompe = sh ? 0 : a_comp;
  int tid = threadIdx.x;
  if (tid < 64) {
    int gp = bm + tid;
    int cp = gp < cnt ? gp : cnt - 1;
    rowmap[tid] = toke ? toke[cp] : (acompe ? obase + cp : cp);
  }
  __syncthreads();
  int wave = tid >> 6, lane = tid & 63;
  int quad = lane >> 4, l16 = lane & 15;
  int wm = wave >> 1, wn = wave & 1;
  int pA = tid >> 2, qA = tid & 3;
  int pB = tid >> 1, hf = tid & 1;
  f32x4 acc[2][4];
#pragma unroll
  for (int i = 0; i < 2; ++i)
#pragma unroll
    for (int j = 0; j < 4; ++j) acc[i][j] = (f32x4){0.f, 0.f, 0.f, 0.f};
  for (int k0 = 0; k0 < K; k0 += 32) {
    int4 a0 = *(const int4*)(Ab + (size_t)rowmap[pA] * K + k0 + qA * 8);
    const int4* gb = (const int4*)(BTe + (size_t)(bn + pB) * K + k0 + hf * 16);
    int4 b0 = gb[0], b1 = gb[1];
    *(int4*)&AsI[pA * 20 + qA * 4] = a0;
    *(int4*)&BsI[pB * 20 + hf * 8] = b0;
    *(int4*)&BsI[pB * 20 + hf * 8 + 4] = b1;
    __syncthreads();
    I4B8 af[2], bfr[4];
#pragma unroll
    for (int s = 0; s < 2; ++s)
      af[s].i = *(const int4*)&AsI[(wm * 32 + s * 16 + l16) * 20 + quad * 4];
#pragma unroll
    for (int s = 0; s < 4; ++s)
      bfr[s].i = *(const int4*)&BsI[(wn * 64 + s * 16 + l16) * 20 + quad * 4];
#pragma unroll
    for (int i = 0; i < 2; ++i)
#pragma unroll
      for (int j = 0; j < 4; ++j)
        acc[i][j] = __builtin_amdgcn_mfma_f32_16x16x32_bf16(af[i].v, bfr[j].v, acc[i][j], 0, 0, 0);
    __syncthreads();
  }
#pragma unroll
  for (int i = 0; i < 2; ++i) {
#pragma unroll
    for (int r = 0; r < 4; ++r) {
      int trow = wm * 32 + i * 16 + quad * 4 + r;
      int gp = bm + trow;
      if (gp < cnt) {
        size_t rowb = (size_t)(obase + gp) * N;
#pragma unroll
        for (int j = 0; j < 4; ++j) {
          int col = bn + wn * 64 + j * 16 + l16;
          size_t idx = rowb + col;
          Cp[idx] = acc[i][j][r] + (Cadd ? Cadd[idx] : 0.f);
        }
      }
    }
  }
}

// ------------------------------------------- dual-B MFMA GEMM + silu, 64x128 tile
__global__ __launch_bounds__(256) void mgemm_gu_kernel(
    const __hip_bfloat16* __restrict__ A, const __hip_bfloat16* __restrict__ BTg,
    const __hip_bfloat16* __restrict__ BTu, __hip_bfloat16* __restrict__ act,
    int M, int N, int K,
    const int* __restrict__ counts, const int* __restrict__ offsets,
    const int* __restrict__ tok,
    const __hip_bfloat16* __restrict__ BTgs, const __hip_bfloat16* __restrict__ BTus,
    __hip_bfloat16* __restrict__ acts) {
  __shared__ int AsI[64 * 20];
  __shared__ int BgI[128 * 20];
  __shared__ int BuI[128 * 20];
  __shared__ int rowmap[64];
  int e = blockIdx.z;
  bool sh = (counts != nullptr) && (e == NE);
  int cnt = sh ? M : (counts ? counts[e] : M);
  int bm = blockIdx.y * 64;
  if (bm >= cnt) return;
  int bn = blockIdx.x * 128;
  int obase = sh ? 0 : (offsets ? offsets[e] : 0);
  const bf16_t* Ab = (const bf16_t*)A;
  const bf16_t* Bg = sh ? (const bf16_t*)BTgs : ((const bf16_t*)BTg + (size_t)e * N * K);
  const bf16_t* Bu = sh ? (const bf16_t*)BTus : ((const bf16_t*)BTu + (size_t)e * N * K);
  bf16_t* outp = sh ? (bf16_t*)acts : (bf16_t*)act;
  const int* toke = (!sh && tok) ? tok + e * S : nullptr;
  int tid = threadIdx.x;
  if (tid < 64) {
    int gp = bm + tid;
    int cp = gp < cnt ? gp : cnt - 1;
    rowmap[tid] = toke ? toke[cp] : cp;
  }
  __syncthreads();
  int wave = tid >> 6, lane = tid & 63;
  int quad = lane >> 4, l16 = lane & 15;
  int wm = wave >> 1, wn = wave & 1;
  int pA = tid >> 2, qA = tid & 3;
  int pB = tid >> 1, hf = tid & 1;
  f32x4 accg[2][4], accu[2][4];
#pragma unroll
  for (int i = 0; i < 2; ++i)
#pragma unroll
    for (int j = 0; j < 4; ++j) {
      accg[i][j] = (f32x4){0.f, 0.f, 0.f, 0.f};
      accu[i][j] = (f32x4){0.f, 0.f, 0.f, 0.f};
    }
  for (int k0 = 0; k0 < K; k0 += 32) {
    int4 a0 = *(const int4*)(Ab + (size_t)rowmap[pA] * K + k0 + qA * 8);
    const int4* gg = (const int4*)(Bg + (size_t)(bn + pB) * K + k0 + hf * 16);
    int4 g0 = gg[0], g1 = gg[1];
    const int4* gu = (const int4*)(Bu + (size_t)(bn + pB) * K + k0 + hf * 16);
    int4 u0 = gu[0], u1 = gu[1];
    *(int4*)&AsI[pA * 20 + qA * 4] = a0;
    *(int4*)&BgI[pB * 20 + hf * 8] = g0;
    *(int4*)&BgI[pB * 20 + hf * 8 + 4] = g1;
    *(int4*)&BuI[pB * 20 + hf * 8] = u0;
    *(int4*)&BuI[pB * 20 + hf * 8 + 4] = u1;
    __syncthreads();
    I4B8 af[2], bg[4], bu[4];
#pragma unroll
    for (int s = 0; s < 2; ++s)
      af[s].i = *(const int4*)&AsI[(wm * 32 + s * 16 + l16) * 20 + quad * 4];
#pragma unroll
    for (int s = 0; s < 4; ++s) {
      bg[s].i = *(const int4*)&BgI[(wn * 64 + s * 16 + l16) * 20 + quad * 4];
      bu[s].i = *(const int4*)&BuI[(wn * 64 + s * 16 + l16) * 20 + quad * 4];
    }
#pragma unroll
    for (int i = 0; i < 2; ++i)
#pragma unroll
      for (int j = 0; j < 4; ++j) {
        accg[i][j] = __builtin_amdgcn_mfma_f32_16x16x32_bf16(af[i].v, bg[j].v, accg[i][j], 0, 0, 0);
        accu[i][j] = __builtin_amdgcn_mfma_f32_16x16x32_bf16(af[i].v, bu[j].v, accu[i][j], 0, 0, 0);
      }
    __syncthreads();
  }
#pragma unroll
  for (int i = 0; i < 2; ++i) {
#pragma unroll
    for (int r = 0; r < 4; ++r) {
      int trow = wm * 32 + i * 16 + quad * 4 + r;
      int gp = bm + trow;
      if (gp < cnt) {
        size_t rowb = (size_t)(obase + gp) * N;
#pragma unroll
        for (int j = 0; j < 4; ++j) {
          int col = bn + wn * 64 + j * 16 + l16;
          float g = accg[i][j][r], uu = accu[i][j][r];
          float sg = g / (1.f + __expf(-g));
          outp[rowb + col] = __float2bfloat16(sg * uu);
        }
      }
    }
  }
}

// --------------------------------------------- q/k head rmsnorm + RoPE + bf16 cast
__global__ void qkv_post_kernel(const float* __restrict__ qkv,
                                const float* __restrict__ qw, const float* __restrict__ kw,
                                const float* __restrict__ cosb, const float* __restrict__ sinb,
                                __hip_bfloat16* __restrict__ qout,
                                __hip_bfloat16* __restrict__ kout,
                                __hip_bfloat16* __restrict__ vout) {
  int t = blockIdx.x;
  int u = blockIdx.y * 4 + (threadIdx.x >> 6);
  int lane = threadIdx.x & 63;
  if (u >= NH + NKV) {                       // v: plain cast (unused when grid.y==5)
    int h = u - NH - NKV;
    float xv = qkv[(size_t)t * QKV_N + (NH + NKV) * HD + h * HD + lane];
    vout[(size_t)t * (NKV * HD) + h * HD + lane] = __float2bfloat16(xv);
    return;
  }
  bool isq = (u < NH);
  int h = isq ? u : (u - NH);
  size_t src = (size_t)t * QKV_N + (isq ? (h * HD) : (NH * HD + h * HD)) + lane;
  float xv = qkv[src];
  float ss = xv * xv;
#pragma unroll
  for (int off = 32; off; off >>= 1) ss += __shfl_xor(ss, off);
  float r = rsqrtf(ss * (1.f / 64.f) + EPS);
  float xn = xv * r * (isq ? qw[lane] : kw[lane]);
  float other = __shfl_xor(xn, 32);
  float rot = (lane < 32) ? -other : other;
  float res = xn * cosb[t * 64 + lane] + rot * sinb[t * 64 + lane];
  if (isq) qout[(size_t)t * (NH * HD) + h * HD + lane] = __float2bfloat16(res * 0.125f);
  else     kout[(size_t)t * (NKV * HD) + h * HD + lane] = __float2bfloat16(res);
}

// --------------------------------------------- MFMA flash attention v3
// GQA-merged: block = (16-row q-tile, kv head); 4 waves = 4 q-heads sharing K/V.
// KVBLK=64 with -1e30 masking of the trailing half tile (block-causal at 32).
// V is pre-transposed globally (vT[256][2048]) so PV B-frags are ds_read_b128.
__global__ __launch_bounds__(256) void attn_kernel(
    const __hip_bfloat16* __restrict__ qg, const __hip_bfloat16* __restrict__ kg,
    const __hip_bfloat16* __restrict__ vT, __hip_bfloat16* __restrict__ attn) {
  int qt = (int)(gridDim.x - 1) - (int)blockIdx.x;   // heavy tiles first
  int kvh = blockIdx.y;
  int tid = threadIdx.x;
  int wave = tid >> 6, lane = tid & 63;
  int quad = lane >> 4, l16 = lane & 15;
  int h = kvh * 4 + wave;

  __shared__ __align__(16) int KsI[64 * 36];         // K tile [64 k][64 d + pad]
  __shared__ __align__(16) int VTI[64 * 36];         // V^T tile [64 d][64 k + pad]
  __shared__ __align__(16) int PsI[4][16 * 36];      // per-wave P [16 q][64 k + pad]

  // Q fragments direct from global: row qt*16+l16, d = ch*32 + quad*8 + j
  I4B8 qf[2];
#pragma unroll
  for (int ch = 0; ch < 2; ++ch)
    qf[ch].i = *(const int4*)((const abf16*)qg +
        (size_t)(qt * 16 + l16) * (NH * HD) + h * HD + ch * 32 + quad * 8);

  int nb = (qt >> 1) + 1;            // valid 32-blocks of kv
  int nt = (nb + 1) >> 1;            // 64-wide tiles
  bool half = (nb & 1) != 0;         // last tile only 32 valid

  float m_r[4], l_r[4];
  f32x4 o[4];
#pragma unroll
  for (int r = 0; r < 4; ++r) { m_r[r] = -1e30f; l_r[r] = 0.f; }
#pragma unroll
  for (int sub = 0; sub < 4; ++sub) o[sub] = (f32x4){0.f, 0.f, 0.f, 0.f};

  int sp = tid >> 3, sc = tid & 7;   // staging: 32 rows x 8 octets (x2 halves)

  for (int kc = 0; kc < nt; ++kc) {
    // ---- stage K tile and V^T tile (all vectorized)
    {
      const abf16* kb = (const abf16*)kg;
      int4 k0 = *(const int4*)(kb + (size_t)(kc * 64 + sp) * (NKV * HD) + kvh * HD + sc * 8);
      int4 k1 = *(const int4*)(kb + (size_t)(kc * 64 + 32 + sp) * (NKV * HD) + kvh * HD + sc * 8);
      const abf16* vb = (const abf16*)vT;
      int4 v0 = *(const int4*)(vb + (size_t)(kvh * HD + sp) * S + kc * 64 + sc * 8);
      int4 v1 = *(const int4*)(vb + (size_t)(kvh * HD + 32 + sp) * S + kc * 64 + sc * 8);
      *(int4*)&KsI[sp * 36 + sc * 4] = k0;
      *(int4*)&KsI[(sp + 32) * 36 + sc * 4] = k1;
      *(int4*)&VTI[sp * 36 + sc * 4] = v0;
      *(int4*)&VTI[(sp + 32) * 36 + sc * 4] = v1;
    }
    __syncthreads();

    // ---- QK^T: 16 q-rows x 64 k
    f32x4 s[4];
#pragma unroll
    for (int sub = 0; sub < 4; ++sub) s[sub] = (f32x4){0.f, 0.f, 0.f, 0.f};
#pragma unroll
    for (int sub = 0; sub < 4; ++sub)
#pragma unroll
      for (int ch = 0; ch < 2; ++ch) {
        I4B8 ku;
        ku.i = *(const int4*)&KsI[(sub * 16 + l16) * 36 + ch * 16 + quad * 4];
        s[sub] = __builtin_amdgcn_mfma_f32_16x16x32_bf16(qf[ch].v, ku.v, s[sub], 0, 0, 0);
      }
    if (half && kc == nt - 1) {
#pragma unroll
      for (int r = 0; r < 4; ++r) { s[2][r] = -1e30f; s[3][r] = -1e30f; }
    }

    // ---- online softmax (rows quad*4+r, reduce over 16 lanes = 64 k via 4 subs)
    abf16* pw = (abf16*)PsI[wave];
#pragma unroll
    for (int r = 0; r < 4; ++r) {
      float v = fmaxf(fmaxf(s[0][r], s[1][r]), fmaxf(s[2][r], s[3][r]));
#pragma unroll
      for (int off = 1; off < 16; off <<= 1) v = fmaxf(v, __shfl_xor(v, off));
      float mx = fmaxf(m_r[r], v);
      float al = __expf(m_r[r] - mx);
      m_r[r] = mx;
      float p0 = __expf(s[0][r] - mx);
      float p1 = __expf(s[1][r] - mx);
      float p2 = __expf(s[2][r] - mx);
      float p3 = __expf(s[3][r] - mx);
      float su = (p0 + p1) + (p2 + p3);
#pragma unroll
      for (int off = 1; off < 16; off <<= 1) su += __shfl_xor(su, off);
      l_r[r] = l_r[r] * al + su;
      int prow = quad * 4 + r;
      pw[prow * 72 + l16]      = (bf16_t)p0;
      pw[prow * 72 + 16 + l16] = (bf16_t)p1;
      pw[prow * 72 + 32 + l16] = (bf16_t)p2;
      pw[prow * 72 + 48 + l16] = (bf16_t)p3;
#pragma unroll
      for (int sub = 0; sub < 4; ++sub) o[sub][r] *= al;
    }

    // ---- PV: P(16x64) x V(64x64); per-wave P, vectorized V^T frags
    I4B8 pu[2];
#pragma unroll
    for (int ch = 0; ch < 2; ++ch)
      pu[ch].i = *(const int4*)&PsI[wave][l16 * 36 + ch * 16 + quad * 4];
#pragma unroll
    for (int sub = 0; sub < 4; ++sub)
#pragma unroll
      for (int ch = 0; ch < 2; ++ch) {
        I4B8 vf;
        vf.i = *(const int4*)&VTI[(sub * 16 + l16) * 36 + ch * 16 + quad * 4];
        o[sub] = __builtin_amdgcn_mfma_f32_16x16x32_bf16(pu[ch].v, vf.v, o[sub], 0, 0, 0);
      }
    __syncthreads();
  }

#pragma unroll
  for (int r = 0; r < 4; ++r) {
    float inv = 1.f / l_r[r];
    int row = qt * 16 + quad * 4 + r;
#pragma unroll
    for (int sub = 0; sub < 4; ++sub)
      attn[(size_t)row * (NH * HD) + h * HD + sub * 16 + l16] =
          __float2bfloat16(o[sub][r] * inv);
  }
}

// ---------------------------------------------------------------- router
__global__ void zero_counts_kernel(int* counts) {
  if (threadIdx.x < NE) counts[threadIdx.x] = 0;
}

__global__ void router_kernel(const float* __restrict__ h2, const float* __restrict__ rw,
                              int* counts, int* tok_list, int* topk_e, int* topk_pos,
                              float* topk_w) {
  int t = blockIdx.x;
  int lane = threadIdx.x;   // 64
  float p[NE] = {};
  for (int d = lane; d < D; d += 64) {
    float hv = h2[(size_t)t * D + d];
#pragma unroll
    for (int e = 0; e < NE; ++e) p[e] += hv * rw[d * NE + e];
  }
#pragma unroll
  for (int off = 32; off; off >>= 1)
#pragma unroll
    for (int e = 0; e < NE; ++e) p[e] += __shfl_xor(p[e], off);
  if (lane == 0) {
    float mx = p[0];
#pragma unroll
    for (int e = 1; e < NE; ++e) mx = fmaxf(mx, p[e]);
    float ex[NE];
#pragma unroll
    for (int e = 0; e < NE; ++e) ex[e] = __expf(p[e] - mx);
    int e0 = 0;
#pragma unroll
    for (int e = 1; e < NE; ++e) if (ex[e] > ex[e0]) e0 = e;
    int e1 = (e0 == 0) ? 1 : 0;
#pragma unroll
    for (int e = 0; e < NE; ++e) if (e != e0 && ex[e] > ex[e1]) e1 = e;
    float w0 = ex[e0] / (ex[e0] + ex[e1]);
    float w1 = ex[e1] / (ex[e0] + ex[e1]);
    int pos0 = atomicAdd(&counts[e0], 1);
    int pos1 = atomicAdd(&counts[e1], 1);
    tok_list[e0 * S + pos0] = t;
    tok_list[e1 * S + pos1] = t;
    topk_e[2 * t] = e0;  topk_e[2 * t + 1] = e1;
    topk_pos[2 * t] = pos0;  topk_pos[2 * t + 1] = pos1;
    topk_w[2 * t] = w0;  topk_w[2 * t + 1] = w1;
  }
}

__global__ void scan_kernel(const int* counts, int* offsets) {
  if (threadIdx.x == 0) {
    int acc = 0;
    for (int e = 0; e < NE; ++e) { offsets[e] = acc; acc += counts[e]; }
  }
}

// ---------------------------------------------------------------- final add
__global__ void final_kernel(const float* __restrict__ x, const float* __restrict__ sout,
                             const float* __restrict__ eo,
                             const int* __restrict__ topk_e, const int* __restrict__ topk_pos,
                             const float* __restrict__ topk_w, const int* __restrict__ offsets,
                             float* __restrict__ out) {
  int t = blockIdx.x;
  int tid = threadIdx.x;
  int e0 = topk_e[2 * t], e1 = topk_e[2 * t + 1];
  size_t r0 = (size_t)offsets[e0] + topk_pos[2 * t];
  size_t r1 = (size_t)offsets[e1] + topk_pos[2 * t + 1];
  float w0 = topk_w[2 * t], w1 = topk_w[2 * t + 1];
#pragma unroll
  for (int i = 0; i < 4; ++i) {
    int d = tid + i * 256;
    size_t idx = (size_t)t * D + d;
    out[idx] = x[idx] + sout[idx] + w0 * eo[r0 * D + d] + w1 * eo[r1 * D + d];
  }
}

extern "C" void kernel_launch(void* const* d_in, const int* in_sizes, int n_in,
                              void* d_out, int out_size, void* d_ws, size_t ws_size,
                              hipStream_t stream) {
  const float* hidden  = (const float*)d_in[0];
  const float* cosb    = (const float*)d_in[1];
  const float* sinb    = (const float*)d_in[2];
  const float* w_qkv   = (const float*)d_in[3];
  const float* w_o     = (const float*)d_in[4];
  const float* q_norm  = (const float*)d_in[5];
  const float* k_norm  = (const float*)d_in[6];
  const float* in_ln   = (const float*)d_in[7];
  const float* post_ln = (const float*)d_in[8];
  const float* router_w= (const float*)d_in[9];
  const float* w_gate  = (const float*)d_in[10];
  const float* w_up    = (const float*)d_in[11];
  const float* w_down  = (const float*)d_in[12];
  const float* ws_gate = (const float*)d_in[13];
  const float* ws_up   = (const float*)d_in[14];
  const float* ws_down = (const float*)d_in[15];
  float* out = (float*)d_out;
  float* ws = (float*)d_ws;

  typedef __hip_bfloat16 hbf;
  // weights (bf16)
  hbf* wqkvT = (hbf*)(ws);                      // 1.5M el
  hbf* woT   = (hbf*)(ws +  768 * 1024);        // 1M el
  hbf* wgT   = (hbf*)(ws + 1280 * 1024);        // 8M el
  hbf* wuT   = (hbf*)(ws + 5376 * 1024);        // 8M el
  hbf* wdT   = (hbf*)(ws + 9472 * 1024);        // 8M el
  hbf* wsgT  = (hbf*)(ws + 13568 * 1024);       // 1M el
  hbf* wsuT  = (hbf*)(ws + 14080 * 1024);       // 1M el
  hbf* wsdT  = (hbf*)(ws + 14592 * 1024);       // 1M el
  // activations
  hbf*   hb      = (hbf*)(ws + 15104 * 1024);   // [15104K,16128K)
  float* qkv     = ws + 16128 * 1024;           // [16128K,19200K)
  hbf*   qbB     = (hbf*)(ws + 19200 * 1024);   // [19200K,20224K)
  hbf*   kbB     = (hbf*)(ws + 20224 * 1024);   // [20224K,20480K)
  hbf*   vTb     = (hbf*)(ws + 20480 * 1024);   // [20480K,20736K)  V^T [256][2048]
  hbf*   attnb16 = (hbf*)(ws + 20736 * 1024);   // [20736K,21760K)
  float* x       = ws + 22784 * 1024;           // 2M fl
  float* h2      = ws + 24832 * 1024;           // 2M fl
  hbf*   h2b     = (hbf*)(ws + 26880 * 1024);   // [26880K,27904K)
  hbf*   act     = (hbf*)(ws + 16128 * 1024);   // 4096x1024 bf16, aliases dead qkv
  float* eo      = ws + 18176 * 1024;           // 4096x1024 fp32, aliases dead q/k/v/attnb16
  hbf*   sact    = (hbf*)(ws + 27904 * 1024);   // 2048x1024 bf16
  float* sout    = ws + 28928 * 1024;           // 2048x1024 fp32
  int* counts   = (int*)(ws + 30976 * 1024);
  int* offsets  = counts + NE;
  int* tok_list = offsets + NE;
  int* topk_e   = tok_list + NE * S;
  int* topk_pos = topk_e + 2 * S;
  float* topk_w = (float*)(topk_pos + 2 * S);

  dim3 b256(256);
  zero_counts_kernel<<<1, 64, 0, stream>>>(counts);
  transpose_cast_kernel<<<dim3(QKV_N/32, D/32, 1), b256, 0, stream>>>(w_qkv, wqkvT, D, QKV_N);
  transpose_cast_kernel<<<dim3(D/32, D/32, 1),     b256, 0, stream>>>(w_o, woT, D, D);
  transpose_cast_kernel<<<dim3(NI/32, D/32, NE),   b256, 0, stream>>>(w_gate, wgT, D, NI);
  transpose_cast_kernel<<<dim3(NI/32, D/32, NE),   b256, 0, stream>>>(w_up, wuT, D, NI);
  transpose_cast_kernel<<<dim3(D/32, NI/32, NE),   b256, 0, stream>>>(w_down, wdT, NI, D);
  transpose_cast_kernel<<<dim3(NI/32, D/32, 1),    b256, 0, stream>>>(ws_gate, wsgT, D, NI);
  transpose_cast_kernel<<<dim3(NI/32, D/32, 1),    b256, 0, stream>>>(ws_up, wsuT, D, NI);
  transpose_cast_kernel<<<dim3(D/32, NI/32, 1),    b256, 0, stream>>>(ws_down, wsdT, NI, D);
  // attention block
  rmsnorm_kernel<<<S, b256, 0, stream>>>(hidden, in_ln, nullptr, hb);
  mgemm_kernel<<<dim3(QKV_N/128, S/64, 1), b256, 0, stream>>>(hb, wqkvT, nullptr, qkv,
      S, QKV_N, D, nullptr, nullptr, nullptr, 0, nullptr, nullptr, nullptr);
  qkv_post_kernel<<<dim3(S, 5), b256, 0, stream>>>(qkv, q_norm, k_norm, cosb, sinb, qbB, kbB, nullptr);
  v_transpose_kernel<<<dim3(S/32, (NKV*HD)/32), b256, 0, stream>>>(qkv, vTb);
  attn_kernel<<<dim3(S/16, NKV), b256, 0, stream>>>(qbB, kbB, vTb, attnb16);
  mgemm_kernel<<<dim3(D/128, S/64, 1), b256, 0, stream>>>(attnb16, woT, hidden, x,
      S, D, D, nullptr, nullptr, nullptr, 0, nullptr, nullptr, nullptr);
  // MoE block (shared expert merged as z == NE)
  rmsnorm_kernel<<<S, b256, 0, stream>>>(x, post_ln, h2, h2b);
  router_kernel<<<S, 64, 0, stream>>>(h2, router_w, counts, tok_list, topk_e, topk_pos, topk_w);
  scan_kernel<<<1, 64, 0, stream>>>(counts, offsets);
  mgemm_gu_kernel<<<dim3(NI/128, S/64, NE + 1), b256, 0, stream>>>(h2b, wgT, wuT, act,
      S, NI, D, counts, offsets, tok_list, wsgT, wsuT, sact);
  mgemm_kernel<<<dim3(D/128, S/64, NE + 1), b256, 0, stream>>>(act, wdT, nullptr, eo,
      S, D, NI, counts, offsets, nullptr, 1, sact, wsdT, sout);
  final_kernel<<<S, b256, 0, stream>>>(x, sout, eo, topk_e, topk_pos, topk_w, offsets, out);
}

// Round 2
// 511.529 us; speedup vs baseline: 1.1037x; 1.0152x over previous
//
#include <hip/hip_runtime.h>
#include <hip/hip_bf16.h>
#include <math.h>

#define S 2048
#define D 1024
#define NH 16
#define NKV 4
#define HD 64
#define QKV_N 1536          // (NH + 2*NKV) * HD
#define NE 8
#define NI 1024
#define EPS 1e-6f

typedef __bf16 bf16_t;
typedef __bf16 __attribute__((may_alias)) abf16;
typedef __attribute__((ext_vector_type(8))) __bf16 bf16x8;
typedef __attribute__((ext_vector_type(4))) float f32x4;
union I4B8 { int4 i; bf16x8 v; bf16_t e[8]; };

// async global->LDS, 16B per lane. LDS dest must be wave-uniform base
// (HW adds lane*16); global src is per-lane.
__device__ __forceinline__ void gll16(const void* g, void* l) {
  __builtin_amdgcn_global_load_lds(
      (const __attribute__((address_space(1))) void*)g,
      (__attribute__((address_space(3))) void*)l, 16, 0, 0);
}

// ---------------------------------------------------------------- rmsnorm(D)
__global__ void rmsnorm_kernel(const float* __restrict__ in, const float* __restrict__ w,
                               float* __restrict__ out32, __hip_bfloat16* __restrict__ out16) {
  int t = blockIdx.x;
  int tid = threadIdx.x;
  const float* row = in + (size_t)t * D;
  float v[4];
  float ss = 0.f;
#pragma unroll
  for (int i = 0; i < 4; ++i) {
    v[i] = row[tid + i * 256];
    ss += v[i] * v[i];
  }
#pragma unroll
  for (int off = 32; off; off >>= 1) ss += __shfl_xor(ss, off);
  __shared__ float wsum[4];
  int wave = tid >> 6;
  if ((tid & 63) == 0) wsum[wave] = ss;
  __syncthreads();
  float tot = wsum[0] + wsum[1] + wsum[2] + wsum[3];
  float r = rsqrtf(tot / (float)D + EPS);
#pragma unroll
  for (int i = 0; i < 4; ++i) {
    int d = tid + i * 256;
    float val = v[i] * r * w[d];
    if (out32) out32[(size_t)t * D + d] = val;
    if (out16) out16[(size_t)t * D + d] = __float2bfloat16(val);
  }
}

// ------------------------------------------- weight transpose + bf16 cast
__global__ void transpose_cast_kernel(const float* __restrict__ W,
                                      __hip_bfloat16* __restrict__ WT, int Kd, int Nd) {
  __shared__ float tile[32][33];
  int e = blockIdx.z;
  const float* Wp = W + (size_t)e * Kd * Nd;
  __hip_bfloat16* WTp = WT + (size_t)e * Kd * Nd;
  int n0 = blockIdx.x * 32, k0 = blockIdx.y * 32;
  int tx = threadIdx.x & 31, ty = threadIdx.x >> 5;
#pragma unroll
  for (int i = 0; i < 4; ++i)
    tile[ty + i * 8][tx] = Wp[(size_t)(k0 + ty + i * 8) * Nd + n0 + tx];
  __syncthreads();
#pragma unroll
  for (int i = 0; i < 4; ++i)
    WTp[(size_t)(n0 + ty + i * 8) * Kd + k0 + tx] = __float2bfloat16(tile[tx][ty + i * 8]);
}

// ------------------------------------------- V transpose (fp32 qkv slice -> bf16 vT[256][2048])
__global__ void v_transpose_kernel(const float* __restrict__ qkv, __hip_bfloat16* __restrict__ vT) {
  __shared__ float tile[32][33];
  int t0 = blockIdx.x * 32;            // token
  int c0 = blockIdx.y * 32;            // v channel (0..255)
  int tx = threadIdx.x & 31, ty = threadIdx.x >> 5;
#pragma unroll
  for (int i = 0; i < 4; ++i)
    tile[ty + i * 8][tx] = qkv[(size_t)(t0 + ty + i * 8) * QKV_N + (NH + NKV) * HD + c0 + tx];
  __syncthreads();
#pragma unroll
  for (int i = 0; i < 4; ++i)
    vT[(size_t)(c0 + ty + i * 8) * S + t0 + tx] = __float2bfloat16(tile[tx][ty + i * 8]);
}

// ------------------------------------------- MFMA bf16 GEMM, 128x128 tile (m97 structure)
// 4 waves in 2x2 grid, each 64x64 (4x4 16x16 frags); BK=32; global_load_lds staging.
// Gather rows via rowmap (per-lane global src; linear LDS dest).
__global__ __launch_bounds__(256) void mgemm_kernel(
    const __hip_bfloat16* __restrict__ A, const __hip_bfloat16* __restrict__ BT,
    const float* __restrict__ Cadd, float* __restrict__ C,
    int M, int N, int K,
    const int* __restrict__ counts, const int* __restrict__ offsets,
    const int* __restrict__ tok, int a_comp,
    const __hip_bfloat16* __restrict__ As2, const __hip_bfloat16* __restrict__ BTs2,
    float* __restrict__ Cs2) {
  __shared__ __align__(16) bf16_t Asd[128 * 32];   // [row][k] linear, 8 KB
  __shared__ __align__(16) bf16_t Bsd[128 * 32];
  __shared__ int rowmap[128];
  int e = blockIdx.z;
  bool sh = (counts != nullptr) && (e == NE);
  int cnt = sh ? M : (counts ? counts[e] : M);
  int bm = blockIdx.y * 128;
  if (bm >= cnt) return;
  int bn = blockIdx.x * 128;
  int obase = sh ? 0 : (offsets ? offsets[e] : 0);
  const bf16_t* Ab = sh ? (const bf16_t*)As2 : (const bf16_t*)A;
  const bf16_t* BTe = sh ? (const bf16_t*)BTs2 : ((const bf16_t*)BT + (size_t)e * N * K);
  float* Cp = sh ? Cs2 : C;
  const int* toke = (!sh && tok) ? tok + e * S : nullptr;
  int acompe = sh ? 0 : a_comp;
  int tid = threadIdx.x;
  if (tid < 128) {
    int gp = bm + tid;
    int cp = gp < cnt ? gp : cnt - 1;
    rowmap[tid] = toke ? toke[cp] : (acompe ? obase + cp : cp);
  }
  __syncthreads();
  int wave = tid >> 6, lane = tid & 63;
  int quad = lane >> 4, l16 = lane & 15;
  int wm = wave >> 1, wn = wave & 1;
  // staging geometry: chunk c = tid covers LDS bytes [c*16, c*16+16) => row c>>2, col (c&3)*8
  int srow = tid >> 2, scol = (tid & 3) * 8;
  size_t aoff0 = (size_t)rowmap[srow] * K + scol;
  size_t aoff1 = (size_t)rowmap[64 + srow] * K + scol;
  size_t boff0 = (size_t)(bn + srow) * K + scol;
  size_t boff1 = (size_t)(bn + 64 + srow) * K + scol;
  char* AsB = (char*)Asd + wave * 1024;
  char* BsB = (char*)Bsd + wave * 1024;
  f32x4 acc[4][4];
#pragma unroll
  for (int i = 0; i < 4; ++i)
#pragma unroll
    for (int j = 0; j < 4; ++j) acc[i][j] = (f32x4){0.f, 0.f, 0.f, 0.f};
  for (int k0 = 0; k0 < K; k0 += 32) {
    gll16(Ab + aoff0 + k0, AsB);
    gll16(Ab + aoff1 + k0, AsB + 4096);
    gll16(BTe + boff0 + k0, BsB);
    gll16(BTe + boff1 + k0, BsB + 4096);
    __syncthreads();
    I4B8 af[4], bfr[4];
#pragma unroll
    for (int i = 0; i < 4; ++i)
      af[i].i = *(const int4*)(Asd + (wm * 64 + i * 16 + l16) * 32 + quad * 8);
#pragma unroll
    for (int j = 0; j < 4; ++j)
      bfr[j].i = *(const int4*)(Bsd + (wn * 64 + j * 16 + l16) * 32 + quad * 8);
#pragma unroll
    for (int i = 0; i < 4; ++i)
#pragma unroll
      for (int j = 0; j < 4; ++j)
        acc[i][j] = __builtin_amdgcn_mfma_f32_16x16x32_bf16(af[i].v, bfr[j].v, acc[i][j], 0, 0, 0);
    __syncthreads();
  }
#pragma unroll
  for (int i = 0; i < 4; ++i) {
#pragma unroll
    for (int r = 0; r < 4; ++r) {
      int trow = wm * 64 + i * 16 + quad * 4 + r;
      int gp = bm + trow;
      if (gp < cnt) {
        size_t rowb = (size_t)(obase + gp) * N;
#pragma unroll
        for (int j = 0; j < 4; ++j) {
          int col = bn + wn * 64 + j * 16 + l16;
          size_t idx = rowb + col;
          Cp[idx] = acc[i][j][r] + (Cadd ? Cadd[idx] : 0.f);
        }
      }
    }
  }
}

// ------------------------------------------- dual-B MFMA GEMM + silu, 128x64 tile
// 4 waves 2x2: each wave 64 M x 32 N per matrix (4x2 frags x2 matrices).
__global__ __launch_bounds__(256) void mgemm_gu_kernel(
    const __hip_bfloat16* __restrict__ A, const __hip_bfloat16* __restrict__ BTg,
    const __hip_bfloat16* __restrict__ BTu, __hip_bfloat16* __restrict__ act,
    int M, int N, int K,
    const int* __restrict__ counts, const int* __restrict__ offsets,
    const int* __restrict__ tok,
    const __hip_bfloat16* __restrict__ BTgs, const __hip_bfloat16* __restrict__ BTus,
    __hip_bfloat16* __restrict__ acts) {
  __shared__ __align__(16) bf16_t Asd[128 * 32];   // 8 KB
  __shared__ __align__(16) bf16_t Bgd[64 * 32];    // 4 KB
  __shared__ __align__(16) bf16_t Bud[64 * 32];    // 4 KB
  __shared__ int rowmap[128];
  int e = blockIdx.z;
  bool sh = (counts != nullptr) && (e == NE);
  int cnt = sh ? M : (counts ? counts[e] : M);
  int bm = blockIdx.y * 128;
  if (bm >= cnt) return;
  int bn = blockIdx.x * 64;
  const bf16_t* Ab = (const bf16_t*)A;
  const bf16_t* Bg = sh ? (const bf16_t*)BTgs : ((const bf16_t*)BTg + (size_t)e * N * K);
  const bf16_t* Bu = sh ? (const bf16_t*)BTus : ((const bf16_t*)BTu + (size_t)e * N * K);
  bf16_t* outp = sh ? (bf16_t*)acts : (bf16_t*)act;
  int obase = sh ? 0 : (offsets ? offsets[e] : 0);
  const int* toke = (!sh && tok) ? tok + e * S : nullptr;
  int tid = threadIdx.x;
  if (tid < 128) {
    int gp = bm + tid;
    int cp = gp < cnt ? gp : cnt - 1;
    rowmap[tid] = toke ? toke[cp] : cp;
  }
  __syncthreads();
  int wave = tid >> 6, lane = tid & 63;
  int quad = lane >> 4, l16 = lane & 15;
  int wm = wave >> 1, wn = wave & 1;
  int srow = tid >> 2, scol = (tid & 3) * 8;
  size_t aoff0 = (size_t)rowmap[srow] * K + scol;
  size_t aoff1 = (size_t)rowmap[64 + srow] * K + scol;
  size_t boff = (size_t)(bn + srow) * K + scol;
  char* AsB = (char*)Asd + wave * 1024;
  char* BgB = (char*)Bgd + wave * 1024;
  char* BuB = (char*)Bud + wave * 1024;
  f32x4 accg[4][2], accu[4][2];
#pragma unroll
  for (int i = 0; i < 4; ++i)
#pragma unroll
    for (int j = 0; j < 2; ++j) {
      accg[i][j] = (f32x4){0.f, 0.f, 0.f, 0.f};
      accu[i][j] = (f32x4){0.f, 0.f, 0.f, 0.f};
    }
  for (int k0 = 0; k0 < K; k0 += 32) {
    gll16(Ab + aoff0 + k0, AsB);
    gll16(Ab + aoff1 + k0, AsB + 4096);
    gll16(Bg + boff + k0, BgB);
    gll16(Bu + boff + k0, BuB);
    __syncthreads();
    I4B8 af[4], bg[2], bu[2];
#pragma unroll
    for (int i = 0; i < 4; ++i)
      af[i].i = *(const int4*)(Asd + (wm * 64 + i * 16 + l16) * 32 + quad * 8);
#pragma unroll
    for (int j = 0; j < 2; ++j) {
      bg[j].i = *(const int4*)(Bgd + (wn * 32 + j * 16 + l16) * 32 + quad * 8);
      bu[j].i = *(const int4*)(Bud + (wn * 32 + j * 16 + l16) * 32 + quad * 8);
    }
#pragma unroll
    for (int i = 0; i < 4; ++i)
#pragma unroll
      for (int j = 0; j < 2; ++j) {
        accg[i][j] = __builtin_amdgcn_mfma_f32_16x16x32_bf16(af[i].v, bg[j].v, accg[i][j], 0, 0, 0);
        accu[i][j] = __builtin_amdgcn_mfma_f32_16x16x32_bf16(af[i].v, bu[j].v, accu[i][j], 0, 0, 0);
      }
    __syncthreads();
  }
#pragma unroll
  for (int i = 0; i < 4; ++i) {
#pragma unroll
    for (int r = 0; r < 4; ++r) {
      int trow = wm * 64 + i * 16 + quad * 4 + r;
      int gp = bm + trow;
      if (gp < cnt) {
        size_t rowb = (size_t)(obase + gp) * N;
#pragma unroll
        for (int j = 0; j < 2; ++j) {
          int col = bn + wn * 32 + j * 16 + l16;
          float g = accg[i][j][r], uu = accu[i][j][r];
          float sg = g / (1.f + __expf(-g));
          outp[rowb + col] = __float2bfloat16(sg * uu);
        }
      }
    }
  }
}

// --------------------------------------------- q/k head rmsnorm + RoPE + bf16 cast
__global__ void qkv_post_kernel(const float* __restrict__ qkv,
                                const float* __restrict__ qw, const float* __restrict__ kw,
                                const float* __restrict__ cosb, const float* __restrict__ sinb,
                                __hip_bfloat16* __restrict__ qout,
                                __hip_bfloat16* __restrict__ kout,
                                __hip_bfloat16* __restrict__ vout) {
  int t = blockIdx.x;
  int u = blockIdx.y * 4 + (threadIdx.x >> 6);
  int lane = threadIdx.x & 63;
  if (u >= NH + NKV) {                       // v: plain cast (unused when grid.y==5)
    int h = u - NH - NKV;
    float xv = qkv[(size_t)t * QKV_N + (NH + NKV) * HD + h * HD + lane];
    vout[(size_t)t * (NKV * HD) + h * HD + lane] = __float2bfloat16(xv);
    return;
  }
  bool isq = (u < NH);
  int h = isq ? u : (u - NH);
  size_t src = (size_t)t * QKV_N + (isq ? (h * HD) : (NH * HD + h * HD)) + lane;
  float xv = qkv[src];
  float ss = xv * xv;
#pragma unroll
  for (int off = 32; off; off >>= 1) ss += __shfl_xor(ss, off);
  float r = rsqrtf(ss * (1.f / 64.f) + EPS);
  float xn = xv * r * (isq ? qw[lane] : kw[lane]);
  float other = __shfl_xor(xn, 32);
  float rot = (lane < 32) ? -other : other;
  float res = xn * cosb[t * 64 + lane] + rot * sinb[t * 64 + lane];
  if (isq) qout[(size_t)t * (NH * HD) + h * HD + lane] = __float2bfloat16(res * 0.125f);
  else     kout[(size_t)t * (NKV * HD) + h * HD + lane] = __float2bfloat16(res);
}

// --------------------------------------------- MFMA flash attention v3
// GQA-merged: block = (16-row q-tile, kv head); 4 waves = 4 q-heads sharing K/V.
// KVBLK=64 with -1e30 masking of the trailing half tile (block-causal at 32).
// V is pre-transposed globally (vT[256][2048]) so PV B-frags are ds_read_b128.
__global__ __launch_bounds__(256) void attn_kernel(
    const __hip_bfloat16* __restrict__ qg, const __hip_bfloat16* __restrict__ kg,
    const __hip_bfloat16* __restrict__ vT, __hip_bfloat16* __restrict__ attn) {
  int qt = (int)(gridDim.x - 1) - (int)blockIdx.x;   // heavy tiles first
  int kvh = blockIdx.y;
  int tid = threadIdx.x;
  int wave = tid >> 6, lane = tid & 63;
  int quad = lane >> 4, l16 = lane & 15;
  int h = kvh * 4 + wave;

  __shared__ __align__(16) int KsI[64 * 36];         // K tile [64 k][64 d + pad]
  __shared__ __align__(16) int VTI[64 * 36];         // V^T tile [64 d][64 k + pad]
  __shared__ __align__(16) int PsI[4][16 * 36];      // per-wave P [16 q][64 k + pad]

  // Q fragments direct from global: row qt*16+l16, d = ch*32 + quad*8 + j
  I4B8 qf[2];
#pragma unroll
  for (int ch = 0; ch < 2; ++ch)
    qf[ch].i = *(const int4*)((const abf16*)qg +
        (size_t)(qt * 16 + l16) * (NH * HD) + h * HD + ch * 32 + quad * 8);

  int nb = (qt >> 1) + 1;            // valid 32-blocks of kv
  int nt = (nb + 1) >> 1;            // 64-wide tiles
  bool half = (nb & 1) != 0;         // last tile only 32 valid

  float m_r[4], l_r[4];
  f32x4 o[4];
#pragma unroll
  for (int r = 0; r < 4; ++r) { m_r[r] = -1e30f; l_r[r] = 0.f; }
#pragma unroll
  for (int sub = 0; sub < 4; ++sub) o[sub] = (f32x4){0.f, 0.f, 0.f, 0.f};

  int sp = tid >> 3, sc = tid & 7;   // staging: 32 rows x 8 octets (x2 halves)

  for (int kc = 0; kc < nt; ++kc) {
    // ---- stage K tile and V^T tile (all vectorized)
    {
      const abf16* kb = (const abf16*)kg;
      int4 k0 = *(const int4*)(kb + (size_t)(kc * 64 + sp) * (NKV * HD) + kvh * HD + sc * 8);
      int4 k1 = *(const int4*)(kb + (size_t)(kc * 64 + 32 + sp) * (NKV * HD) + kvh * HD + sc * 8);
      const abf16* vb = (const abf16*)vT;
      int4 v0 = *(const int4*)(vb + (size_t)(kvh * HD + sp) * S + kc * 64 + sc * 8);
      int4 v1 = *(const int4*)(vb + (size_t)(kvh * HD + 32 + sp) * S + kc * 64 + sc * 8);
      *(int4*)&KsI[sp * 36 + sc * 4] = k0;
      *(int4*)&KsI[(sp + 32) * 36 + sc * 4] = k1;
      *(int4*)&VTI[sp * 36 + sc * 4] = v0;
      *(int4*)&VTI[(sp + 32) * 36 + sc * 4] = v1;
    }
    __syncthreads();

    // ---- QK^T: 16 q-rows x 64 k
    f32x4 s[4];
#pragma unroll
    for (int sub = 0; sub < 4; ++sub) s[sub] = (f32x4){0.f, 0.f, 0.f, 0.f};
#pragma unroll
    for (int sub = 0; sub < 4; ++sub)
#pragma unroll
      for (int ch = 0; ch < 2; ++ch) {
        I4B8 ku;
        ku.i = *(const int4*)&KsI[(sub * 16 + l16) * 36 + ch * 16 + quad * 4];
        s[sub] = __builtin_amdgcn_mfma_f32_16x16x32_bf16(qf[ch].v, ku.v, s[sub], 0, 0, 0);
      }
    if (half && kc == nt - 1) {
#pragma unroll
      for (int r = 0; r < 4; ++r) { s[2][r] = -1e30f; s[3][r] = -1e30f; }
    }

    // ---- online softmax (rows quad*4+r, reduce over 16 lanes = 64 k via 4 subs)
    abf16* pw = (abf16*)PsI[wave];
#pragma unroll
    for (int r = 0; r < 4; ++r) {
      float v = fmaxf(fmaxf(s[0][r], s[1][r]), fmaxf(s[2][r], s[3][r]));
#pragma unroll
      for (int off = 1; off < 16; off <<= 1) v = fmaxf(v, __shfl_xor(v, off));
      float mx = fmaxf(m_r[r], v);
      float al = __expf(m_r[r] - mx);
      m_r[r] = mx;
      float p0 = __expf(s[0][r] - mx);
      float p1 = __expf(s[1][r] - mx);
      float p2 = __expf(s[2][r] - mx);
      float p3 = __expf(s[3][r] - mx);
      float su = (p0 + p1) + (p2 + p3);
#pragma unroll
      for (int off = 1; off < 16; off <<= 1) su += __shfl_xor(su, off);
      l_r[r] = l_r[r] * al + su;
      int prow = quad * 4 + r;
      pw[prow * 72 + l16]      = (bf16_t)p0;
      pw[prow * 72 + 16 + l16] = (bf16_t)p1;
      pw[prow * 72 + 32 + l16] = (bf16_t)p2;
      pw[prow * 72 + 48 + l16] = (bf16_t)p3;
#pragma unroll
      for (int sub = 0; sub < 4; ++sub) o[sub][r] *= al;
    }

    // ---- PV: P(16x64) x V(64x64); per-wave P, vectorized V^T frags
    I4B8 pu[2];
#pragma unroll
    for (int ch = 0; ch < 2; ++ch)
      pu[ch].i = *(const int4*)&PsI[wave][l16 * 36 + ch * 16 + quad * 4];
#pragma unroll
    for (int sub = 0; sub < 4; ++sub)
#pragma unroll
      for (int ch = 0; ch < 2; ++ch) {
        I4B8 vf;
        vf.i = *(const int4*)&VTI[(sub * 16 + l16) * 36 + ch * 16 + quad * 4];
        o[sub] = __builtin_amdgcn_mfma_f32_16x16x32_bf16(pu[ch].v, vf.v, o[sub], 0, 0, 0);
      }
    __syncthreads();
  }

#pragma unroll
  for (int r = 0; r < 4; ++r) {
    float inv = 1.f / l_r[r];
    int row = qt * 16 + quad * 4 + r;
#pragma unroll
    for (int sub = 0; sub < 4; ++sub)
      attn[(size_t)row * (NH * HD) + h * HD + sub * 16 + l16] =
          __float2bfloat16(o[sub][r] * inv);
  }
}

// ---------------------------------------------------------------- router
__global__ void zero_counts_kernel(int* counts) {
  if (threadIdx.x < NE) counts[threadIdx.x] = 0;
}

__global__ void router_kernel(const float* __restrict__ h2, const float* __restrict__ rw,
                              int* counts, int* tok_list, int* topk_e, int* topk_pos,
                              float* topk_w) {
  int t = blockIdx.x;
  int lane = threadIdx.x;   // 64
  float p[NE] = {};
  for (int d = lane; d < D; d += 64) {
    float hv = h2[(size_t)t * D + d];
#pragma unroll
    for (int e = 0; e < NE; ++e) p[e] += hv * rw[d * NE + e];
  }
#pragma unroll
  for (int off = 32; off; off >>= 1)
#pragma unroll
    for (int e = 0; e < NE; ++e) p[e] += __shfl_xor(p[e], off);
  if (lane == 0) {
    float mx = p[0];
#pragma unroll
    for (int e = 1; e < NE; ++e) mx = fmaxf(mx, p[e]);
    float ex[NE];
#pragma unroll
    for (int e = 0; e < NE; ++e) ex[e] = __expf(p[e] - mx);
    int e0 = 0;
#pragma unroll
    for (int e = 1; e < NE; ++e) if (ex[e] > ex[e0]) e0 = e;
    int e1 = (e0 == 0) ? 1 : 0;
#pragma unroll
    for (int e = 0; e < NE; ++e) if (e != e0 && ex[e] > ex[e1]) e1 = e;
    float w0 = ex[e0] / (ex[e0] + ex[e1]);
    float w1 = ex[e1] / (ex[e0] + ex[e1]);
    int pos0 = atomicAdd(&counts[e0], 1);
    int pos1 = atomicAdd(&counts[e1], 1);
    tok_list[e0 * S + pos0] = t;
    tok_list[e1 * S + pos1] = t;
    topk_e[2 * t] = e0;  topk_e[2 * t + 1] = e1;
    topk_pos[2 * t] = pos0;  topk_pos[2 * t + 1] = pos1;
    topk_w[2 * t] = w0;  topk_w[2 * t + 1] = w1;
  }
}

__global__ void scan_kernel(const int* counts, int* offsets) {
  if (threadIdx.x == 0) {
    int acc = 0;
    for (int e = 0; e < NE; ++e) { offsets[e] = acc; acc += counts[e]; }
  }
}

// ---------------------------------------------------------------- final add
__global__ void final_kernel(const float* __restrict__ x, const float* __restrict__ sout,
                             const float* __restrict__ eo,
                             const int* __restrict__ topk_e, const int* __restrict__ topk_pos,
                             const float* __restrict__ topk_w, const int* __restrict__ offsets,
                             float* __restrict__ out) {
  int t = blockIdx.x;
  int tid = threadIdx.x;
  int e0 = topk_e[2 * t], e1 = topk_e[2 * t + 1];
  size_t r0 = (size_t)offsets[e0] + topk_pos[2 * t];
  size_t r1 = (size_t)offsets[e1] + topk_pos[2 * t + 1];
  float w0 = topk_w[2 * t], w1 = topk_w[2 * t + 1];
#pragma unroll
  for (int i = 0; i < 4; ++i) {
    int d = tid + i * 256;
    size_t idx = (size_t)t * D + d;
    out[idx] = x[idx] + sout[idx] + w0 * eo[r0 * D + d] + w1 * eo[r1 * D + d];
  }
}

extern "C" void kernel_launch(void* const* d_in, const int* in_sizes, int n_in,
                              void* d_out, int out_size, void* d_ws, size_t ws_size,
                              hipStream_t stream) {
  const float* hidden  = (const float*)d_in[0];
  const float* cosb    = (const float*)d_in[1];
  const float* sinb    = (const float*)d_in[2];
  const float* w_qkv   = (const float*)d_in[3];
  const float* w_o     = (const float*)d_in[4];
  const float* q_norm  = (const float*)d_in[5];
  const float* k_norm  = (const float*)d_in[6];
  const float* in_ln   = (const float*)d_in[7];
  const float* post_ln = (const float*)d_in[8];
  const float* router_w= (const float*)d_in[9];
  const float* w_gate  = (const float*)d_in[10];
  const float* w_up    = (const float*)d_in[11];
  const float* w_down  = (const float*)d_in[12];
  const float* ws_gate = (const float*)d_in[13];
  const float* ws_up   = (const float*)d_in[14];
  const float* ws_down = (const float*)d_in[15];
  float* out = (float*)d_out;
  float* ws = (float*)d_ws;

  typedef __hip_bfloat16 hbf;
  // weights (bf16)
  hbf* wqkvT = (hbf*)(ws);                      // 1.5M el
  hbf* woT   = (hbf*)(ws +  768 * 1024);        // 1M el
  hbf* wgT   = (hbf*)(ws + 1280 * 1024);        // 8M el
  hbf* wuT   = (hbf*)(ws + 5376 * 1024);        // 8M el
  hbf* wdT   = (hbf*)(ws + 9472 * 1024);        // 8M el
  hbf* wsgT  = (hbf*)(ws + 13568 * 1024);       // 1M el
  hbf* wsuT  = (hbf*)(ws + 14080 * 1024);       // 1M el
  hbf* wsdT  = (hbf*)(ws + 14592 * 1024);       // 1M el
  // activations
  hbf*   hb      = (hbf*)(ws + 15104 * 1024);   // [15104K,16128K)
  float* qkv     = ws + 16128 * 1024;           // [16128K,19200K)
  hbf*   qbB     = (hbf*)(ws + 19200 * 1024);   // [19200K,20224K)
  hbf*   kbB     = (hbf*)(ws + 20224 * 1024);   // [20224K,20480K)
  hbf*   vTb     = (hbf*)(ws + 20480 * 1024);   // [20480K,20736K)  V^T [256][2048]
  hbf*   attnb16 = (hbf*)(ws + 20736 * 1024);   // [20736K,21760K)
  float* x       = ws + 22784 * 1024;           // 2M fl
  float* h2      = ws + 24832 * 1024;           // 2M fl
  hbf*   h2b     = (hbf*)(ws + 26880 * 1024);   // [26880K,27904K)
  hbf*   act     = (hbf*)(ws + 16128 * 1024);   // 4096x1024 bf16, aliases dead qkv
  float* eo      = ws + 18176 * 1024;           // 4096x1024 fp32, aliases dead q/k/v/attnb16
  hbf*   sact    = (hbf*)(ws + 27904 * 1024);   // 2048x1024 bf16
  float* sout    = ws + 28928 * 1024;           // 2048x1024 fp32
  int* counts   = (int*)(ws + 30976 * 1024);
  int* offsets  = counts + NE;
  int* tok_list = offsets + NE;
  int* topk_e   = tok_list + NE * S;
  int* topk_pos = topk_e + 2 * S;
  float* topk_w = (float*)(topk_pos + 2 * S);

  dim3 b256(256);
  zero_counts_kernel<<<1, 64, 0, stream>>>(counts);
  transpose_cast_kernel<<<dim3(QKV_N/32, D/32, 1), b256, 0, stream>>>(w_qkv, wqkvT, D, QKV_N);
  transpose_cast_kernel<<<dim3(D/32, D/32, 1),     b256, 0, stream>>>(w_o, woT, D, D);
  transpose_cast_kernel<<<dim3(NI/32, D/32, NE),   b256, 0, stream>>>(w_gate, wgT, D, NI);
  transpose_cast_kernel<<<dim3(NI/32, D/32, NE),   b256, 0, stream>>>(w_up, wuT, D, NI);
  transpose_cast_kernel<<<dim3(D/32, NI/32, NE),   b256, 0, stream>>>(w_down, wdT, NI, D);
  transpose_cast_kernel<<<dim3(NI/32, D/32, 1),    b256, 0, stream>>>(ws_gate, wsgT, D, NI);
  transpose_cast_kernel<<<dim3(NI/32, D/32, 1),    b256, 0, stream>>>(ws_up, wsuT, D, NI);
  transpose_cast_kernel<<<dim3(D/32, NI/32, 1),    b256, 0, stream>>>(ws_down, wsdT, NI, D);
  // attention block
  rmsnorm_kernel<<<S, b256, 0, stream>>>(hidden, in_ln, nullptr, hb);
  mgemm_kernel<<<dim3(QKV_N/128, S/128, 1), b256, 0, stream>>>(hb, wqkvT, nullptr, qkv,
      S, QKV_N, D, nullptr, nullptr, nullptr, 0, nullptr, nullptr, nullptr);
  qkv_post_kernel<<<dim3(S, 5), b256, 0, stream>>>(qkv, q_norm, k_norm, cosb, sinb, qbB, kbB, nullptr);
  v_transpose_kernel<<<dim3(S/32, (NKV*HD)/32), b256, 0, stream>>>(qkv, vTb);
  attn_kernel<<<dim3(S/16, NKV), b256, 0, stream>>>(qbB, kbB, vTb, attnb16);
  mgemm_kernel<<<dim3(D/128, S/128, 1), b256, 0, stream>>>(attnb16, woT, hidden, x,
      S, D, D, nullptr, nullptr, nullptr, 0, nullptr, nullptr, nullptr);
  // MoE block (shared expert merged as z == NE)
  rmsnorm_kernel<<<S, b256, 0, stream>>>(x, post_ln, h2, h2b);
  router_kernel<<<S, 64, 0, stream>>>(h2, router_w, counts, tok_list, topk_e, topk_pos, topk_w);
  scan_kernel<<<1, 64, 0, stream>>>(counts, offsets);
  mgemm_gu_kernel<<<dim3(NI/64, S/128, NE + 1), b256, 0, stream>>>(h2b, wgT, wuT, act,
      S, NI, D, counts, offsets, tok_list, wsgT, wsuT, sact);
  mgemm_kernel<<<dim3(D/128, S/128, NE + 1), b256, 0, stream>>>(act, wdT, nullptr, eo,
      S, D, NI, counts, offsets, nullptr, 1, sact, wsdT, sout);
  final_kernel<<<S, b256, 0, stream>>>(x, sout, eo, topk_e, topk_pos, topk_w, offsets, out);
}

// Round 3
// 496.381 us; speedup vs baseline: 1.1373x; 1.0305x over previous
//
#include <hip/hip_runtime.h>
#include <hip/hip_bf16.h>
#include <math.h>

#define S 2048
#define D 1024
#define NH 16
#define NKV 4
#define HD 64
#define QKV_N 1536          // (NH + 2*NKV) * HD
#define NE 8
#define NI 1024
#define EPS 1e-6f

typedef __bf16 bf16_t;
typedef __bf16 __attribute__((may_alias)) abf16;
typedef __attribute__((ext_vector_type(8))) __bf16 bf16x8;
typedef __attribute__((ext_vector_type(4))) float f32x4;
union I4B8 { int4 i; bf16x8 v; bf16_t e[8]; };

// async global->LDS, 16B per lane. LDS dest must be wave-uniform base
// (HW adds lane*16); global src is per-lane.
__device__ __forceinline__ void gll16(const void* g, void* l) {
  __builtin_amdgcn_global_load_lds(
      (const __attribute__((address_space(1))) void*)g,
      (__attribute__((address_space(3))) void*)l, 16, 0, 0);
}

// ---------------------------------------------------------------- rmsnorm(D)
__global__ void rmsnorm_kernel(const float* __restrict__ in, const float* __restrict__ w,
                               float* __restrict__ out32, __hip_bfloat16* __restrict__ out16) {
  int t = blockIdx.x;
  int tid = threadIdx.x;
  const float* row = in + (size_t)t * D;
  float v[4];
  float ss = 0.f;
#pragma unroll
  for (int i = 0; i < 4; ++i) {
    v[i] = row[tid + i * 256];
    ss += v[i] * v[i];
  }
#pragma unroll
  for (int off = 32; off; off >>= 1) ss += __shfl_xor(ss, off);
  __shared__ float wsum[4];
  int wave = tid >> 6;
  if ((tid & 63) == 0) wsum[wave] = ss;
  __syncthreads();
  float tot = wsum[0] + wsum[1] + wsum[2] + wsum[3];
  float r = rsqrtf(tot / (float)D + EPS);
#pragma unroll
  for (int i = 0; i < 4; ++i) {
    int d = tid + i * 256;
    float val = v[i] * r * w[d];
    if (out32) out32[(size_t)t * D + d] = val;
    if (out16) out16[(size_t)t * D + d] = __float2bfloat16(val);
  }
}

// ------------------------------------------- weight transpose + bf16 cast
__global__ void transpose_cast_kernel(const float* __restrict__ W,
                                      __hip_bfloat16* __restrict__ WT, int Kd, int Nd) {
  __shared__ float tile[32][33];
  int e = blockIdx.z;
  const float* Wp = W + (size_t)e * Kd * Nd;
  __hip_bfloat16* WTp = WT + (size_t)e * Kd * Nd;
  int n0 = blockIdx.x * 32, k0 = blockIdx.y * 32;
  int tx = threadIdx.x & 31, ty = threadIdx.x >> 5;
#pragma unroll
  for (int i = 0; i < 4; ++i)
    tile[ty + i * 8][tx] = Wp[(size_t)(k0 + ty + i * 8) * Nd + n0 + tx];
  __syncthreads();
#pragma unroll
  for (int i = 0; i < 4; ++i)
    WTp[(size_t)(n0 + ty + i * 8) * Kd + k0 + tx] = __float2bfloat16(tile[tx][ty + i * 8]);
}

// ------------------------------------------- V transpose (fp32 qkv slice -> bf16 vT[256][2048])
__global__ void v_transpose_kernel(const float* __restrict__ qkv, __hip_bfloat16* __restrict__ vT) {
  __shared__ float tile[32][33];
  int t0 = blockIdx.x * 32;            // token
  int c0 = blockIdx.y * 32;            // v channel (0..255)
  int tx = threadIdx.x & 31, ty = threadIdx.x >> 5;
#pragma unroll
  for (int i = 0; i < 4; ++i)
    tile[ty + i * 8][tx] = qkv[(size_t)(t0 + ty + i * 8) * QKV_N + (NH + NKV) * HD + c0 + tx];
  __syncthreads();
#pragma unroll
  for (int i = 0; i < 4; ++i)
    vT[(size_t)(c0 + ty + i * 8) * S + t0 + tx] = __float2bfloat16(tile[tx][ty + i * 8]);
}

// ------------------------------------------- MFMA bf16 GEMM, 128x128 tile (m97 structure)
__global__ __launch_bounds__(256) void mgemm_kernel(
    const __hip_bfloat16* __restrict__ A, const __hip_bfloat16* __restrict__ BT,
    const float* __restrict__ Cadd, float* __restrict__ C,
    int M, int N, int K,
    const int* __restrict__ counts, const int* __restrict__ offsets,
    const int* __restrict__ tok, int a_comp,
    const __hip_bfloat16* __restrict__ As2, const __hip_bfloat16* __restrict__ BTs2,
    float* __restrict__ Cs2) {
  __shared__ __align__(16) bf16_t Asd[128 * 32];   // [row][k] linear, 8 KB
  __shared__ __align__(16) bf16_t Bsd[128 * 32];
  __shared__ int rowmap[128];
  int e = blockIdx.z;
  bool sh = (counts != nullptr) && (e == NE);
  int cnt = sh ? M : (counts ? counts[e] : M);
  int bm = blockIdx.y * 128;
  if (bm >= cnt) return;
  int bn = blockIdx.x * 128;
  int obase = sh ? 0 : (offsets ? offsets[e] : 0);
  const bf16_t* Ab = sh ? (const bf16_t*)As2 : (const bf16_t*)A;
  const bf16_t* BTe = sh ? (const bf16_t*)BTs2 : ((const bf16_t*)BT + (size_t)e * N * K);
  float* Cp = sh ? Cs2 : C;
  const int* toke = (!sh && tok) ? tok + e * S : nullptr;
  int acompe = sh ? 0 : a_comp;
  int tid = threadIdx.x;
  if (tid < 128) {
    int gp = bm + tid;
    int cp = gp < cnt ? gp : cnt - 1;
    rowmap[tid] = toke ? toke[cp] : (acompe ? obase + cp : cp);
  }
  __syncthreads();
  int wave = tid >> 6, lane = tid & 63;
  int quad = lane >> 4, l16 = lane & 15;
  int wm = wave >> 1, wn = wave & 1;
  int srow = tid >> 2, scol = (tid & 3) * 8;
  size_t aoff0 = (size_t)rowmap[srow] * K + scol;
  size_t aoff1 = (size_t)rowmap[64 + srow] * K + scol;
  size_t boff0 = (size_t)(bn + srow) * K + scol;
  size_t boff1 = (size_t)(bn + 64 + srow) * K + scol;
  char* AsB = (char*)Asd + wave * 1024;
  char* BsB = (char*)Bsd + wave * 1024;
  f32x4 acc[4][4];
#pragma unroll
  for (int i = 0; i < 4; ++i)
#pragma unroll
    for (int j = 0; j < 4; ++j) acc[i][j] = (f32x4){0.f, 0.f, 0.f, 0.f};
  for (int k0 = 0; k0 < K; k0 += 32) {
    gll16(Ab + aoff0 + k0, AsB);
    gll16(Ab + aoff1 + k0, AsB + 4096);
    gll16(BTe + boff0 + k0, BsB);
    gll16(BTe + boff1 + k0, BsB + 4096);
    __syncthreads();
    I4B8 af[4], bfr[4];
#pragma unroll
    for (int i = 0; i < 4; ++i)
      af[i].i = *(const int4*)(Asd + (wm * 64 + i * 16 + l16) * 32 + quad * 8);
#pragma unroll
    for (int j = 0; j < 4; ++j)
      bfr[j].i = *(const int4*)(Bsd + (wn * 64 + j * 16 + l16) * 32 + quad * 8);
#pragma unroll
    for (int i = 0; i < 4; ++i)
#pragma unroll
      for (int j = 0; j < 4; ++j)
        acc[i][j] = __builtin_amdgcn_mfma_f32_16x16x32_bf16(af[i].v, bfr[j].v, acc[i][j], 0, 0, 0);
    __syncthreads();
  }
#pragma unroll
  for (int i = 0; i < 4; ++i) {
#pragma unroll
    for (int r = 0; r < 4; ++r) {
      int trow = wm * 64 + i * 16 + quad * 4 + r;
      int gp = bm + trow;
      if (gp < cnt) {
        size_t rowb = (size_t)(obase + gp) * N;
#pragma unroll
        for (int j = 0; j < 4; ++j) {
          int col = bn + wn * 64 + j * 16 + l16;
          size_t idx = rowb + col;
          Cp[idx] = acc[i][j][r] + (Cadd ? Cadd[idx] : 0.f);
        }
      }
    }
  }
}

// ------------------------------------------- dual-B MFMA GEMM + silu, 128x64 tile
__global__ __launch_bounds__(256) void mgemm_gu_kernel(
    const __hip_bfloat16* __restrict__ A, const __hip_bfloat16* __restrict__ BTg,
    const __hip_bfloat16* __restrict__ BTu, __hip_bfloat16* __restrict__ act,
    int M, int N, int K,
    const int* __restrict__ counts, const int* __restrict__ offsets,
    const int* __restrict__ tok,
    const __hip_bfloat16* __restrict__ BTgs, const __hip_bfloat16* __restrict__ BTus,
    __hip_bfloat16* __restrict__ acts) {
  __shared__ __align__(16) bf16_t Asd[128 * 32];   // 8 KB
  __shared__ __align__(16) bf16_t Bgd[64 * 32];    // 4 KB
  __shared__ __align__(16) bf16_t Bud[64 * 32];    // 4 KB
  __shared__ int rowmap[128];
  int e = blockIdx.z;
  bool sh = (counts != nullptr) && (e == NE);
  int cnt = sh ? M : (counts ? counts[e] : M);
  int bm = blockIdx.y * 128;
  if (bm >= cnt) return;
  int bn = blockIdx.x * 64;
  const bf16_t* Ab = (const bf16_t*)A;
  const bf16_t* Bg = sh ? (const bf16_t*)BTgs : ((const bf16_t*)BTg + (size_t)e * N * K);
  const bf16_t* Bu = sh ? (const bf16_t*)BTus : ((const bf16_t*)BTu + (size_t)e * N * K);
  bf16_t* outp = sh ? (bf16_t*)acts : (bf16_t*)act;
  int obase = sh ? 0 : (offsets ? offsets[e] : 0);
  const int* toke = (!sh && tok) ? tok + e * S : nullptr;
  int tid = threadIdx.x;
  if (tid < 128) {
    int gp = bm + tid;
    int cp = gp < cnt ? gp : cnt - 1;
    rowmap[tid] = toke ? toke[cp] : cp;
  }
  __syncthreads();
  int wave = tid >> 6, lane = tid & 63;
  int quad = lane >> 4, l16 = lane & 15;
  int wm = wave >> 1, wn = wave & 1;
  int srow = tid >> 2, scol = (tid & 3) * 8;
  size_t aoff0 = (size_t)rowmap[srow] * K + scol;
  size_t aoff1 = (size_t)rowmap[64 + srow] * K + scol;
  size_t boff = (size_t)(bn + srow) * K + scol;
  char* AsB = (char*)Asd + wave * 1024;
  char* BgB = (char*)Bgd + wave * 1024;
  char* BuB = (char*)Bud + wave * 1024;
  f32x4 accg[4][2], accu[4][2];
#pragma unroll
  for (int i = 0; i < 4; ++i)
#pragma unroll
    for (int j = 0; j < 2; ++j) {
      accg[i][j] = (f32x4){0.f, 0.f, 0.f, 0.f};
      accu[i][j] = (f32x4){0.f, 0.f, 0.f, 0.f};
    }
  for (int k0 = 0; k0 < K; k0 += 32) {
    gll16(Ab + aoff0 + k0, AsB);
    gll16(Ab + aoff1 + k0, AsB + 4096);
    gll16(Bg + boff + k0, BgB);
    gll16(Bu + boff + k0, BuB);
    __syncthreads();
    I4B8 af[4], bg[2], bu[2];
#pragma unroll
    for (int i = 0; i < 4; ++i)
      af[i].i = *(const int4*)(Asd + (wm * 64 + i * 16 + l16) * 32 + quad * 8);
#pragma unroll
    for (int j = 0; j < 2; ++j) {
      bg[j].i = *(const int4*)(Bgd + (wn * 32 + j * 16 + l16) * 32 + quad * 8);
      bu[j].i = *(const int4*)(Bud + (wn * 32 + j * 16 + l16) * 32 + quad * 8);
    }
#pragma unroll
    for (int i = 0; i < 4; ++i)
#pragma unroll
      for (int j = 0; j < 2; ++j) {
        accg[i][j] = __builtin_amdgcn_mfma_f32_16x16x32_bf16(af[i].v, bg[j].v, accg[i][j], 0, 0, 0);
        accu[i][j] = __builtin_amdgcn_mfma_f32_16x16x32_bf16(af[i].v, bu[j].v, accu[i][j], 0, 0, 0);
      }
    __syncthreads();
  }
#pragma unroll
  for (int i = 0; i < 4; ++i) {
#pragma unroll
    for (int r = 0; r < 4; ++r) {
      int trow = wm * 64 + i * 16 + quad * 4 + r;
      int gp = bm + trow;
      if (gp < cnt) {
        size_t rowb = (size_t)(obase + gp) * N;
#pragma unroll
        for (int j = 0; j < 2; ++j) {
          int col = bn + wn * 32 + j * 16 + l16;
          float g = accg[i][j][r], uu = accu[i][j][r];
          float sg = g / (1.f + __expf(-g));
          outp[rowb + col] = __float2bfloat16(sg * uu);
        }
      }
    }
  }
}

// --------------------------------------------- q/k head rmsnorm + RoPE + bf16 cast
__global__ void qkv_post_kernel(const float* __restrict__ qkv,
                                const float* __restrict__ qw, const float* __restrict__ kw,
                                const float* __restrict__ cosb, const float* __restrict__ sinb,
                                __hip_bfloat16* __restrict__ qout,
                                __hip_bfloat16* __restrict__ kout,
                                __hip_bfloat16* __restrict__ vout) {
  int t = blockIdx.x;
  int u = blockIdx.y * 4 + (threadIdx.x >> 6);
  int lane = threadIdx.x & 63;
  if (u >= NH + NKV) {
    int h = u - NH - NKV;
    float xv = qkv[(size_t)t * QKV_N + (NH + NKV) * HD + h * HD + lane];
    vout[(size_t)t * (NKV * HD) + h * HD + lane] = __float2bfloat16(xv);
    return;
  }
  bool isq = (u < NH);
  int h = isq ? u : (u - NH);
  size_t src = (size_t)t * QKV_N + (isq ? (h * HD) : (NH * HD + h * HD)) + lane;
  float xv = qkv[src];
  float ss = xv * xv;
#pragma unroll
  for (int off = 32; off; off >>= 1) ss += __shfl_xor(ss, off);
  float r = rsqrtf(ss * (1.f / 64.f) + EPS);
  float xn = xv * r * (isq ? qw[lane] : kw[lane]);
  float other = __shfl_xor(xn, 32);
  float rot = (lane < 32) ? -other : other;
  float res = xn * cosb[t * 64 + lane] + rot * sinb[t * 64 + lane];
  if (isq) qout[(size_t)t * (NH * HD) + h * HD + lane] = __float2bfloat16(res * 0.125f);
  else     kout[(size_t)t * (NKV * HD) + h * HD + lane] = __float2bfloat16(res);
}

// --------------------------------------------- MFMA flash attention v4
// GQA-merged + KV-split-2 (flash-decoding). Block = (16-row q-tile, kv head, chunk z).
// 4 waves = 4 q-heads sharing K/V. T14 async staging (regs loaded one tile ahead).
// l accumulated via ones-column MFMA (no sum shuffles). Partials merged by attn_merge.
__global__ __launch_bounds__(256) void attn_kernel(
    const __hip_bfloat16* __restrict__ qg, const __hip_bfloat16* __restrict__ kg,
    const __hip_bfloat16* __restrict__ vT,
    float* __restrict__ opart0, float* __restrict__ opart1,
    float* __restrict__ mpart, float* __restrict__ lpart) {
  int qt = (int)(gridDim.x - 1) - (int)blockIdx.x;   // heavy tiles first
  int kvh = blockIdx.y;
  int z = blockIdx.z;
  int tid = threadIdx.x;
  int wave = tid >> 6, lane = tid & 63;
  int quad = lane >> 4, l16 = lane & 15;
  int h = kvh * 4 + wave;

  float* opz = z ? opart1 : opart0;
  float* mp = mpart + (size_t)z * S * NH;
  float* lp = lpart + (size_t)z * S * NH;

  int nb = (qt >> 1) + 1;            // valid 32-blocks of kv
  int nt = (nb + 1) >> 1;            // 64-wide tiles
  bool halfm = (nb & 1) != 0;        // last tile only 32 valid
  int h0 = nt >> 1;
  int lo = z ? h0 : 0;
  int hi = z ? nt : h0;

  if (lo >= hi) {                    // empty chunk: zero partials
    int row = qt * 16 + (tid >> 4);
    float* od = opz + (size_t)row * (NH * HD) + kvh * 256 + (tid & 15) * 16;
    int4 zz = {0, 0, 0, 0};
#pragma unroll
    for (int i = 0; i < 4; ++i) *(int4*)(od + i * 4) = zz;
    if (tid < 64) {
      int rr = qt * 16 + (tid >> 2), hh = kvh * 4 + (tid & 3);
      mp[(size_t)rr * NH + hh] = -1e30f;
      lp[(size_t)rr * NH + hh] = 0.f;
    }
    return;
  }

  __shared__ __align__(16) int KsI[64 * 36];         // K tile [64 k][64 d + pad]
  __shared__ __align__(16) int VTI[64 * 36];         // V^T tile [64 d][64 k + pad]
  __shared__ __align__(16) int PsI[4][16 * 36];      // per-wave P [16 q][64 k + pad]

  I4B8 qf[2];
#pragma unroll
  for (int ch = 0; ch < 2; ++ch)
    qf[ch].i = *(const int4*)((const abf16*)qg +
        (size_t)(qt * 16 + l16) * (NH * HD) + h * HD + ch * 32 + quad * 8);

  I4B8 ones;
  ones.i = (int4){0x3F803F80, 0x3F803F80, 0x3F803F80, 0x3F803F80};   // 8x bf16 1.0

  float m_r[4];
  f32x4 o[4], o4;
#pragma unroll
  for (int r = 0; r < 4; ++r) m_r[r] = -1e30f;
#pragma unroll
  for (int sub = 0; sub < 4; ++sub) o[sub] = (f32x4){0.f, 0.f, 0.f, 0.f};
  o4 = (f32x4){0.f, 0.f, 0.f, 0.f};

  int sp = tid >> 3, sc = tid & 7;   // staging: 32 rows x 8 octets (x2 halves)
  const abf16* kb = (const abf16*)kg;
  const abf16* vb = (const abf16*)vT;

  // T14 prologue: load first tile into regs
  int4 rk0 = *(const int4*)(kb + (size_t)(lo * 64 + sp) * (NKV * HD) + kvh * HD + sc * 8);
  int4 rk1 = *(const int4*)(kb + (size_t)(lo * 64 + 32 + sp) * (NKV * HD) + kvh * HD + sc * 8);
  int4 rv0 = *(const int4*)(vb + (size_t)(kvh * HD + sp) * S + lo * 64 + sc * 8);
  int4 rv1 = *(const int4*)(vb + (size_t)(kvh * HD + 32 + sp) * S + lo * 64 + sc * 8);

  for (int kc = lo; kc < hi; ++kc) {
    // ---- write staged regs to LDS (prev compute done via loop-bottom barrier)
    *(int4*)&KsI[sp * 36 + sc * 4] = rk0;
    *(int4*)&KsI[(sp + 32) * 36 + sc * 4] = rk1;
    *(int4*)&VTI[sp * 36 + sc * 4] = rv0;
    *(int4*)&VTI[(sp + 32) * 36 + sc * 4] = rv1;
    __syncthreads();

    // ---- issue next tile loads (latency hides under compute below)
    if (kc + 1 < hi) {
      rk0 = *(const int4*)(kb + (size_t)((kc + 1) * 64 + sp) * (NKV * HD) + kvh * HD + sc * 8);
      rk1 = *(const int4*)(kb + (size_t)((kc + 1) * 64 + 32 + sp) * (NKV * HD) + kvh * HD + sc * 8);
      rv0 = *(const int4*)(vb + (size_t)(kvh * HD + sp) * S + (kc + 1) * 64 + sc * 8);
      rv1 = *(const int4*)(vb + (size_t)(kvh * HD + 32 + sp) * S + (kc + 1) * 64 + sc * 8);
    }

    // ---- QK^T: 16 q-rows x 64 k
    f32x4 s[4];
#pragma unroll
    for (int sub = 0; sub < 4; ++sub) s[sub] = (f32x4){0.f, 0.f, 0.f, 0.f};
    __builtin_amdgcn_s_setprio(1);
#pragma unroll
    for (int sub = 0; sub < 4; ++sub)
#pragma unroll
      for (int ch = 0; ch < 2; ++ch) {
        I4B8 ku;
        ku.i = *(const int4*)&KsI[(sub * 16 + l16) * 36 + ch * 16 + quad * 4];
        s[sub] = __builtin_amdgcn_mfma_f32_16x16x32_bf16(qf[ch].v, ku.v, s[sub], 0, 0, 0);
      }
    __builtin_amdgcn_s_setprio(0);
    if (halfm && kc == nt - 1) {
#pragma unroll
      for (int r = 0; r < 4; ++r) { s[2][r] = -1e30f; s[3][r] = -1e30f; }
    }

    // ---- online softmax: max-reduce + exp; sums come from ones-MFMA
    abf16* pw = (abf16*)PsI[wave];
#pragma unroll
    for (int r = 0; r < 4; ++r) {
      float v = fmaxf(fmaxf(s[0][r], s[1][r]), fmaxf(s[2][r], s[3][r]));
#pragma unroll
      for (int off = 1; off < 16; off <<= 1) v = fmaxf(v, __shfl_xor(v, off));
      float mx = fmaxf(m_r[r], v);
      float al = __expf(m_r[r] - mx);
      m_r[r] = mx;
      float p0 = __expf(s[0][r] - mx);
      float p1 = __expf(s[1][r] - mx);
      float p2 = __expf(s[2][r] - mx);
      float p3 = __expf(s[3][r] - mx);
      int prow = quad * 4 + r;
      pw[prow * 72 + l16]      = (bf16_t)p0;
      pw[prow * 72 + 16 + l16] = (bf16_t)p1;
      pw[prow * 72 + 32 + l16] = (bf16_t)p2;
      pw[prow * 72 + 48 + l16] = (bf16_t)p3;
      o4[r] *= al;
#pragma unroll
      for (int sub = 0; sub < 4; ++sub) o[sub][r] *= al;
    }

    // ---- PV: P(16x64) x V(64x64) + ones-column for row sums
    I4B8 pu[2];
#pragma unroll
    for (int ch = 0; ch < 2; ++ch)
      pu[ch].i = *(const int4*)&PsI[wave][l16 * 36 + ch * 16 + quad * 4];
    __builtin_amdgcn_s_setprio(1);
#pragma unroll
    for (int sub = 0; sub < 4; ++sub)
#pragma unroll
      for (int ch = 0; ch < 2; ++ch) {
        I4B8 vf;
        vf.i = *(const int4*)&VTI[(sub * 16 + l16) * 36 + ch * 16 + quad * 4];
        o[sub] = __builtin_amdgcn_mfma_f32_16x16x32_bf16(pu[ch].v, vf.v, o[sub], 0, 0, 0);
      }
#pragma unroll
    for (int ch = 0; ch < 2; ++ch)
      o4 = __builtin_amdgcn_mfma_f32_16x16x32_bf16(pu[ch].v, ones.v, o4, 0, 0, 0);
    __builtin_amdgcn_s_setprio(0);
    __syncthreads();
  }

  // epilogue: write raw partials (normalize at merge)
#pragma unroll
  for (int r = 0; r < 4; ++r) {
    int row = qt * 16 + quad * 4 + r;
    float* od = opz + (size_t)row * (NH * HD) + h * HD;
#pragma unroll
    for (int sub = 0; sub < 4; ++sub)
      od[sub * 16 + l16] = o[sub][r];
    if (l16 == 0) {
      mp[(size_t)row * NH + h] = m_r[r];
      lp[(size_t)row * NH + h] = o4[r];
    }
  }
}

// --------------------------------------------- merge KV-split partials
__global__ void attn_merge_kernel(const float* __restrict__ opart0,
                                  const float* __restrict__ opart1,
                                  const float* __restrict__ mpart,
                                  const float* __restrict__ lpart,
                                  __hip_bfloat16* __restrict__ attn) {
  int row = blockIdx.x;
  int tid = threadIdx.x;
#pragma unroll
  for (int i = 0; i < 4; ++i) {
    int c = tid + i * 256;
    int h = c >> 6;
    float m0 = mpart[(size_t)row * NH + h];
    float m1 = mpart[(size_t)(S + row) * NH + h];
    float l0 = lpart[(size_t)row * NH + h];
    float l1 = lpart[(size_t)(S + row) * NH + h];
    float M = fmaxf(m0, m1);
    float a0 = __expf(m0 - M), a1 = __expf(m1 - M);
    float l = l0 * a0 + l1 * a1;
    float v = (opart0[(size_t)row * (NH * HD) + c] * a0 +
               opart1[(size_t)row * (NH * HD) + c] * a1) / l;
    attn[(size_t)row * (NH * HD) + c] = __float2bfloat16(v);
  }
}

// ---------------------------------------------------------------- router
__global__ void zero_counts_kernel(int* counts) {
  if (threadIdx.x < NE) counts[threadIdx.x] = 0;
}

__global__ void router_kernel(const float* __restrict__ h2, const float* __restrict__ rw,
                              int* counts, int* tok_list, int* topk_e, int* topk_pos,
                              float* topk_w) {
  int t = blockIdx.x;
  int lane = threadIdx.x;   // 64
  float p[NE] = {};
  for (int d = lane; d < D; d += 64) {
    float hv = h2[(size_t)t * D + d];
#pragma unroll
    for (int e = 0; e < NE; ++e) p[e] += hv * rw[d * NE + e];
  }
#pragma unroll
  for (int off = 32; off; off >>= 1)
#pragma unroll
    for (int e = 0; e < NE; ++e) p[e] += __shfl_xor(p[e], off);
  if (lane == 0) {
    float mx = p[0];
#pragma unroll
    for (int e = 1; e < NE; ++e) mx = fmaxf(mx, p[e]);
    float ex[NE];
#pragma unroll
    for (int e = 0; e < NE; ++e) ex[e] = __expf(p[e] - mx);
    int e0 = 0;
#pragma unroll
    for (int e = 1; e < NE; ++e) if (ex[e] > ex[e0]) e0 = e;
    int e1 = (e0 == 0) ? 1 : 0;
#pragma unroll
    for (int e = 0; e < NE; ++e) if (e != e0 && ex[e] > ex[e1]) e1 = e;
    float w0 = ex[e0] / (ex[e0] + ex[e1]);
    float w1 = ex[e1] / (ex[e0] + ex[e1]);
    int pos0 = atomicAdd(&counts[e0], 1);
    int pos1 = atomicAdd(&counts[e1], 1);
    tok_list[e0 * S + pos0] = t;
    tok_list[e1 * S + pos1] = t;
    topk_e[2 * t] = e0;  topk_e[2 * t + 1] = e1;
    topk_pos[2 * t] = pos0;  topk_pos[2 * t + 1] = pos1;
    topk_w[2 * t] = w0;  topk_w[2 * t + 1] = w1;
  }
}

__global__ void scan_kernel(const int* counts, int* offsets) {
  if (threadIdx.x == 0) {
    int acc = 0;
    for (int e = 0; e < NE; ++e) { offsets[e] = acc; acc += counts[e]; }
  }
}

// ---------------------------------------------------------------- final add
__global__ void final_kernel(const float* __restrict__ x, const float* __restrict__ sout,
                             const float* __restrict__ eo,
                             const int* __restrict__ topk_e, const int* __restrict__ topk_pos,
                             const float* __restrict__ topk_w, const int* __restrict__ offsets,
                             float* __restrict__ out) {
  int t = blockIdx.x;
  int tid = threadIdx.x;
  int e0 = topk_e[2 * t], e1 = topk_e[2 * t + 1];
  size_t r0 = (size_t)offsets[e0] + topk_pos[2 * t];
  size_t r1 = (size_t)offsets[e1] + topk_pos[2 * t + 1];
  float w0 = topk_w[2 * t], w1 = topk_w[2 * t + 1];
#pragma unroll
  for (int i = 0; i < 4; ++i) {
    int d = tid + i * 256;
    size_t idx = (size_t)t * D + d;
    out[idx] = x[idx] + sout[idx] + w0 * eo[r0 * D + d] + w1 * eo[r1 * D + d];
  }
}

extern "C" void kernel_launch(void* const* d_in, const int* in_sizes, int n_in,
                              void* d_out, int out_size, void* d_ws, size_t ws_size,
                              hipStream_t stream) {
  const float* hidden  = (const float*)d_in[0];
  const float* cosb    = (const float*)d_in[1];
  const float* sinb    = (const float*)d_in[2];
  const float* w_qkv   = (const float*)d_in[3];
  const float* w_o     = (const float*)d_in[4];
  const float* q_norm  = (const float*)d_in[5];
  const float* k_norm  = (const float*)d_in[6];
  const float* in_ln   = (const float*)d_in[7];
  const float* post_ln = (const float*)d_in[8];
  const float* router_w= (const float*)d_in[9];
  const float* w_gate  = (const float*)d_in[10];
  const float* w_up    = (const float*)d_in[11];
  const float* w_down  = (const float*)d_in[12];
  const float* ws_gate = (const float*)d_in[13];
  const float* ws_up   = (const float*)d_in[14];
  const float* ws_down = (const float*)d_in[15];
  float* out = (float*)d_out;
  float* ws = (float*)d_ws;

  typedef __hip_bfloat16 hbf;
  // weights (bf16)
  hbf* wqkvT = (hbf*)(ws);                      // 1.5M el
  hbf* woT   = (hbf*)(ws +  768 * 1024);        // 1M el
  hbf* wgT   = (hbf*)(ws + 1280 * 1024);        // 8M el
  hbf* wuT   = (hbf*)(ws + 5376 * 1024);        // 8M el
  hbf* wdT   = (hbf*)(ws + 9472 * 1024);        // 8M el
  hbf* wsgT  = (hbf*)(ws + 13568 * 1024);       // 1M el
  hbf* wsuT  = (hbf*)(ws + 14080 * 1024);       // 1M el
  hbf* wsdT  = (hbf*)(ws + 14592 * 1024);       // 1M el
  // activations
  hbf*   hb      = (hbf*)(ws + 15104 * 1024);   // [15104K,16128K), dead after qkv GEMM
  float* qkv     = ws + 16128 * 1024;           // [16128K,19200K), dead after v_transpose
  hbf*   qbB     = (hbf*)(ws + 19200 * 1024);   // [19200K,20224K)
  hbf*   kbB     = (hbf*)(ws + 20224 * 1024);   // [20224K,20480K)
  hbf*   vTb     = (hbf*)(ws + 20480 * 1024);   // [20480K,20736K)  V^T [256][2048]
  hbf*   attnb16 = (hbf*)(ws + 20736 * 1024);   // [20736K,21760K)
  float* x       = ws + 22784 * 1024;           // 2M fl (written by wo GEMM, after merge)
  float* h2      = ws + 24832 * 1024;           // 2M fl
  hbf*   h2b     = (hbf*)(ws + 26880 * 1024);   // [26880K,27904K)
  hbf*   act     = (hbf*)(ws + 16128 * 1024);   // 4096x1024 bf16, aliases dead qkv
  float* eo      = ws + 18176 * 1024;           // 4096x1024 fp32, aliases dead q/k/v
  hbf*   sact    = (hbf*)(ws + 27904 * 1024);   // 2048x1024 bf16
  float* sout    = ws + 28928 * 1024;           // 2048x1024 fp32
  // attention partials (live only attn -> merge):
  float* mpart   = ws + 15104 * 1024;           // [2][S][NH]  (aliases dead hb)
  float* lpart   = mpart + 2 * S * NH;
  float* opart0  = ws + 16128 * 1024;           // [S][1024]   (aliases dead qkv)
  float* opart1  = ws + 22784 * 1024;           // [S][1024]   (aliases x, written later)
  int* counts   = (int*)(ws + 30976 * 1024);
  int* offsets  = counts + NE;
  int* tok_list = offsets + NE;
  int* topk_e   = tok_list + NE * S;
  int* topk_pos = topk_e + 2 * S;
  float* topk_w = (float*)(topk_pos + 2 * S);

  dim3 b256(256);
  zero_counts_kernel<<<1, 64, 0, stream>>>(counts);
  transpose_cast_kernel<<<dim3(QKV_N/32, D/32, 1), b256, 0, stream>>>(w_qkv, wqkvT, D, QKV_N);
  transpose_cast_kernel<<<dim3(D/32, D/32, 1),     b256, 0, stream>>>(w_o, woT, D, D);
  transpose_cast_kernel<<<dim3(NI/32, D/32, NE),   b256, 0, stream>>>(w_gate, wgT, D, NI);
  transpose_cast_kernel<<<dim3(NI/32, D/32, NE),   b256, 0, stream>>>(w_up, wuT, D, NI);
  transpose_cast_kernel<<<dim3(D/32, NI/32, NE),   b256, 0, stream>>>(w_down, wdT, NI, D);
  transpose_cast_kernel<<<dim3(NI/32, D/32, 1),    b256, 0, stream>>>(ws_gate, wsgT, D, NI);
  transpose_cast_kernel<<<dim3(NI/32, D/32, 1),    b256, 0, stream>>>(ws_up, wsuT, D, NI);
  transpose_cast_kernel<<<dim3(D/32, NI/32, 1),    b256, 0, stream>>>(ws_down, wsdT, NI, D);
  // attention block
  rmsnorm_kernel<<<S, b256, 0, stream>>>(hidden, in_ln, nullptr, hb);
  mgemm_kernel<<<dim3(QKV_N/128, S/128, 1), b256, 0, stream>>>(hb, wqkvT, nullptr, qkv,
      S, QKV_N, D, nullptr, nullptr, nullptr, 0, nullptr, nullptr, nullptr);
  qkv_post_kernel<<<dim3(S, 5), b256, 0, stream>>>(qkv, q_norm, k_norm, cosb, sinb, qbB, kbB, nullptr);
  v_transpose_kernel<<<dim3(S/32, (NKV*HD)/32), b256, 0, stream>>>(qkv, vTb);
  attn_kernel<<<dim3(S/16, NKV, 2), b256, 0, stream>>>(qbB, kbB, vTb,
      opart0, opart1, mpart, lpart);
  attn_merge_kernel<<<S, b256, 0, stream>>>(opart0, opart1, mpart, lpart, attnb16);
  mgemm_kernel<<<dim3(D/128, S/128, 1), b256, 0, stream>>>(attnb16, woT, hidden, x,
      S, D, D, nullptr, nullptr, nullptr, 0, nullptr, nullptr, nullptr);
  // MoE block (shared expert merged as z == NE)
  rmsnorm_kernel<<<S, b256, 0, stream>>>(x, post_ln, h2, h2b);
  router_kernel<<<S, 64, 0, stream>>>(h2, router_w, counts, tok_list, topk_e, topk_pos, topk_w);
  scan_kernel<<<1, 64, 0, stream>>>(counts, offsets);
  mgemm_gu_kernel<<<dim3(NI/64, S/128, NE + 1), b256, 0, stream>>>(h2b, wgT, wuT, act,
      S, NI, D, counts, offsets, tok_list, wsgT, wsuT, sact);
  mgemm_kernel<<<dim3(D/128, S/128, NE + 1), b256, 0, stream>>>(act, wdT, nullptr, eo,
      S, D, NI, counts, offsets, nullptr, 1, sact, wsdT, sout);
  final_kernel<<<S, b256, 0, stream>>>(x, sout, eo, topk_e, topk_pos, topk_w, offsets, out);
}

// Round 4
// 487.575 us; speedup vs baseline: 1.1579x; 1.0181x over previous
//
#include <hip/hip_runtime.h>
#include <hip/hip_bf16.h>
#include <math.h>

#define S 2048
#define D 1024
#define NH 16
#define NKV 4
#define HD 64
#define QKV_N 1536          // (NH + 2*NKV) * HD
#define NE 8
#define NI 1024
#define EPS 1e-6f

typedef __bf16 bf16_t;
typedef __bf16 __attribute__((may_alias)) abf16;
typedef __attribute__((ext_vector_type(8))) __bf16 bf16x8;
typedef __attribute__((ext_vector_type(4))) float f32x4;
union I4B8 { int4 i; bf16x8 v; bf16_t e[8]; };

// async global->LDS, 16B per lane. LDS dest must be wave-uniform base
// (HW adds lane*16); global src is per-lane.
__device__ __forceinline__ void gll16(const void* g, void* l) {
  __builtin_amdgcn_global_load_lds(
      (const __attribute__((address_space(1))) void*)g,
      (__attribute__((address_space(3))) void*)l, 16, 0, 0);
}

// ---------------------------------------------------------------- rmsnorm(D)
__global__ void rmsnorm_kernel(const float* __restrict__ in, const float* __restrict__ w,
                               float* __restrict__ out32, __hip_bfloat16* __restrict__ out16) {
  int t = blockIdx.x;
  int tid = threadIdx.x;
  const float* row = in + (size_t)t * D;
  float v[4];
  float ss = 0.f;
#pragma unroll
  for (int i = 0; i < 4; ++i) {
    v[i] = row[tid + i * 256];
    ss += v[i] * v[i];
  }
#pragma unroll
  for (int off = 32; off; off >>= 1) ss += __shfl_xor(ss, off);
  __shared__ float wsum[4];
  int wave = tid >> 6;
  if ((tid & 63) == 0) wsum[wave] = ss;
  __syncthreads();
  float tot = wsum[0] + wsum[1] + wsum[2] + wsum[3];
  float r = rsqrtf(tot / (float)D + EPS);
#pragma unroll
  for (int i = 0; i < 4; ++i) {
    int d = tid + i * 256;
    float val = v[i] * r * w[d];
    if (out32) out32[(size_t)t * D + d] = val;
    if (out16) out16[(size_t)t * D + d] = __float2bfloat16(val);
  }
}

// ------------------------------------------- weight transpose + bf16 cast
__global__ void transpose_cast_kernel(const float* __restrict__ W,
                                      __hip_bfloat16* __restrict__ WT, int Kd, int Nd) {
  __shared__ float tile[32][33];
  int e = blockIdx.z;
  const float* Wp = W + (size_t)e * Kd * Nd;
  __hip_bfloat16* WTp = WT + (size_t)e * Kd * Nd;
  int n0 = blockIdx.x * 32, k0 = blockIdx.y * 32;
  int tx = threadIdx.x & 31, ty = threadIdx.x >> 5;
#pragma unroll
  for (int i = 0; i < 4; ++i)
    tile[ty + i * 8][tx] = Wp[(size_t)(k0 + ty + i * 8) * Nd + n0 + tx];
  __syncthreads();
#pragma unroll
  for (int i = 0; i < 4; ++i)
    WTp[(size_t)(n0 + ty + i * 8) * Kd + k0 + tx] = __float2bfloat16(tile[tx][ty + i * 8]);
}

// ------------------------------------------- V transpose (fp32 qkv slice -> bf16 vT[256][2048])
__global__ void v_transpose_kernel(const float* __restrict__ qkv, __hip_bfloat16* __restrict__ vT) {
  __shared__ float tile[32][33];
  int t0 = blockIdx.x * 32;            // token
  int c0 = blockIdx.y * 32;            // v channel (0..255)
  int tx = threadIdx.x & 31, ty = threadIdx.x >> 5;
#pragma unroll
  for (int i = 0; i < 4; ++i)
    tile[ty + i * 8][tx] = qkv[(size_t)(t0 + ty + i * 8) * QKV_N + (NH + NKV) * HD + c0 + tx];
  __syncthreads();
#pragma unroll
  for (int i = 0; i < 4; ++i)
    vT[(size_t)(c0 + ty + i * 8) * S + t0 + tx] = __float2bfloat16(tile[tx][ty + i * 8]);
}

// ------------------------------------------- MFMA bf16 GEMM, 128x128 tile
// m97 structure + double-buffered LDS prefetch: stage(buf^1) issued right after
// the barrier, so HBM/L3 latency hides under ds_read+MFMA of buf. One barrier/K-step.
__global__ __launch_bounds__(256) void mgemm_kernel(
    const __hip_bfloat16* __restrict__ A, const __hip_bfloat16* __restrict__ BT,
    const float* __restrict__ Cadd, float* __restrict__ C,
    int M, int N, int K,
    const int* __restrict__ counts, const int* __restrict__ offsets,
    const int* __restrict__ tok, int a_comp,
    const __hip_bfloat16* __restrict__ As2, const __hip_bfloat16* __restrict__ BTs2,
    float* __restrict__ Cs2) {
  __shared__ __align__(16) bf16_t Asd[2][128 * 32];   // 2 x 8 KB
  __shared__ __align__(16) bf16_t Bsd[2][128 * 32];
  __shared__ int rowmap[128];
  int e = blockIdx.z;
  bool sh = (counts != nullptr) && (e == NE);
  int cnt = sh ? M : (counts ? counts[e] : M);
  int bm = blockIdx.y * 128;
  if (bm >= cnt) return;
  int bn = blockIdx.x * 128;
  int obase = sh ? 0 : (offsets ? offsets[e] : 0);
  const bf16_t* Ab = sh ? (const bf16_t*)As2 : (const bf16_t*)A;
  const bf16_t* BTe = sh ? (const bf16_t*)BTs2 : ((const bf16_t*)BT + (size_t)e * N * K);
  float* Cp = sh ? Cs2 : C;
  const int* toke = (!sh && tok) ? tok + e * S : nullptr;
  int acompe = sh ? 0 : a_comp;
  int tid = threadIdx.x;
  if (tid < 128) {
    int gp = bm + tid;
    int cp = gp < cnt ? gp : cnt - 1;
    rowmap[tid] = toke ? toke[cp] : (acompe ? obase + cp : cp);
  }
  __syncthreads();
  int wave = tid >> 6, lane = tid & 63;
  int quad = lane >> 4, l16 = lane & 15;
  int wm = wave >> 1, wn = wave & 1;
  int srow = tid >> 2, scol = (tid & 3) * 8;
  size_t aoff0 = (size_t)rowmap[srow] * K + scol;
  size_t aoff1 = (size_t)rowmap[64 + srow] * K + scol;
  size_t boff0 = (size_t)(bn + srow) * K + scol;
  size_t boff1 = (size_t)(bn + 64 + srow) * K + scol;
  f32x4 acc[4][4];
#pragma unroll
  for (int i = 0; i < 4; ++i)
#pragma unroll
    for (int j = 0; j < 4; ++j) acc[i][j] = (f32x4){0.f, 0.f, 0.f, 0.f};

  // prologue: stage k0=0 into buf 0
  {
    char* AsB = (char*)Asd[0] + wave * 1024;
    char* BsB = (char*)Bsd[0] + wave * 1024;
    gll16(Ab + aoff0, AsB);
    gll16(Ab + aoff1, AsB + 4096);
    gll16(BTe + boff0, BsB);
    gll16(BTe + boff1, BsB + 4096);
  }
  for (int k0 = 0; k0 < K; k0 += 32) {
    int cur = (k0 >> 5) & 1;
    __syncthreads();                         // buf[cur] staged; prev reads done
    if (k0 + 32 < K) {                       // prefetch next into buf[cur^1]
      char* AsB = (char*)Asd[cur ^ 1] + wave * 1024;
      char* BsB = (char*)Bsd[cur ^ 1] + wave * 1024;
      gll16(Ab + aoff0 + k0 + 32, AsB);
      gll16(Ab + aoff1 + k0 + 32, AsB + 4096);
      gll16(BTe + boff0 + k0 + 32, BsB);
      gll16(BTe + boff1 + k0 + 32, BsB + 4096);
    }
    I4B8 af[4], bfr[4];
#pragma unroll
    for (int i = 0; i < 4; ++i)
      af[i].i = *(const int4*)(Asd[cur] + (wm * 64 + i * 16 + l16) * 32 + quad * 8);
#pragma unroll
    for (int j = 0; j < 4; ++j)
      bfr[j].i = *(const int4*)(Bsd[cur] + (wn * 64 + j * 16 + l16) * 32 + quad * 8);
#pragma unroll
    for (int i = 0; i < 4; ++i)
#pragma unroll
      for (int j = 0; j < 4; ++j)
        acc[i][j] = __builtin_amdgcn_mfma_f32_16x16x32_bf16(af[i].v, bfr[j].v, acc[i][j], 0, 0, 0);
  }
#pragma unroll
  for (int i = 0; i < 4; ++i) {
#pragma unroll
    for (int r = 0; r < 4; ++r) {
      int trow = wm * 64 + i * 16 + quad * 4 + r;
      int gp = bm + trow;
      if (gp < cnt) {
        size_t rowb = (size_t)(obase + gp) * N;
#pragma unroll
        for (int j = 0; j < 4; ++j) {
          int col = bn + wn * 64 + j * 16 + l16;
          size_t idx = rowb + col;
          Cp[idx] = acc[i][j][r] + (Cadd ? Cadd[idx] : 0.f);
        }
      }
    }
  }
}

// ------------------------------------------- dual-B MFMA GEMM + silu, 128x64 tile
// Same double-buffered prefetch structure as mgemm_kernel.
__global__ __launch_bounds__(256) void mgemm_gu_kernel(
    const __hip_bfloat16* __restrict__ A, const __hip_bfloat16* __restrict__ BTg,
    const __hip_bfloat16* __restrict__ BTu, __hip_bfloat16* __restrict__ act,
    int M, int N, int K,
    const int* __restrict__ counts, const int* __restrict__ offsets,
    const int* __restrict__ tok,
    const __hip_bfloat16* __restrict__ BTgs, const __hip_bfloat16* __restrict__ BTus,
    __hip_bfloat16* __restrict__ acts) {
  __shared__ __align__(16) bf16_t Asd[2][128 * 32];   // 2 x 8 KB
  __shared__ __align__(16) bf16_t Bgd[2][64 * 32];    // 2 x 4 KB
  __shared__ __align__(16) bf16_t Bud[2][64 * 32];    // 2 x 4 KB
  __shared__ int rowmap[128];
  int e = blockIdx.z;
  bool sh = (counts != nullptr) && (e == NE);
  int cnt = sh ? M : (counts ? counts[e] : M);
  int bm = blockIdx.y * 128;
  if (bm >= cnt) return;
  int bn = blockIdx.x * 64;
  const bf16_t* Ab = (const bf16_t*)A;
  const bf16_t* Bg = sh ? (const bf16_t*)BTgs : ((const bf16_t*)BTg + (size_t)e * N * K);
  const bf16_t* Bu = sh ? (const bf16_t*)BTus : ((const bf16_t*)BTu + (size_t)e * N * K);
  bf16_t* outp = sh ? (bf16_t*)acts : (bf16_t*)act;
  int obase = sh ? 0 : (offsets ? offsets[e] : 0);
  const int* toke = (!sh && tok) ? tok + e * S : nullptr;
  int tid = threadIdx.x;
  if (tid < 128) {
    int gp = bm + tid;
    int cp = gp < cnt ? gp : cnt - 1;
    rowmap[tid] = toke ? toke[cp] : cp;
  }
  __syncthreads();
  int wave = tid >> 6, lane = tid & 63;
  int quad = lane >> 4, l16 = lane & 15;
  int wm = wave >> 1, wn = wave & 1;
  int srow = tid >> 2, scol = (tid & 3) * 8;
  size_t aoff0 = (size_t)rowmap[srow] * K + scol;
  size_t aoff1 = (size_t)rowmap[64 + srow] * K + scol;
  size_t boff = (size_t)(bn + srow) * K + scol;
  f32x4 accg[4][2], accu[4][2];
#pragma unroll
  for (int i = 0; i < 4; ++i)
#pragma unroll
    for (int j = 0; j < 2; ++j) {
      accg[i][j] = (f32x4){0.f, 0.f, 0.f, 0.f};
      accu[i][j] = (f32x4){0.f, 0.f, 0.f, 0.f};
    }
  // prologue
  {
    char* AsB = (char*)Asd[0] + wave * 1024;
    gll16(Ab + aoff0, AsB);
    gll16(Ab + aoff1, AsB + 4096);
    gll16(Bg + boff, (char*)Bgd[0] + wave * 1024);
    gll16(Bu + boff, (char*)Bud[0] + wave * 1024);
  }
  for (int k0 = 0; k0 < K; k0 += 32) {
    int cur = (k0 >> 5) & 1;
    __syncthreads();
    if (k0 + 32 < K) {
      char* AsB = (char*)Asd[cur ^ 1] + wave * 1024;
      gll16(Ab + aoff0 + k0 + 32, AsB);
      gll16(Ab + aoff1 + k0 + 32, AsB + 4096);
      gll16(Bg + boff + k0 + 32, (char*)Bgd[cur ^ 1] + wave * 1024);
      gll16(Bu + boff + k0 + 32, (char*)Bud[cur ^ 1] + wave * 1024);
    }
    I4B8 af[4], bg[2], bu[2];
#pragma unroll
    for (int i = 0; i < 4; ++i)
      af[i].i = *(const int4*)(Asd[cur] + (wm * 64 + i * 16 + l16) * 32 + quad * 8);
#pragma unroll
    for (int j = 0; j < 2; ++j) {
      bg[j].i = *(const int4*)(Bgd[cur] + (wn * 32 + j * 16 + l16) * 32 + quad * 8);
      bu[j].i = *(const int4*)(Bud[cur] + (wn * 32 + j * 16 + l16) * 32 + quad * 8);
    }
#pragma unroll
    for (int i = 0; i < 4; ++i)
#pragma unroll
      for (int j = 0; j < 2; ++j) {
        accg[i][j] = __builtin_amdgcn_mfma_f32_16x16x32_bf16(af[i].v, bg[j].v, accg[i][j], 0, 0, 0);
        accu[i][j] = __builtin_amdgcn_mfma_f32_16x16x32_bf16(af[i].v, bu[j].v, accu[i][j], 0, 0, 0);
      }
  }
#pragma unroll
  for (int i = 0; i < 4; ++i) {
#pragma unroll
    for (int r = 0; r < 4; ++r) {
      int trow = wm * 64 + i * 16 + quad * 4 + r;
      int gp = bm + trow;
      if (gp < cnt) {
        size_t rowb = (size_t)(obase + gp) * N;
#pragma unroll
        for (int j = 0; j < 2; ++j) {
          int col = bn + wn * 32 + j * 16 + l16;
          float g = accg[i][j][r], uu = accu[i][j][r];
          float sg = g / (1.f + __expf(-g));
          outp[rowb + col] = __float2bfloat16(sg * uu);
        }
      }
    }
  }
}

// --------------------------------------------- q/k head rmsnorm + RoPE + bf16 cast
__global__ void qkv_post_kernel(const float* __restrict__ qkv,
                                const float* __restrict__ qw, const float* __restrict__ kw,
                                const float* __restrict__ cosb, const float* __restrict__ sinb,
                                __hip_bfloat16* __restrict__ qout,
                                __hip_bfloat16* __restrict__ kout,
                                __hip_bfloat16* __restrict__ vout) {
  int t = blockIdx.x;
  int u = blockIdx.y * 4 + (threadIdx.x >> 6);
  int lane = threadIdx.x & 63;
  if (u >= NH + NKV) {
    int h = u - NH - NKV;
    float xv = qkv[(size_t)t * QKV_N + (NH + NKV) * HD + h * HD + lane];
    vout[(size_t)t * (NKV * HD) + h * HD + lane] = __float2bfloat16(xv);
    return;
  }
  bool isq = (u < NH);
  int h = isq ? u : (u - NH);
  size_t src = (size_t)t * QKV_N + (isq ? (h * HD) : (NH * HD + h * HD)) + lane;
  float xv = qkv[src];
  float ss = xv * xv;
#pragma unroll
  for (int off = 32; off; off >>= 1) ss += __shfl_xor(ss, off);
  float r = rsqrtf(ss * (1.f / 64.f) + EPS);
  float xn = xv * r * (isq ? qw[lane] : kw[lane]);
  float other = __shfl_xor(xn, 32);
  float rot = (lane < 32) ? -other : other;
  float res = xn * cosb[t * 64 + lane] + rot * sinb[t * 64 + lane];
  if (isq) qout[(size_t)t * (NH * HD) + h * HD + lane] = __float2bfloat16(res * 0.125f);
  else     kout[(size_t)t * (NKV * HD) + h * HD + lane] = __float2bfloat16(res);
}

// --------------------------------------------- MFMA flash attention v4
// GQA-merged + KV-split-2 (flash-decoding). Block = (16-row q-tile, kv head, chunk z).
// 4 waves = 4 q-heads sharing K/V. T14 async staging (regs loaded one tile ahead).
// l accumulated via ones-column MFMA (no sum shuffles). Partials merged by attn_merge.
__global__ __launch_bounds__(256) void attn_kernel(
    const __hip_bfloat16* __restrict__ qg, const __hip_bfloat16* __restrict__ kg,
    const __hip_bfloat16* __restrict__ vT,
    float* __restrict__ opart0, float* __restrict__ opart1,
    float* __restrict__ mpart, float* __restrict__ lpart) {
  int qt = (int)(gridDim.x - 1) - (int)blockIdx.x;   // heavy tiles first
  int kvh = blockIdx.y;
  int z = blockIdx.z;
  int tid = threadIdx.x;
  int wave = tid >> 6, lane = tid & 63;
  int quad = lane >> 4, l16 = lane & 15;
  int h = kvh * 4 + wave;

  float* opz = z ? opart1 : opart0;
  float* mp = mpart + (size_t)z * S * NH;
  float* lp = lpart + (size_t)z * S * NH;

  int nb = (qt >> 1) + 1;            // valid 32-blocks of kv
  int nt = (nb + 1) >> 1;            // 64-wide tiles
  bool halfm = (nb & 1) != 0;        // last tile only 32 valid
  int h0 = nt >> 1;
  int lo = z ? h0 : 0;
  int hi = z ? nt : h0;

  if (lo >= hi) {                    // empty chunk: zero partials
    int row = qt * 16 + (tid >> 4);
    float* od = opz + (size_t)row * (NH * HD) + kvh * 256 + (tid & 15) * 16;
    int4 zz = {0, 0, 0, 0};
#pragma unroll
    for (int i = 0; i < 4; ++i) *(int4*)(od + i * 4) = zz;
    if (tid < 64) {
      int rr = qt * 16 + (tid >> 2), hh = kvh * 4 + (tid & 3);
      mp[(size_t)rr * NH + hh] = -1e30f;
      lp[(size_t)rr * NH + hh] = 0.f;
    }
    return;
  }

  __shared__ __align__(16) int KsI[64 * 36];         // K tile [64 k][64 d + pad]
  __shared__ __align__(16) int VTI[64 * 36];         // V^T tile [64 d][64 k + pad]
  __shared__ __align__(16) int PsI[4][16 * 36];      // per-wave P [16 q][64 k + pad]

  I4B8 qf[2];
#pragma unroll
  for (int ch = 0; ch < 2; ++ch)
    qf[ch].i = *(const int4*)((const abf16*)qg +
        (size_t)(qt * 16 + l16) * (NH * HD) + h * HD + ch * 32 + quad * 8);

  I4B8 ones;
  ones.i = (int4){0x3F803F80, 0x3F803F80, 0x3F803F80, 0x3F803F80};   // 8x bf16 1.0

  float m_r[4];
  f32x4 o[4], o4;
#pragma unroll
  for (int r = 0; r < 4; ++r) m_r[r] = -1e30f;
#pragma unroll
  for (int sub = 0; sub < 4; ++sub) o[sub] = (f32x4){0.f, 0.f, 0.f, 0.f};
  o4 = (f32x4){0.f, 0.f, 0.f, 0.f};

  int sp = tid >> 3, sc = tid & 7;   // staging: 32 rows x 8 octets (x2 halves)
  const abf16* kb = (const abf16*)kg;
  const abf16* vb = (const abf16*)vT;

  // T14 prologue: load first tile into regs
  int4 rk0 = *(const int4*)(kb + (size_t)(lo * 64 + sp) * (NKV * HD) + kvh * HD + sc * 8);
  int4 rk1 = *(const int4*)(kb + (size_t)(lo * 64 + 32 + sp) * (NKV * HD) + kvh * HD + sc * 8);
  int4 rv0 = *(const int4*)(vb + (size_t)(kvh * HD + sp) * S + lo * 64 + sc * 8);
  int4 rv1 = *(const int4*)(vb + (size_t)(kvh * HD + 32 + sp) * S + lo * 64 + sc * 8);

  for (int kc = lo; kc < hi; ++kc) {
    // ---- write staged regs to LDS (prev compute done via loop-bottom barrier)
    *(int4*)&KsI[sp * 36 + sc * 4] = rk0;
    *(int4*)&KsI[(sp + 32) * 36 + sc * 4] = rk1;
    *(int4*)&VTI[sp * 36 + sc * 4] = rv0;
    *(int4*)&VTI[(sp + 32) * 36 + sc * 4] = rv1;
    __syncthreads();

    // ---- issue next tile loads (latency hides under compute below)
    if (kc + 1 < hi) {
      rk0 = *(const int4*)(kb + (size_t)((kc + 1) * 64 + sp) * (NKV * HD) + kvh * HD + sc * 8);
      rk1 = *(const int4*)(kb + (size_t)((kc + 1) * 64 + 32 + sp) * (NKV * HD) + kvh * HD + sc * 8);
      rv0 = *(const int4*)(vb + (size_t)(kvh * HD + sp) * S + (kc + 1) * 64 + sc * 8);
      rv1 = *(const int4*)(vb + (size_t)(kvh * HD + 32 + sp) * S + (kc + 1) * 64 + sc * 8);
    }

    // ---- QK^T: 16 q-rows x 64 k
    f32x4 s[4];
#pragma unroll
    for (int sub = 0; sub < 4; ++sub) s[sub] = (f32x4){0.f, 0.f, 0.f, 0.f};
    __builtin_amdgcn_s_setprio(1);
#pragma unroll
    for (int sub = 0; sub < 4; ++sub)
#pragma unroll
      for (int ch = 0; ch < 2; ++ch) {
        I4B8 ku;
        ku.i = *(const int4*)&KsI[(sub * 16 + l16) * 36 + ch * 16 + quad * 4];
        s[sub] = __builtin_amdgcn_mfma_f32_16x16x32_bf16(qf[ch].v, ku.v, s[sub], 0, 0, 0);
      }
    __builtin_amdgcn_s_setprio(0);
    if (halfm && kc == nt - 1) {
#pragma unroll
      for (int r = 0; r < 4; ++r) { s[2][r] = -1e30f; s[3][r] = -1e30f; }
    }

    // ---- online softmax: max-reduce + exp; sums come from ones-MFMA
    abf16* pw = (abf16*)PsI[wave];
#pragma unroll
    for (int r = 0; r < 4; ++r) {
      float v = fmaxf(fmaxf(s[0][r], s[1][r]), fmaxf(s[2][r], s[3][r]));
#pragma unroll
      for (int off = 1; off < 16; off <<= 1) v = fmaxf(v, __shfl_xor(v, off));
      float mx = fmaxf(m_r[r], v);
      float al = __expf(m_r[r] - mx);
      m_r[r] = mx;
      float p0 = __expf(s[0][r] - mx);
      float p1 = __expf(s[1][r] - mx);
      float p2 = __expf(s[2][r] - mx);
      float p3 = __expf(s[3][r] - mx);
      int prow = quad * 4 + r;
      pw[prow * 72 + l16]      = (bf16_t)p0;
      pw[prow * 72 + 16 + l16] = (bf16_t)p1;
      pw[prow * 72 + 32 + l16] = (bf16_t)p2;
      pw[prow * 72 + 48 + l16] = (bf16_t)p3;
      o4[r] *= al;
#pragma unroll
      for (int sub = 0; sub < 4; ++sub) o[sub][r] *= al;
    }

    // ---- PV: P(16x64) x V(64x64) + ones-column for row sums
    I4B8 pu[2];
#pragma unroll
    for (int ch = 0; ch < 2; ++ch)
      pu[ch].i = *(const int4*)&PsI[wave][l16 * 36 + ch * 16 + quad * 4];
    __builtin_amdgcn_s_setprio(1);
#pragma unroll
    for (int sub = 0; sub < 4; ++sub)
#pragma unroll
      for (int ch = 0; ch < 2; ++ch) {
        I4B8 vf;
        vf.i = *(const int4*)&VTI[(sub * 16 + l16) * 36 + ch * 16 + quad * 4];
        o[sub] = __builtin_amdgcn_mfma_f32_16x16x32_bf16(pu[ch].v, vf.v, o[sub], 0, 0, 0);
      }
#pragma unroll
    for (int ch = 0; ch < 2; ++ch)
      o4 = __builtin_amdgcn_mfma_f32_16x16x32_bf16(pu[ch].v, ones.v, o4, 0, 0, 0);
    __builtin_amdgcn_s_setprio(0);
    __syncthreads();
  }

  // epilogue: write raw partials (normalize at merge)
#pragma unroll
  for (int r = 0; r < 4; ++r) {
    int row = qt * 16 + quad * 4 + r;
    float* od = opz + (size_t)row * (NH * HD) + h * HD;
#pragma unroll
    for (int sub = 0; sub < 4; ++sub)
      od[sub * 16 + l16] = o[sub][r];
    if (l16 == 0) {
      mp[(size_t)row * NH + h] = m_r[r];
      lp[(size_t)row * NH + h] = o4[r];
    }
  }
}

// --------------------------------------------- merge KV-split partials
__global__ void attn_merge_kernel(const float* __restrict__ opart0,
                                  const float* __restrict__ opart1,
                                  const float* __restrict__ mpart,
                                  const float* __restrict__ lpart,
                                  __hip_bfloat16* __restrict__ attn) {
  int row = blockIdx.x;
  int tid = threadIdx.x;
#pragma unroll
  for (int i = 0; i < 4; ++i) {
    int c = tid + i * 256;
    int h = c >> 6;
    float m0 = mpart[(size_t)row * NH + h];
    float m1 = mpart[(size_t)(S + row) * NH + h];
    float l0 = lpart[(size_t)row * NH + h];
    float l1 = lpart[(size_t)(S + row) * NH + h];
    float M = fmaxf(m0, m1);
    float a0 = __expf(m0 - M), a1 = __expf(m1 - M);
    float l = l0 * a0 + l1 * a1;
    float v = (opart0[(size_t)row * (NH * HD) + c] * a0 +
               opart1[(size_t)row * (NH * HD) + c] * a1) / l;
    attn[(size_t)row * (NH * HD) + c] = __float2bfloat16(v);
  }
}

// ---------------------------------------------------------------- router
__global__ void zero_counts_kernel(int* counts) {
  if (threadIdx.x < NE) counts[threadIdx.x] = 0;
}

__global__ void router_kernel(const float* __restrict__ h2, const float* __restrict__ rw,
                              int* counts, int* tok_list, int* topk_e, int* topk_pos,
                              float* topk_w) {
  int t = blockIdx.x;
  int lane = threadIdx.x;   // 64
  float p[NE] = {};
  for (int d = lane; d < D; d += 64) {
    float hv = h2[(size_t)t * D + d];
#pragma unroll
    for (int e = 0; e < NE; ++e) p[e] += hv * rw[d * NE + e];
  }
#pragma unroll
  for (int off = 32; off; off >>= 1)
#pragma unroll
    for (int e = 0; e < NE; ++e) p[e] += __shfl_xor(p[e], off);
  if (lane == 0) {
    float mx = p[0];
#pragma unroll
    for (int e = 1; e < NE; ++e) mx = fmaxf(mx, p[e]);
    float ex[NE];
#pragma unroll
    for (int e = 0; e < NE; ++e) ex[e] = __expf(p[e] - mx);
    int e0 = 0;
#pragma unroll
    for (int e = 1; e < NE; ++e) if (ex[e] > ex[e0]) e0 = e;
    int e1 = (e0 == 0) ? 1 : 0;
#pragma unroll
    for (int e = 0; e < NE; ++e) if (e != e0 && ex[e] > ex[e1]) e1 = e;
    float w0 = ex[e0] / (ex[e0] + ex[e1]);
    float w1 = ex[e1] / (ex[e0] + ex[e1]);
    int pos0 = atomicAdd(&counts[e0], 1);
    int pos1 = atomicAdd(&counts[e1], 1);
    tok_list[e0 * S + pos0] = t;
    tok_list[e1 * S + pos1] = t;
    topk_e[2 * t] = e0;  topk_e[2 * t + 1] = e1;
    topk_pos[2 * t] = pos0;  topk_pos[2 * t + 1] = pos1;
    topk_w[2 * t] = w0;  topk_w[2 * t + 1] = w1;
  }
}

__global__ void scan_kernel(const int* counts, int* offsets) {
  if (threadIdx.x == 0) {
    int acc = 0;
    for (int e = 0; e < NE; ++e) { offsets[e] = acc; acc += counts[e]; }
  }
}

// ---------------------------------------------------------------- final add
__global__ void final_kernel(const float* __restrict__ x, const float* __restrict__ sout,
                             const float* __restrict__ eo,
                             const int* __restrict__ topk_e, const int* __restrict__ topk_pos,
                             const float* __restrict__ topk_w, const int* __restrict__ offsets,
                             float* __restrict__ out) {
  int t = blockIdx.x;
  int tid = threadIdx.x;
  int e0 = topk_e[2 * t], e1 = topk_e[2 * t + 1];
  size_t r0 = (size_t)offsets[e0] + topk_pos[2 * t];
  size_t r1 = (size_t)offsets[e1] + topk_pos[2 * t + 1];
  float w0 = topk_w[2 * t], w1 = topk_w[2 * t + 1];
#pragma unroll
  for (int i = 0; i < 4; ++i) {
    int d = tid + i * 256;
    size_t idx = (size_t)t * D + d;
    out[idx] = x[idx] + sout[idx] + w0 * eo[r0 * D + d] + w1 * eo[r1 * D + d];
  }
}

extern "C" void kernel_launch(void* const* d_in, const int* in_sizes, int n_in,
                              void* d_out, int out_size, void* d_ws, size_t ws_size,
                              hipStream_t stream) {
  const float* hidden  = (const float*)d_in[0];
  const float* cosb    = (const float*)d_in[1];
  const float* sinb    = (const float*)d_in[2];
  const float* w_qkv   = (const float*)d_in[3];
  const float* w_o     = (const float*)d_in[4];
  const float* q_norm  = (const float*)d_in[5];
  const float* k_norm  = (const float*)d_in[6];
  const float* in_ln   = (const float*)d_in[7];
  const float* post_ln = (const float*)d_in[8];
  const float* router_w= (const float*)d_in[9];
  const float* w_gate  = (const float*)d_in[10];
  const float* w_up    = (const float*)d_in[11];
  const float* w_down  = (const float*)d_in[12];
  const float* ws_gate = (const float*)d_in[13];
  const float* ws_up   = (const float*)d_in[14];
  const float* ws_down = (const float*)d_in[15];
  float* out = (float*)d_out;
  float* ws = (float*)d_ws;

  typedef __hip_bfloat16 hbf;
  // weights (bf16)
  hbf* wqkvT = (hbf*)(ws);                      // 1.5M el
  hbf* woT   = (hbf*)(ws +  768 * 1024);        // 1M el
  hbf* wgT   = (hbf*)(ws + 1280 * 1024);        // 8M el
  hbf* wuT   = (hbf*)(ws + 5376 * 1024);        // 8M el
  hbf* wdT   = (hbf*)(ws + 9472 * 1024);        // 8M el
  hbf* wsgT  = (hbf*)(ws + 13568 * 1024);       // 1M el
  hbf* wsuT  = (hbf*)(ws + 14080 * 1024);       // 1M el
  hbf* wsdT  = (hbf*)(ws + 14592 * 1024);       // 1M el
  // activations
  hbf*   hb      = (hbf*)(ws + 15104 * 1024);   // [15104K,16128K), dead after qkv GEMM
  float* qkv     = ws + 16128 * 1024;           // [16128K,19200K), dead after v_transpose
  hbf*   qbB     = (hbf*)(ws + 19200 * 1024);   // [19200K,20224K)
  hbf*   kbB     = (hbf*)(ws + 20224 * 1024);   // [20224K,20480K)
  hbf*   vTb     = (hbf*)(ws + 20480 * 1024);   // [20480K,20736K)  V^T [256][2048]
  hbf*   attnb16 = (hbf*)(ws + 20736 * 1024);   // [20736K,21760K)
  float* x       = ws + 22784 * 1024;           // 2M fl (written by wo GEMM, after merge)
  float* h2      = ws + 24832 * 1024;           // 2M fl
  hbf*   h2b     = (hbf*)(ws + 26880 * 1024);   // [26880K,27904K)
  hbf*   act     = (hbf*)(ws + 16128 * 1024);   // 4096x1024 bf16, aliases dead qkv
  float* eo      = ws + 18176 * 1024;           // 4096x1024 fp32, aliases dead q/k/v
  hbf*   sact    = (hbf*)(ws + 27904 * 1024);   // 2048x1024 bf16
  float* sout    = ws + 28928 * 1024;           // 2048x1024 fp32
  // attention partials (live only attn -> merge):
  float* mpart   = ws + 15104 * 1024;           // [2][S][NH]  (aliases dead hb)
  float* lpart   = mpart + 2 * S * NH;
  float* opart0  = ws + 16128 * 1024;           // [S][1024]   (aliases dead qkv)
  float* opart1  = ws + 22784 * 1024;           // [S][1024]   (aliases x, written later)
  int* counts   = (int*)(ws + 30976 * 1024);
  int* offsets  = counts + NE;
  int* tok_list = offsets + NE;
  int* topk_e   = tok_list + NE * S;
  int* topk_pos = topk_e + 2 * S;
  float* topk_w = (float*)(topk_pos + 2 * S);

  dim3 b256(256);
  zero_counts_kernel<<<1, 64, 0, stream>>>(counts);
  transpose_cast_kernel<<<dim3(QKV_N/32, D/32, 1), b256, 0, stream>>>(w_qkv, wqkvT, D, QKV_N);
  transpose_cast_kernel<<<dim3(D/32, D/32, 1),     b256, 0, stream>>>(w_o, woT, D, D);
  transpose_cast_kernel<<<dim3(NI/32, D/32, NE),   b256, 0, stream>>>(w_gate, wgT, D, NI);
  transpose_cast_kernel<<<dim3(NI/32, D/32, NE),   b256, 0, stream>>>(w_up, wuT, D, NI);
  transpose_cast_kernel<<<dim3(D/32, NI/32, NE),   b256, 0, stream>>>(w_down, wdT, NI, D);
  transpose_cast_kernel<<<dim3(NI/32, D/32, 1),    b256, 0, stream>>>(ws_gate, wsgT, D, NI);
  transpose_cast_kernel<<<dim3(NI/32, D/32, 1),    b256, 0, stream>>>(ws_up, wsuT, D, NI);
  transpose_cast_kernel<<<dim3(D/32, NI/32, 1),    b256, 0, stream>>>(ws_down, wsdT, NI, D);
  // attention block
  rmsnorm_kernel<<<S, b256, 0, stream>>>(hidden, in_ln, nullptr, hb);
  mgemm_kernel<<<dim3(QKV_N/128, S/128, 1), b256, 0, stream>>>(hb, wqkvT, nullptr, qkv,
      S, QKV_N, D, nullptr, nullptr, nullptr, 0, nullptr, nullptr, nullptr);
  qkv_post_kernel<<<dim3(S, 5), b256, 0, stream>>>(qkv, q_norm, k_norm, cosb, sinb, qbB, kbB, nullptr);
  v_transpose_kernel<<<dim3(S/32, (NKV*HD)/32), b256, 0, stream>>>(qkv, vTb);
  attn_kernel<<<dim3(S/16, NKV, 2), b256, 0, stream>>>(qbB, kbB, vTb,
      opart0, opart1, mpart, lpart);
  attn_merge_kernel<<<S, b256, 0, stream>>>(opart0, opart1, mpart, lpart, attnb16);
  mgemm_kernel<<<dim3(D/128, S/128, 1), b256, 0, stream>>>(attnb16, woT, hidden, x,
      S, D, D, nullptr, nullptr, nullptr, 0, nullptr, nullptr, nullptr);
  // MoE block (shared expert merged as z == NE)
  rmsnorm_kernel<<<S, b256, 0, stream>>>(x, post_ln, h2, h2b);
  router_kernel<<<S, 64, 0, stream>>>(h2, router_w, counts, tok_list, topk_e, topk_pos, topk_w);
  scan_kernel<<<1, 64, 0, stream>>>(counts, offsets);
  mgemm_gu_kernel<<<dim3(NI/64, S/128, NE + 1), b256, 0, stream>>>(h2b, wgT, wuT, act,
      S, NI, D, counts, offsets, tok_list, wsgT, wsuT, sact);
  mgemm_kernel<<<dim3(D/128, S/128, NE + 1), b256, 0, stream>>>(act, wdT, nullptr, eo,
      S, D, NI, counts, offsets, nullptr, 1, sact, wsdT, sout);
  final_kernel<<<S, b256, 0, stream>>>(x, sout, eo, topk_e, topk_pos, topk_w, offsets, out);
}

// Round 5
// 444.765 us; speedup vs baseline: 1.2693x; 1.0963x over previous
//
#include <hip/hip_runtime.h>
#include <hip/hip_bf16.h>
#include <math.h>

#define S 2048
#define D 1024
#define NH 16
#define NKV 4
#define HD 64
#define QKV_N 1536          // (NH + 2*NKV) * HD
#define NE 8
#define NI 1024
#define EPS 1e-6f

typedef __bf16 bf16_t;
typedef __bf16 __attribute__((may_alias)) abf16;
typedef __attribute__((ext_vector_type(8))) __bf16 bf16x8;
typedef __attribute__((ext_vector_type(4))) float f32x4;
union I4B8 { int4 i; bf16x8 v; bf16_t e[8]; };

// async global->LDS, 16B per lane. LDS dest must be wave-uniform base
// (HW adds lane*16); global src is per-lane.
__device__ __forceinline__ void gll16(const void* g, void* l) {
  __builtin_amdgcn_global_load_lds(
      (const __attribute__((address_space(1))) void*)g,
      (__attribute__((address_space(3))) void*)l, 16, 0, 0);
}

// ---------------------------------------------------------------- rmsnorm(D)
__global__ void rmsnorm_kernel(const float* __restrict__ in, const float* __restrict__ w,
                               float* __restrict__ out32, __hip_bfloat16* __restrict__ out16) {
  int t = blockIdx.x;
  int tid = threadIdx.x;
  const float* row = in + (size_t)t * D;
  float v[4];
  float ss = 0.f;
#pragma unroll
  for (int i = 0; i < 4; ++i) {
    v[i] = row[tid + i * 256];
    ss += v[i] * v[i];
  }
#pragma unroll
  for (int off = 32; off; off >>= 1) ss += __shfl_xor(ss, off);
  __shared__ float wsum[4];
  int wave = tid >> 6;
  if ((tid & 63) == 0) wsum[wave] = ss;
  __syncthreads();
  float tot = wsum[0] + wsum[1] + wsum[2] + wsum[3];
  float r = rsqrtf(tot / (float)D + EPS);
#pragma unroll
  for (int i = 0; i < 4; ++i) {
    int d = tid + i * 256;
    float val = v[i] * r * w[d];
    if (out32) out32[(size_t)t * D + d] = val;
    if (out16) out16[(size_t)t * D + d] = __float2bfloat16(val);
  }
}

// ------------------------------------------- weight transpose + bf16 cast
__global__ void transpose_cast_kernel(const float* __restrict__ W,
                                      __hip_bfloat16* __restrict__ WT, int Kd, int Nd) {
  __shared__ float tile[32][33];
  int e = blockIdx.z;
  const float* Wp = W + (size_t)e * Kd * Nd;
  __hip_bfloat16* WTp = WT + (size_t)e * Kd * Nd;
  int n0 = blockIdx.x * 32, k0 = blockIdx.y * 32;
  int tx = threadIdx.x & 31, ty = threadIdx.x >> 5;
#pragma unroll
  for (int i = 0; i < 4; ++i)
    tile[ty + i * 8][tx] = Wp[(size_t)(k0 + ty + i * 8) * Nd + n0 + tx];
  __syncthreads();
#pragma unroll
  for (int i = 0; i < 4; ++i)
    WTp[(size_t)(n0 + ty + i * 8) * Kd + k0 + tx] = __float2bfloat16(tile[tx][ty + i * 8]);
}

// ------------------------------------------- V transpose (fp32 qkv slice -> bf16 vT[256][2048])
__global__ void v_transpose_kernel(const float* __restrict__ qkv, __hip_bfloat16* __restrict__ vT) {
  __shared__ float tile[32][33];
  int t0 = blockIdx.x * 32;            // token
  int c0 = blockIdx.y * 32;            // v channel (0..255)
  int tx = threadIdx.x & 31, ty = threadIdx.x >> 5;
#pragma unroll
  for (int i = 0; i < 4; ++i)
    tile[ty + i * 8][tx] = qkv[(size_t)(t0 + ty + i * 8) * QKV_N + (NH + NKV) * HD + c0 + tx];
  __syncthreads();
#pragma unroll
  for (int i = 0; i < 4; ++i)
    vT[(size_t)(c0 + ty + i * 8) * S + t0 + tx] = __float2bfloat16(tile[tx][ty + i * 8]);
}

// ------------------------------------------- MFMA bf16 GEMM, 128x128 tile
// m97 structure + double-buffered LDS prefetch: stage(buf^1) issued right after
// the barrier, so HBM/L3 latency hides under ds_read+MFMA of buf. One barrier/K-step.
__global__ __launch_bounds__(256) void mgemm_kernel(
    const __hip_bfloat16* __restrict__ A, const __hip_bfloat16* __restrict__ BT,
    const float* __restrict__ Cadd, float* __restrict__ C,
    int M, int N, int K,
    const int* __restrict__ counts, const int* __restrict__ offsets,
    const int* __restrict__ tok, int a_comp,
    const __hip_bfloat16* __restrict__ As2, const __hip_bfloat16* __restrict__ BTs2,
    float* __restrict__ Cs2) {
  __shared__ __align__(16) bf16_t Asd[2][128 * 32];   // 2 x 8 KB
  __shared__ __align__(16) bf16_t Bsd[2][128 * 32];
  __shared__ int rowmap[128];
  int e = blockIdx.z;
  bool sh = (counts != nullptr) && (e == NE);
  int cnt = sh ? M : (counts ? counts[e] : M);
  int bm = blockIdx.y * 128;
  if (bm >= cnt) return;
  int bn = blockIdx.x * 128;
  int obase = sh ? 0 : (offsets ? offsets[e] : 0);
  const bf16_t* Ab = sh ? (const bf16_t*)As2 : (const bf16_t*)A;
  const bf16_t* BTe = sh ? (const bf16_t*)BTs2 : ((const bf16_t*)BT + (size_t)e * N * K);
  float* Cp = sh ? Cs2 : C;
  const int* toke = (!sh && tok) ? tok + e * S : nullptr;
  int acompe = sh ? 0 : a_comp;
  int tid = threadIdx.x;
  if (tid < 128) {
    int gp = bm + tid;
    int cp = gp < cnt ? gp : cnt - 1;
    rowmap[tid] = toke ? toke[cp] : (acompe ? obase + cp : cp);
  }
  __syncthreads();
  int wave = tid >> 6, lane = tid & 63;
  int quad = lane >> 4, l16 = lane & 15;
  int wm = wave >> 1, wn = wave & 1;
  int srow = tid >> 2, scol = (tid & 3) * 8;
  size_t aoff0 = (size_t)rowmap[srow] * K + scol;
  size_t aoff1 = (size_t)rowmap[64 + srow] * K + scol;
  size_t boff0 = (size_t)(bn + srow) * K + scol;
  size_t boff1 = (size_t)(bn + 64 + srow) * K + scol;
  f32x4 acc[4][4];
#pragma unroll
  for (int i = 0; i < 4; ++i)
#pragma unroll
    for (int j = 0; j < 4; ++j) acc[i][j] = (f32x4){0.f, 0.f, 0.f, 0.f};

  // prologue: stage k0=0 into buf 0
  {
    char* AsB = (char*)Asd[0] + wave * 1024;
    char* BsB = (char*)Bsd[0] + wave * 1024;
    gll16(Ab + aoff0, AsB);
    gll16(Ab + aoff1, AsB + 4096);
    gll16(BTe + boff0, BsB);
    gll16(BTe + boff1, BsB + 4096);
  }
  for (int k0 = 0; k0 < K; k0 += 32) {
    int cur = (k0 >> 5) & 1;
    __syncthreads();                         // buf[cur] staged; prev reads done
    if (k0 + 32 < K) {                       // prefetch next into buf[cur^1]
      char* AsB = (char*)Asd[cur ^ 1] + wave * 1024;
      char* BsB = (char*)Bsd[cur ^ 1] + wave * 1024;
      gll16(Ab + aoff0 + k0 + 32, AsB);
      gll16(Ab + aoff1 + k0 + 32, AsB + 4096);
      gll16(BTe + boff0 + k0 + 32, BsB);
      gll16(BTe + boff1 + k0 + 32, BsB + 4096);
    }
    I4B8 af[4], bfr[4];
#pragma unroll
    for (int i = 0; i < 4; ++i)
      af[i].i = *(const int4*)(Asd[cur] + (wm * 64 + i * 16 + l16) * 32 + quad * 8);
#pragma unroll
    for (int j = 0; j < 4; ++j)
      bfr[j].i = *(const int4*)(Bsd[cur] + (wn * 64 + j * 16 + l16) * 32 + quad * 8);
#pragma unroll
    for (int i = 0; i < 4; ++i)
#pragma unroll
      for (int j = 0; j < 4; ++j)
        acc[i][j] = __builtin_amdgcn_mfma_f32_16x16x32_bf16(af[i].v, bfr[j].v, acc[i][j], 0, 0, 0);
  }
#pragma unroll
  for (int i = 0; i < 4; ++i) {
#pragma unroll
    for (int r = 0; r < 4; ++r) {
      int trow = wm * 64 + i * 16 + quad * 4 + r;
      int gp = bm + trow;
      if (gp < cnt) {
        size_t rowb = (size_t)(obase + gp) * N;
#pragma unroll
        for (int j = 0; j < 4; ++j) {
          int col = bn + wn * 64 + j * 16 + l16;
          size_t idx = rowb + col;
          Cp[idx] = acc[i][j][r] + (Cadd ? Cadd[idx] : 0.f);
        }
      }
    }
  }
}

// ------------------------------------------- dual-B MFMA GEMM + silu, 128x64 tile
// Same double-buffered prefetch structure as mgemm_kernel.
__global__ __launch_bounds__(256) void mgemm_gu_kernel(
    const __hip_bfloat16* __restrict__ A, const __hip_bfloat16* __restrict__ BTg,
    const __hip_bfloat16* __restrict__ BTu, __hip_bfloat16* __restrict__ act,
    int M, int N, int K,
    const int* __restrict__ counts, const int* __restrict__ offsets,
    const int* __restrict__ tok,
    const __hip_bfloat16* __restrict__ BTgs, const __hip_bfloat16* __restrict__ BTus,
    __hip_bfloat16* __restrict__ acts) {
  __shared__ __align__(16) bf16_t Asd[2][128 * 32];   // 2 x 8 KB
  __shared__ __align__(16) bf16_t Bgd[2][64 * 32];    // 2 x 4 KB
  __shared__ __align__(16) bf16_t Bud[2][64 * 32];    // 2 x 4 KB
  __shared__ int rowmap[128];
  int e = blockIdx.z;
  bool sh = (counts != nullptr) && (e == NE);
  int cnt = sh ? M : (counts ? counts[e] : M);
  int bm = blockIdx.y * 128;
  if (bm >= cnt) return;
  int bn = blockIdx.x * 64;
  const bf16_t* Ab = (const bf16_t*)A;
  const bf16_t* Bg = sh ? (const bf16_t*)BTgs : ((const bf16_t*)BTg + (size_t)e * N * K);
  const bf16_t* Bu = sh ? (const bf16_t*)BTus : ((const bf16_t*)BTu + (size_t)e * N * K);
  bf16_t* outp = sh ? (bf16_t*)acts : (bf16_t*)act;
  int obase = sh ? 0 : (offsets ? offsets[e] : 0);
  const int* toke = (!sh && tok) ? tok + e * S : nullptr;
  int tid = threadIdx.x;
  if (tid < 128) {
    int gp = bm + tid;
    int cp = gp < cnt ? gp : cnt - 1;
    rowmap[tid] = toke ? toke[cp] : cp;
  }
  __syncthreads();
  int wave = tid >> 6, lane = tid & 63;
  int quad = lane >> 4, l16 = lane & 15;
  int wm = wave >> 1, wn = wave & 1;
  int srow = tid >> 2, scol = (tid & 3) * 8;
  size_t aoff0 = (size_t)rowmap[srow] * K + scol;
  size_t aoff1 = (size_t)rowmap[64 + srow] * K + scol;
  size_t boff = (size_t)(bn + srow) * K + scol;
  f32x4 accg[4][2], accu[4][2];
#pragma unroll
  for (int i = 0; i < 4; ++i)
#pragma unroll
    for (int j = 0; j < 2; ++j) {
      accg[i][j] = (f32x4){0.f, 0.f, 0.f, 0.f};
      accu[i][j] = (f32x4){0.f, 0.f, 0.f, 0.f};
    }
  // prologue
  {
    char* AsB = (char*)Asd[0] + wave * 1024;
    gll16(Ab + aoff0, AsB);
    gll16(Ab + aoff1, AsB + 4096);
    gll16(Bg + boff, (char*)Bgd[0] + wave * 1024);
    gll16(Bu + boff, (char*)Bud[0] + wave * 1024);
  }
  for (int k0 = 0; k0 < K; k0 += 32) {
    int cur = (k0 >> 5) & 1;
    __syncthreads();
    if (k0 + 32 < K) {
      char* AsB = (char*)Asd[cur ^ 1] + wave * 1024;
      gll16(Ab + aoff0 + k0 + 32, AsB);
      gll16(Ab + aoff1 + k0 + 32, AsB + 4096);
      gll16(Bg + boff + k0 + 32, (char*)Bgd[cur ^ 1] + wave * 1024);
      gll16(Bu + boff + k0 + 32, (char*)Bud[cur ^ 1] + wave * 1024);
    }
    I4B8 af[4], bg[2], bu[2];
#pragma unroll
    for (int i = 0; i < 4; ++i)
      af[i].i = *(const int4*)(Asd[cur] + (wm * 64 + i * 16 + l16) * 32 + quad * 8);
#pragma unroll
    for (int j = 0; j < 2; ++j) {
      bg[j].i = *(const int4*)(Bgd[cur] + (wn * 32 + j * 16 + l16) * 32 + quad * 8);
      bu[j].i = *(const int4*)(Bud[cur] + (wn * 32 + j * 16 + l16) * 32 + quad * 8);
    }
#pragma unroll
    for (int i = 0; i < 4; ++i)
#pragma unroll
      for (int j = 0; j < 2; ++j) {
        accg[i][j] = __builtin_amdgcn_mfma_f32_16x16x32_bf16(af[i].v, bg[j].v, accg[i][j], 0, 0, 0);
        accu[i][j] = __builtin_amdgcn_mfma_f32_16x16x32_bf16(af[i].v, bu[j].v, accu[i][j], 0, 0, 0);
      }
  }
#pragma unroll
  for (int i = 0; i < 4; ++i) {
#pragma unroll
    for (int r = 0; r < 4; ++r) {
      int trow = wm * 64 + i * 16 + quad * 4 + r;
      int gp = bm + trow;
      if (gp < cnt) {
        size_t rowb = (size_t)(obase + gp) * N;
#pragma unroll
        for (int j = 0; j < 2; ++j) {
          int col = bn + wn * 32 + j * 16 + l16;
          float g = accg[i][j][r], uu = accu[i][j][r];
          float sg = g / (1.f + __expf(-g));
          outp[rowb + col] = __float2bfloat16(sg * uu);
        }
      }
    }
  }
}

// --------------------------------------------- q/k head rmsnorm + RoPE + bf16 cast
__global__ void qkv_post_kernel(const float* __restrict__ qkv,
                                const float* __restrict__ qw, const float* __restrict__ kw,
                                const float* __restrict__ cosb, const float* __restrict__ sinb,
                                __hip_bfloat16* __restrict__ qout,
                                __hip_bfloat16* __restrict__ kout,
                                __hip_bfloat16* __restrict__ vout) {
  int t = blockIdx.x;
  int u = blockIdx.y * 4 + (threadIdx.x >> 6);
  int lane = threadIdx.x & 63;
  if (u >= NH + NKV) {
    int h = u - NH - NKV;
    float xv = qkv[(size_t)t * QKV_N + (NH + NKV) * HD + h * HD + lane];
    vout[(size_t)t * (NKV * HD) + h * HD + lane] = __float2bfloat16(xv);
    return;
  }
  bool isq = (u < NH);
  int h = isq ? u : (u - NH);
  size_t src = (size_t)t * QKV_N + (isq ? (h * HD) : (NH * HD + h * HD)) + lane;
  float xv = qkv[src];
  float ss = xv * xv;
#pragma unroll
  for (int off = 32; off; off >>= 1) ss += __shfl_xor(ss, off);
  float r = rsqrtf(ss * (1.f / 64.f) + EPS);
  float xn = xv * r * (isq ? qw[lane] : kw[lane]);
  float other = __shfl_xor(xn, 32);
  float rot = (lane < 32) ? -other : other;
  float res = xn * cosb[t * 64 + lane] + rot * sinb[t * 64 + lane];
  if (isq) qout[(size_t)t * (NH * HD) + h * HD + lane] = __float2bfloat16(res * 0.125f);
  else     kout[(size_t)t * (NKV * HD) + h * HD + lane] = __float2bfloat16(res);
}

// --------------------------------------------- MFMA flash attention v4
// GQA-merged + KV-split-2 (flash-decoding). Block = (16-row q-tile, kv head, chunk z).
// 4 waves = 4 q-heads sharing K/V. T14 async staging (regs loaded one tile ahead).
// l accumulated via ones-column MFMA (no sum shuffles). Partials merged by attn_merge.
__global__ __launch_bounds__(256) void attn_kernel(
    const __hip_bfloat16* __restrict__ qg, const __hip_bfloat16* __restrict__ kg,
    const __hip_bfloat16* __restrict__ vT,
    float* __restrict__ opart0, float* __restrict__ opart1,
    float* __restrict__ mpart, float* __restrict__ lpart) {
  int qt = (int)(gridDim.x - 1) - (int)blockIdx.x;   // heavy tiles first
  int kvh = blockIdx.y;
  int z = blockIdx.z;
  int tid = threadIdx.x;
  int wave = tid >> 6, lane = tid & 63;
  int quad = lane >> 4, l16 = lane & 15;
  int h = kvh * 4 + wave;

  float* opz = z ? opart1 : opart0;
  float* mp = mpart + (size_t)z * S * NH;
  float* lp = lpart + (size_t)z * S * NH;

  int nb = (qt >> 1) + 1;            // valid 32-blocks of kv
  int nt = (nb + 1) >> 1;            // 64-wide tiles
  bool halfm = (nb & 1) != 0;        // last tile only 32 valid
  int h0 = nt >> 1;
  int lo = z ? h0 : 0;
  int hi = z ? nt : h0;

  if (lo >= hi) {                    // empty chunk: zero partials
    int row = qt * 16 + (tid >> 4);
    float* od = opz + (size_t)row * (NH * HD) + kvh * 256 + (tid & 15) * 16;
    int4 zz = {0, 0, 0, 0};
#pragma unroll
    for (int i = 0; i < 4; ++i) *(int4*)(od + i * 4) = zz;
    if (tid < 64) {
      int rr = qt * 16 + (tid >> 2), hh = kvh * 4 + (tid & 3);
      mp[(size_t)rr * NH + hh] = -1e30f;
      lp[(size_t)rr * NH + hh] = 0.f;
    }
    return;
  }

  __shared__ __align__(16) int KsI[64 * 36];         // K tile [64 k][64 d + pad]
  __shared__ __align__(16) int VTI[64 * 36];         // V^T tile [64 d][64 k + pad]
  __shared__ __align__(16) int PsI[4][16 * 36];      // per-wave P [16 q][64 k + pad]

  I4B8 qf[2];
#pragma unroll
  for (int ch = 0; ch < 2; ++ch)
    qf[ch].i = *(const int4*)((const abf16*)qg +
        (size_t)(qt * 16 + l16) * (NH * HD) + h * HD + ch * 32 + quad * 8);

  I4B8 ones;
  ones.i = (int4){0x3F803F80, 0x3F803F80, 0x3F803F80, 0x3F803F80};   // 8x bf16 1.0

  float m_r[4];
  f32x4 o[4], o4;
#pragma unroll
  for (int r = 0; r < 4; ++r) m_r[r] = -1e30f;
#pragma unroll
  for (int sub = 0; sub < 4; ++sub) o[sub] = (f32x4){0.f, 0.f, 0.f, 0.f};
  o4 = (f32x4){0.f, 0.f, 0.f, 0.f};

  int sp = tid >> 3, sc = tid & 7;   // staging: 32 rows x 8 octets (x2 halves)
  const abf16* kb = (const abf16*)kg;
  const abf16* vb = (const abf16*)vT;

  // T14 prologue: load first tile into regs
  int4 rk0 = *(const int4*)(kb + (size_t)(lo * 64 + sp) * (NKV * HD) + kvh * HD + sc * 8);
  int4 rk1 = *(const int4*)(kb + (size_t)(lo * 64 + 32 + sp) * (NKV * HD) + kvh * HD + sc * 8);
  int4 rv0 = *(const int4*)(vb + (size_t)(kvh * HD + sp) * S + lo * 64 + sc * 8);
  int4 rv1 = *(const int4*)(vb + (size_t)(kvh * HD + 32 + sp) * S + lo * 64 + sc * 8);

  for (int kc = lo; kc < hi; ++kc) {
    // ---- write staged regs to LDS (prev compute done via loop-bottom barrier)
    *(int4*)&KsI[sp * 36 + sc * 4] = rk0;
    *(int4*)&KsI[(sp + 32) * 36 + sc * 4] = rk1;
    *(int4*)&VTI[sp * 36 + sc * 4] = rv0;
    *(int4*)&VTI[(sp + 32) * 36 + sc * 4] = rv1;
    __syncthreads();

    // ---- issue next tile loads (latency hides under compute below)
    if (kc + 1 < hi) {
      rk0 = *(const int4*)(kb + (size_t)((kc + 1) * 64 + sp) * (NKV * HD) + kvh * HD + sc * 8);
      rk1 = *(const int4*)(kb + (size_t)((kc + 1) * 64 + 32 + sp) * (NKV * HD) + kvh * HD + sc * 8);
      rv0 = *(const int4*)(vb + (size_t)(kvh * HD + sp) * S + (kc + 1) * 64 + sc * 8);
      rv1 = *(const int4*)(vb + (size_t)(kvh * HD + 32 + sp) * S + (kc + 1) * 64 + sc * 8);
    }

    // ---- QK^T: 16 q-rows x 64 k
    f32x4 s[4];
#pragma unroll
    for (int sub = 0; sub < 4; ++sub) s[sub] = (f32x4){0.f, 0.f, 0.f, 0.f};
    __builtin_amdgcn_s_setprio(1);
#pragma unroll
    for (int sub = 0; sub < 4; ++sub)
#pragma unroll
      for (int ch = 0; ch < 2; ++ch) {
        I4B8 ku;
        ku.i = *(const int4*)&KsI[(sub * 16 + l16) * 36 + ch * 16 + quad * 4];
        s[sub] = __builtin_amdgcn_mfma_f32_16x16x32_bf16(qf[ch].v, ku.v, s[sub], 0, 0, 0);
      }
    __builtin_amdgcn_s_setprio(0);
    if (halfm && kc == nt - 1) {
#pragma unroll
      for (int r = 0; r < 4; ++r) { s[2][r] = -1e30f; s[3][r] = -1e30f; }
    }

    // ---- online softmax: max-reduce + exp; sums come from ones-MFMA
    abf16* pw = (abf16*)PsI[wave];
#pragma unroll
    for (int r = 0; r < 4; ++r) {
      float v = fmaxf(fmaxf(s[0][r], s[1][r]), fmaxf(s[2][r], s[3][r]));
#pragma unroll
      for (int off = 1; off < 16; off <<= 1) v = fmaxf(v, __shfl_xor(v, off));
      float mx = fmaxf(m_r[r], v);
      float al = __expf(m_r[r] - mx);
      m_r[r] = mx;
      float p0 = __expf(s[0][r] - mx);
      float p1 = __expf(s[1][r] - mx);
      float p2 = __expf(s[2][r] - mx);
      float p3 = __expf(s[3][r] - mx);
      int prow = quad * 4 + r;
      pw[prow * 72 + l16]      = (bf16_t)p0;
      pw[prow * 72 + 16 + l16] = (bf16_t)p1;
      pw[prow * 72 + 32 + l16] = (bf16_t)p2;
      pw[prow * 72 + 48 + l16] = (bf16_t)p3;
      o4[r] *= al;
#pragma unroll
      for (int sub = 0; sub < 4; ++sub) o[sub][r] *= al;
    }

    // ---- PV: P(16x64) x V(64x64) + ones-column for row sums
    I4B8 pu[2];
#pragma unroll
    for (int ch = 0; ch < 2; ++ch)
      pu[ch].i = *(const int4*)&PsI[wave][l16 * 36 + ch * 16 + quad * 4];
    __builtin_amdgcn_s_setprio(1);
#pragma unroll
    for (int sub = 0; sub < 4; ++sub)
#pragma unroll
      for (int ch = 0; ch < 2; ++ch) {
        I4B8 vf;
        vf.i = *(const int4*)&VTI[(sub * 16 + l16) * 36 + ch * 16 + quad * 4];
        o[sub] = __builtin_amdgcn_mfma_f32_16x16x32_bf16(pu[ch].v, vf.v, o[sub], 0, 0, 0);
      }
#pragma unroll
    for (int ch = 0; ch < 2; ++ch)
      o4 = __builtin_amdgcn_mfma_f32_16x16x32_bf16(pu[ch].v, ones.v, o4, 0, 0, 0);
    __builtin_amdgcn_s_setprio(0);
    __syncthreads();
  }

  // epilogue: write raw partials (normalize at merge)
#pragma unroll
  for (int r = 0; r < 4; ++r) {
    int row = qt * 16 + quad * 4 + r;
    float* od = opz + (size_t)row * (NH * HD) + h * HD;
#pragma unroll
    for (int sub = 0; sub < 4; ++sub)
      od[sub * 16 + l16] = o[sub][r];
    if (l16 == 0) {
      mp[(size_t)row * NH + h] = m_r[r];
      lp[(size_t)row * NH + h] = o4[r];
    }
  }
}

// --------------------------------------------- merge KV-split partials
__global__ void attn_merge_kernel(const float* __restrict__ opart0,
                                  const float* __restrict__ opart1,
                                  const float* __restrict__ mpart,
                                  const float* __restrict__ lpart,
                                  __hip_bfloat16* __restrict__ attn) {
  int row = blockIdx.x;
  int tid = threadIdx.x;
#pragma unroll
  for (int i = 0; i < 4; ++i) {
    int c = tid + i * 256;
    int h = c >> 6;
    float m0 = mpart[(size_t)row * NH + h];
    float m1 = mpart[(size_t)(S + row) * NH + h];
    float l0 = lpart[(size_t)row * NH + h];
    float l1 = lpart[(size_t)(S + row) * NH + h];
    float M = fmaxf(m0, m1);
    float a0 = __expf(m0 - M), a1 = __expf(m1 - M);
    float l = l0 * a0 + l1 * a1;
    float v = (opart0[(size_t)row * (NH * HD) + c] * a0 +
               opart1[(size_t)row * (NH * HD) + c] * a1) / l;
    attn[(size_t)row * (NH * HD) + c] = __float2bfloat16(v);
  }
}

// ---------------------------------------------------------------- router phase A
// logits + top2 + weights only; NO atomics (they were a 64 us cross-XCD convoy).
__global__ void router_kernel(const float* __restrict__ h2, const float* __restrict__ rw,
                              int* __restrict__ topk_e, float* __restrict__ topk_w) {
  int t = blockIdx.x * 4 + (threadIdx.x >> 6);
  int lane = threadIdx.x & 63;
  float p[NE] = {};
  for (int d = lane; d < D; d += 64) {
    float hv = h2[(size_t)t * D + d];
#pragma unroll
    for (int e = 0; e < NE; ++e) p[e] += hv * rw[d * NE + e];
  }
#pragma unroll
  for (int off = 32; off; off >>= 1)
#pragma unroll
    for (int e = 0; e < NE; ++e) p[e] += __shfl_xor(p[e], off);
  if (lane == 0) {
    float mx = p[0];
#pragma unroll
    for (int e = 1; e < NE; ++e) mx = fmaxf(mx, p[e]);
    float ex[NE];
#pragma unroll
    for (int e = 0; e < NE; ++e) ex[e] = __expf(p[e] - mx);
    int e0 = 0;
#pragma unroll
    for (int e = 1; e < NE; ++e) if (ex[e] > ex[e0]) e0 = e;
    int e1 = (e0 == 0) ? 1 : 0;
#pragma unroll
    for (int e = 0; e < NE; ++e) if (e != e0 && ex[e] > ex[e1]) e1 = e;
    float w0 = ex[e0] / (ex[e0] + ex[e1]);
    float w1 = ex[e1] / (ex[e0] + ex[e1]);
    topk_e[2 * t] = e0;  topk_e[2 * t + 1] = e1;
    topk_w[2 * t] = w0;  topk_w[2 * t + 1] = w1;
  }
}

// ---------------------------------------------------------------- router phase B
// ONE block, 1024 threads. Ballot-aggregated LDS counters -> tok_list/topk_pos;
// absorbs zero_counts + scan. ~64 LDS atomics replace 4096 cross-XCD global RMWs.
__global__ __launch_bounds__(1024) void router_place_kernel(
    const int* __restrict__ topk_e, int* __restrict__ counts, int* __restrict__ offsets,
    int* __restrict__ tok_list, int* __restrict__ topk_pos) {
  __shared__ int lcnt[NE];
  int tid = threadIdx.x;
  int lane = tid & 63;
  if (tid < NE) lcnt[tid] = 0;
  __syncthreads();
#pragma unroll
  for (int r = 0; r < 2; ++r) {
    int t = r * 1024 + tid;
#pragma unroll
    for (int s = 0; s < 2; ++s) {
      int e = topk_e[2 * t + s];
      int pos = 0;
#pragma unroll
      for (int x = 0; x < NE; ++x) {
        unsigned long long mask = __ballot(e == x);
        if (mask) {
          int leader = __ffsll((unsigned long long)mask) - 1;
          int cnt = __popcll(mask);
          int base = 0;
          if (lane == leader) base = atomicAdd(&lcnt[x], cnt);
          base = __shfl(base, leader);
          if (e == x)
            pos = base + __popcll(mask & ((1ull << lane) - 1ull));
        }
      }
      topk_pos[2 * t + s] = pos;
      tok_list[e * S + pos] = t;
    }
  }
  __syncthreads();
  if (tid == 0) {
    int acc = 0;
    for (int e = 0; e < NE; ++e) { offsets[e] = acc; counts[e] = lcnt[e]; acc += lcnt[e]; }
  }
}

// ---------------------------------------------------------------- final add
__global__ void final_kernel(const float* __restrict__ x, const float* __restrict__ sout,
                             const float* __restrict__ eo,
                             const int* __restrict__ topk_e, const int* __restrict__ topk_pos,
                             const float* __restrict__ topk_w, const int* __restrict__ offsets,
                             float* __restrict__ out) {
  int t = blockIdx.x;
  int tid = threadIdx.x;
  int e0 = topk_e[2 * t], e1 = topk_e[2 * t + 1];
  size_t r0 = (size_t)offsets[e0] + topk_pos[2 * t];
  size_t r1 = (size_t)offsets[e1] + topk_pos[2 * t + 1];
  float w0 = topk_w[2 * t], w1 = topk_w[2 * t + 1];
#pragma unroll
  for (int i = 0; i < 4; ++i) {
    int d = tid + i * 256;
    size_t idx = (size_t)t * D + d;
    out[idx] = x[idx] + sout[idx] + w0 * eo[r0 * D + d] + w1 * eo[r1 * D + d];
  }
}

extern "C" void kernel_launch(void* const* d_in, const int* in_sizes, int n_in,
                              void* d_out, int out_size, void* d_ws, size_t ws_size,
                              hipStream_t stream) {
  const float* hidden  = (const float*)d_in[0];
  const float* cosb    = (const float*)d_in[1];
  const float* sinb    = (const float*)d_in[2];
  const float* w_qkv   = (const float*)d_in[3];
  const float* w_o     = (const float*)d_in[4];
  const float* q_norm  = (const float*)d_in[5];
  const float* k_norm  = (const float*)d_in[6];
  const float* in_ln   = (const float*)d_in[7];
  const float* post_ln = (const float*)d_in[8];
  const float* router_w= (const float*)d_in[9];
  const float* w_gate  = (const float*)d_in[10];
  const float* w_up    = (const float*)d_in[11];
  const float* w_down  = (const float*)d_in[12];
  const float* ws_gate = (const float*)d_in[13];
  const float* ws_up   = (const float*)d_in[14];
  const float* ws_down = (const float*)d_in[15];
  float* out = (float*)d_out;
  float* ws = (float*)d_ws;

  typedef __hip_bfloat16 hbf;
  // weights (bf16)
  hbf* wqkvT = (hbf*)(ws);                      // 1.5M el
  hbf* woT   = (hbf*)(ws +  768 * 1024);        // 1M el
  hbf* wgT   = (hbf*)(ws + 1280 * 1024);        // 8M el
  hbf* wuT   = (hbf*)(ws + 5376 * 1024);        // 8M el
  hbf* wdT   = (hbf*)(ws + 9472 * 1024);        // 8M el
  hbf* wsgT  = (hbf*)(ws + 13568 * 1024);       // 1M el
  hbf* wsuT  = (hbf*)(ws + 14080 * 1024);       // 1M el
  hbf* wsdT  = (hbf*)(ws + 14592 * 1024);       // 1M el
  // activations
  hbf*   hb      = (hbf*)(ws + 15104 * 1024);   // [15104K,16128K), dead after qkv GEMM
  float* qkv     = ws + 16128 * 1024;           // [16128K,19200K), dead after v_transpose
  hbf*   qbB     = (hbf*)(ws + 19200 * 1024);   // [19200K,20224K)
  hbf*   kbB     = (hbf*)(ws + 20224 * 1024);   // [20224K,20480K)
  hbf*   vTb     = (hbf*)(ws + 20480 * 1024);   // [20480K,20736K)  V^T [256][2048]
  hbf*   attnb16 = (hbf*)(ws + 20736 * 1024);   // [20736K,21760K)
  float* x       = ws + 22784 * 1024;           // 2M fl (written by wo GEMM, after merge)
  float* h2      = ws + 24832 * 1024;           // 2M fl
  hbf*   h2b     = (hbf*)(ws + 26880 * 1024);   // [26880K,27904K)
  hbf*   act     = (hbf*)(ws + 16128 * 1024);   // 4096x1024 bf16, aliases dead qkv
  float* eo      = ws + 18176 * 1024;           // 4096x1024 fp32, aliases dead q/k/v
  hbf*   sact    = (hbf*)(ws + 27904 * 1024);   // 2048x1024 bf16
  float* sout    = ws + 28928 * 1024;           // 2048x1024 fp32
  // attention partials (live only attn -> merge):
  float* mpart   = ws + 15104 * 1024;           // [2][S][NH]  (aliases dead hb)
  float* lpart   = mpart + 2 * S * NH;
  float* opart0  = ws + 16128 * 1024;           // [S][1024]   (aliases dead qkv)
  float* opart1  = ws + 22784 * 1024;           // [S][1024]   (aliases x, written later)
  int* counts   = (int*)(ws + 30976 * 1024);
  int* offsets  = counts + NE;
  int* tok_list = offsets + NE;
  int* topk_e   = tok_list + NE * S;
  int* topk_pos = topk_e + 2 * S;
  float* topk_w = (float*)(topk_pos + 2 * S);

  dim3 b256(256);
  transpose_cast_kernel<<<dim3(QKV_N/32, D/32, 1), b256, 0, stream>>>(w_qkv, wqkvT, D, QKV_N);
  transpose_cast_kernel<<<dim3(D/32, D/32, 1),     b256, 0, stream>>>(w_o, woT, D, D);
  transpose_cast_kernel<<<dim3(NI/32, D/32, NE),   b256, 0, stream>>>(w_gate, wgT, D, NI);
  transpose_cast_kernel<<<dim3(NI/32, D/32, NE),   b256, 0, stream>>>(w_up, wuT, D, NI);
  transpose_cast_kernel<<<dim3(D/32, NI/32, NE),   b256, 0, stream>>>(w_down, wdT, NI, D);
  transpose_cast_kernel<<<dim3(NI/32, D/32, 1),    b256, 0, stream>>>(ws_gate, wsgT, D, NI);
  transpose_cast_kernel<<<dim3(NI/32, D/32, 1),    b256, 0, stream>>>(ws_up, wsuT, D, NI);
  transpose_cast_kernel<<<dim3(D/32, NI/32, 1),    b256, 0, stream>>>(ws_down, wsdT, NI, D);
  // attention block
  rmsnorm_kernel<<<S, b256, 0, stream>>>(hidden, in_ln, nullptr, hb);
  mgemm_kernel<<<dim3(QKV_N/128, S/128, 1), b256, 0, stream>>>(hb, wqkvT, nullptr, qkv,
      S, QKV_N, D, nullptr, nullptr, nullptr, 0, nullptr, nullptr, nullptr);
  qkv_post_kernel<<<dim3(S, 5), b256, 0, stream>>>(qkv, q_norm, k_norm, cosb, sinb, qbB, kbB, nullptr);
  v_transpose_kernel<<<dim3(S/32, (NKV*HD)/32), b256, 0, stream>>>(qkv, vTb);
  attn_kernel<<<dim3(S/16, NKV, 2), b256, 0, stream>>>(qbB, kbB, vTb,
      opart0, opart1, mpart, lpart);
  attn_merge_kernel<<<S, b256, 0, stream>>>(opart0, opart1, mpart, lpart, attnb16);
  mgemm_kernel<<<dim3(D/128, S/128, 1), b256, 0, stream>>>(attnb16, woT, hidden, x,
      S, D, D, nullptr, nullptr, nullptr, 0, nullptr, nullptr, nullptr);
  // MoE block (shared expert merged as z == NE)
  rmsnorm_kernel<<<S, b256, 0, stream>>>(x, post_ln, h2, h2b);
  router_kernel<<<S/4, b256, 0, stream>>>(h2, router_w, topk_e, topk_w);
  router_place_kernel<<<1, 1024, 0, stream>>>(topk_e, counts, offsets, tok_list, topk_pos);
  mgemm_gu_kernel<<<dim3(NI/64, S/128, NE + 1), b256, 0, stream>>>(h2b, wgT, wuT, act,
      S, NI, D, counts, offsets, tok_list, wsgT, wsuT, sact);
  mgemm_kernel<<<dim3(D/128, S/128, NE + 1), b256, 0, stream>>>(act, wdT, nullptr, eo,
      S, D, NI, counts, offsets, nullptr, 1, sact, wsdT, sout);
  final_kernel<<<S, b256, 0, stream>>>(x, sout, eo, topk_e, topk_pos, topk_w, offsets, out);
}

// Round 6
// 442.934 us; speedup vs baseline: 1.2746x; 1.0041x over previous
//
#include <hip/hip_runtime.h>
#include <hip/hip_bf16.h>
#include <math.h>

#define S 2048
#define D 1024
#define NH 16
#define NKV 4
#define HD 64
#define QKV_N 1536          // (NH + 2*NKV) * HD
#define NE 8
#define NI 1024
#define EPS 1e-6f

typedef __bf16 bf16_t;
typedef __bf16 __attribute__((may_alias)) abf16;
typedef __attribute__((ext_vector_type(8))) __bf16 bf16x8;
typedef __attribute__((ext_vector_type(4))) float f32x4;
union I4B8 { int4 i; bf16x8 v; bf16_t e[8]; };

// async global->LDS, 16B per lane. LDS dest must be wave-uniform base
// (HW adds lane*16); global src is per-lane.
__device__ __forceinline__ void gll16(const void* g, void* l) {
  __builtin_amdgcn_global_load_lds(
      (const __attribute__((address_space(1))) void*)g,
      (__attribute__((address_space(3))) void*)l, 16, 0, 0);
}

// ---------------------------------------------------------------- rmsnorm(D)
__global__ void rmsnorm_kernel(const float* __restrict__ in, const float* __restrict__ w,
                               float* __restrict__ out32, __hip_bfloat16* __restrict__ out16) {
  int t = blockIdx.x;
  int tid = threadIdx.x;
  const float* row = in + (size_t)t * D;
  float v[4];
  float ss = 0.f;
#pragma unroll
  for (int i = 0; i < 4; ++i) {
    v[i] = row[tid + i * 256];
    ss += v[i] * v[i];
  }
#pragma unroll
  for (int off = 32; off; off >>= 1) ss += __shfl_xor(ss, off);
  __shared__ float wsum[4];
  int wave = tid >> 6;
  if ((tid & 63) == 0) wsum[wave] = ss;
  __syncthreads();
  float tot = wsum[0] + wsum[1] + wsum[2] + wsum[3];
  float r = rsqrtf(tot / (float)D + EPS);
#pragma unroll
  for (int i = 0; i < 4; ++i) {
    int d = tid + i * 256;
    float val = v[i] * r * w[d];
    if (out32) out32[(size_t)t * D + d] = val;
    if (out16) out16[(size_t)t * D + d] = __float2bfloat16(val);
  }
}

// ------------------------------------------- weight transpose + bf16 cast
__global__ void transpose_cast_kernel(const float* __restrict__ W,
                                      __hip_bfloat16* __restrict__ WT, int Kd, int Nd) {
  __shared__ float tile[32][33];
  int e = blockIdx.z;
  const float* Wp = W + (size_t)e * Kd * Nd;
  __hip_bfloat16* WTp = WT + (size_t)e * Kd * Nd;
  int n0 = blockIdx.x * 32, k0 = blockIdx.y * 32;
  int tx = threadIdx.x & 31, ty = threadIdx.x >> 5;
#pragma unroll
  for (int i = 0; i < 4; ++i)
    tile[ty + i * 8][tx] = Wp[(size_t)(k0 + ty + i * 8) * Nd + n0 + tx];
  __syncthreads();
#pragma unroll
  for (int i = 0; i < 4; ++i)
    WTp[(size_t)(n0 + ty + i * 8) * Kd + k0 + tx] = __float2bfloat16(tile[tx][ty + i * 8]);
}

// ------------------------------------------- V transpose (fp32 qkv slice -> bf16 vT[256][2048])
__global__ void v_transpose_kernel(const float* __restrict__ qkv, __hip_bfloat16* __restrict__ vT) {
  __shared__ float tile[32][33];
  int t0 = blockIdx.x * 32;            // token
  int c0 = blockIdx.y * 32;            // v channel (0..255)
  int tx = threadIdx.x & 31, ty = threadIdx.x >> 5;
#pragma unroll
  for (int i = 0; i < 4; ++i)
    tile[ty + i * 8][tx] = qkv[(size_t)(t0 + ty + i * 8) * QKV_N + (NH + NKV) * HD + c0 + tx];
  __syncthreads();
#pragma unroll
  for (int i = 0; i < 4; ++i)
    vT[(size_t)(c0 + ty + i * 8) * S + t0 + tx] = __float2bfloat16(tile[tx][ty + i * 8]);
}

// ------------------------------------------- MFMA bf16 GEMM, 128x128 tile
// m97 structure + 3-deep LDS pipeline with counted vmcnt (T4): at each barrier
// wait vmcnt(4) -> only the batch issued TWO phases ago must land; the newest
// 4 loads stay in flight across the barrier. Wait is BEFORE s_barrier so all
// waves' chunks are visible when any wave reads.
__global__ __launch_bounds__(256) void mgemm_kernel(
    const __hip_bfloat16* __restrict__ A, const __hip_bfloat16* __restrict__ BT,
    const float* __restrict__ Cadd, float* __restrict__ C,
    int M, int N, int K,
    const int* __restrict__ counts, const int* __restrict__ offsets,
    const int* __restrict__ tok, int a_comp,
    const __hip_bfloat16* __restrict__ As2, const __hip_bfloat16* __restrict__ BTs2,
    float* __restrict__ Cs2) {
  __shared__ __align__(16) bf16_t Asd[3][128 * 32];   // 3 x 8 KB
  __shared__ __align__(16) bf16_t Bsd[3][128 * 32];
  __shared__ int rowmap[128];
  int e = blockIdx.z;
  bool sh = (counts != nullptr) && (e == NE);
  int cnt = sh ? M : (counts ? counts[e] : M);
  int bm = blockIdx.y * 128;
  if (bm >= cnt) return;
  int bn = blockIdx.x * 128;
  int obase = sh ? 0 : (offsets ? offsets[e] : 0);
  const bf16_t* Ab = sh ? (const bf16_t*)As2 : (const bf16_t*)A;
  const bf16_t* BTe = sh ? (const bf16_t*)BTs2 : ((const bf16_t*)BT + (size_t)e * N * K);
  float* Cp = sh ? Cs2 : C;
  const int* toke = (!sh && tok) ? tok + e * S : nullptr;
  int acompe = sh ? 0 : a_comp;
  int tid = threadIdx.x;
  if (tid < 128) {
    int gp = bm + tid;
    int cp = gp < cnt ? gp : cnt - 1;
    rowmap[tid] = toke ? toke[cp] : (acompe ? obase + cp : cp);
  }
  __syncthreads();
  int wave = tid >> 6, lane = tid & 63;
  int quad = lane >> 4, l16 = lane & 15;
  int wm = wave >> 1, wn = wave & 1;
  int srow = tid >> 2, scol = (tid & 3) * 8;
  size_t aoff0 = (size_t)rowmap[srow] * K + scol;
  size_t aoff1 = (size_t)rowmap[64 + srow] * K + scol;
  size_t boff0 = (size_t)(bn + srow) * K + scol;
  size_t boff1 = (size_t)(bn + 64 + srow) * K + scol;
  f32x4 acc[4][4];
#pragma unroll
  for (int i = 0; i < 4; ++i)
#pragma unroll
    for (int j = 0; j < 4; ++j) acc[i][j] = (f32x4){0.f, 0.f, 0.f, 0.f};

  int nt = K >> 5;
  // prologue: stage batch 0 (and 1 if present)
  {
    char* AsB = (char*)Asd[0] + wave * 1024;
    char* BsB = (char*)Bsd[0] + wave * 1024;
    gll16(Ab + aoff0, AsB);
    gll16(Ab + aoff1, AsB + 4096);
    gll16(BTe + boff0, BsB);
    gll16(BTe + boff1, BsB + 4096);
    if (nt > 1) {
      char* AsB1 = (char*)Asd[1] + wave * 1024;
      char* BsB1 = (char*)Bsd[1] + wave * 1024;
      gll16(Ab + aoff0 + 32, AsB1);
      gll16(Ab + aoff1 + 32, AsB1 + 4096);
      gll16(BTe + boff0 + 32, BsB1);
      gll16(BTe + boff1 + 32, BsB1 + 4096);
    }
  }
  int cur = 0;
  for (int t = 0; t < nt; ++t) {
    if (t == nt - 1) asm volatile("s_waitcnt vmcnt(0)" ::: "memory");
    else             asm volatile("s_waitcnt vmcnt(4)" ::: "memory");
    __builtin_amdgcn_s_barrier();
    asm volatile("" ::: "memory");
    if (t + 2 < nt) {
      int pb = cur + 2; if (pb >= 3) pb -= 3;
      int kp = (t + 2) << 5;
      char* AsB = (char*)Asd[pb] + wave * 1024;
      char* BsB = (char*)Bsd[pb] + wave * 1024;
      gll16(Ab + aoff0 + kp, AsB);
      gll16(Ab + aoff1 + kp, AsB + 4096);
      gll16(BTe + boff0 + kp, BsB);
      gll16(BTe + boff1 + kp, BsB + 4096);
    }
    const bf16_t* Ac = Asd[cur];
    const bf16_t* Bc = Bsd[cur];
    I4B8 af[4], bfr[4];
#pragma unroll
    for (int i = 0; i < 4; ++i)
      af[i].i = *(const int4*)(Ac + (wm * 64 + i * 16 + l16) * 32 + quad * 8);
#pragma unroll
    for (int j = 0; j < 4; ++j)
      bfr[j].i = *(const int4*)(Bc + (wn * 64 + j * 16 + l16) * 32 + quad * 8);
#pragma unroll
    for (int i = 0; i < 4; ++i)
#pragma unroll
      for (int j = 0; j < 4; ++j)
        acc[i][j] = __builtin_amdgcn_mfma_f32_16x16x32_bf16(af[i].v, bfr[j].v, acc[i][j], 0, 0, 0);
    cur = (cur == 2) ? 0 : cur + 1;
  }
#pragma unroll
  for (int i = 0; i < 4; ++i) {
#pragma unroll
    for (int r = 0; r < 4; ++r) {
      int trow = wm * 64 + i * 16 + quad * 4 + r;
      int gp = bm + trow;
      if (gp < cnt) {
        size_t rowb = (size_t)(obase + gp) * N;
#pragma unroll
        for (int j = 0; j < 4; ++j) {
          int col = bn + wn * 64 + j * 16 + l16;
          size_t idx = rowb + col;
          Cp[idx] = acc[i][j][r] + (Cadd ? Cadd[idx] : 0.f);
        }
      }
    }
  }
}

// ------------------------------------------- dual-B MFMA GEMM + silu, 128x64 tile
// Same 3-deep counted-vmcnt pipeline as mgemm_kernel.
__global__ __launch_bounds__(256) void mgemm_gu_kernel(
    const __hip_bfloat16* __restrict__ A, const __hip_bfloat16* __restrict__ BTg,
    const __hip_bfloat16* __restrict__ BTu, __hip_bfloat16* __restrict__ act,
    int M, int N, int K,
    const int* __restrict__ counts, const int* __restrict__ offsets,
    const int* __restrict__ tok,
    const __hip_bfloat16* __restrict__ BTgs, const __hip_bfloat16* __restrict__ BTus,
    __hip_bfloat16* __restrict__ acts) {
  __shared__ __align__(16) bf16_t Asd[3][128 * 32];   // 3 x 8 KB
  __shared__ __align__(16) bf16_t Bgd[3][64 * 32];    // 3 x 4 KB
  __shared__ __align__(16) bf16_t Bud[3][64 * 32];    // 3 x 4 KB
  __shared__ int rowmap[128];
  int e = blockIdx.z;
  bool sh = (counts != nullptr) && (e == NE);
  int cnt = sh ? M : (counts ? counts[e] : M);
  int bm = blockIdx.y * 128;
  if (bm >= cnt) return;
  int bn = blockIdx.x * 64;
  const bf16_t* Ab = (const bf16_t*)A;
  const bf16_t* Bg = sh ? (const bf16_t*)BTgs : ((const bf16_t*)BTg + (size_t)e * N * K);
  const bf16_t* Bu = sh ? (const bf16_t*)BTus : ((const bf16_t*)BTu + (size_t)e * N * K);
  bf16_t* outp = sh ? (bf16_t*)acts : (bf16_t*)act;
  int obase = sh ? 0 : (offsets ? offsets[e] : 0);
  const int* toke = (!sh && tok) ? tok + e * S : nullptr;
  int tid = threadIdx.x;
  if (tid < 128) {
    int gp = bm + tid;
    int cp = gp < cnt ? gp : cnt - 1;
    rowmap[tid] = toke ? toke[cp] : cp;
  }
  __syncthreads();
  int wave = tid >> 6, lane = tid & 63;
  int quad = lane >> 4, l16 = lane & 15;
  int wm = wave >> 1, wn = wave & 1;
  int srow = tid >> 2, scol = (tid & 3) * 8;
  size_t aoff0 = (size_t)rowmap[srow] * K + scol;
  size_t aoff1 = (size_t)rowmap[64 + srow] * K + scol;
  size_t boff = (size_t)(bn + srow) * K + scol;
  f32x4 accg[4][2], accu[4][2];
#pragma unroll
  for (int i = 0; i < 4; ++i)
#pragma unroll
    for (int j = 0; j < 2; ++j) {
      accg[i][j] = (f32x4){0.f, 0.f, 0.f, 0.f};
      accu[i][j] = (f32x4){0.f, 0.f, 0.f, 0.f};
    }
  int nt = K >> 5;
  // prologue
  {
    char* AsB = (char*)Asd[0] + wave * 1024;
    gll16(Ab + aoff0, AsB);
    gll16(Ab + aoff1, AsB + 4096);
    gll16(Bg + boff, (char*)Bgd[0] + wave * 1024);
    gll16(Bu + boff, (char*)Bud[0] + wave * 1024);
    if (nt > 1) {
      char* AsB1 = (char*)Asd[1] + wave * 1024;
      gll16(Ab + aoff0 + 32, AsB1);
      gll16(Ab + aoff1 + 32, AsB1 + 4096);
      gll16(Bg + boff + 32, (char*)Bgd[1] + wave * 1024);
      gll16(Bu + boff + 32, (char*)Bud[1] + wave * 1024);
    }
  }
  int cur = 0;
  for (int t = 0; t < nt; ++t) {
    if (t == nt - 1) asm volatile("s_waitcnt vmcnt(0)" ::: "memory");
    else             asm volatile("s_waitcnt vmcnt(4)" ::: "memory");
    __builtin_amdgcn_s_barrier();
    asm volatile("" ::: "memory");
    if (t + 2 < nt) {
      int pb = cur + 2; if (pb >= 3) pb -= 3;
      int kp = (t + 2) << 5;
      char* AsB = (char*)Asd[pb] + wave * 1024;
      gll16(Ab + aoff0 + kp, AsB);
      gll16(Ab + aoff1 + kp, AsB + 4096);
      gll16(Bg + boff + kp, (char*)Bgd[pb] + wave * 1024);
      gll16(Bu + boff + kp, (char*)Bud[pb] + wave * 1024);
    }
    const bf16_t* Ac = Asd[cur];
    const bf16_t* Bgc = Bgd[cur];
    const bf16_t* Buc = Bud[cur];
    I4B8 af[4], bg[2], bu[2];
#pragma unroll
    for (int i = 0; i < 4; ++i)
      af[i].i = *(const int4*)(Ac + (wm * 64 + i * 16 + l16) * 32 + quad * 8);
#pragma unroll
    for (int j = 0; j < 2; ++j) {
      bg[j].i = *(const int4*)(Bgc + (wn * 32 + j * 16 + l16) * 32 + quad * 8);
      bu[j].i = *(const int4*)(Buc + (wn * 32 + j * 16 + l16) * 32 + quad * 8);
    }
#pragma unroll
    for (int i = 0; i < 4; ++i)
#pragma unroll
      for (int j = 0; j < 2; ++j) {
        accg[i][j] = __builtin_amdgcn_mfma_f32_16x16x32_bf16(af[i].v, bg[j].v, accg[i][j], 0, 0, 0);
        accu[i][j] = __builtin_amdgcn_mfma_f32_16x16x32_bf16(af[i].v, bu[j].v, accu[i][j], 0, 0, 0);
      }
    cur = (cur == 2) ? 0 : cur + 1;
  }
#pragma unroll
  for (int i = 0; i < 4; ++i) {
#pragma unroll
    for (int r = 0; r < 4; ++r) {
      int trow = wm * 64 + i * 16 + quad * 4 + r;
      int gp = bm + trow;
      if (gp < cnt) {
        size_t rowb = (size_t)(obase + gp) * N;
#pragma unroll
        for (int j = 0; j < 2; ++j) {
          int col = bn + wn * 32 + j * 16 + l16;
          float g = accg[i][j][r], uu = accu[i][j][r];
          float sg = g / (1.f + __expf(-g));
          outp[rowb + col] = __float2bfloat16(sg * uu);
        }
      }
    }
  }
}

// --------------------------------------------- q/k head rmsnorm + RoPE + bf16 cast
__global__ void qkv_post_kernel(const float* __restrict__ qkv,
                                const float* __restrict__ qw, const float* __restrict__ kw,
                                const float* __restrict__ cosb, const float* __restrict__ sinb,
                                __hip_bfloat16* __restrict__ qout,
                                __hip_bfloat16* __restrict__ kout,
                                __hip_bfloat16* __restrict__ vout) {
  int t = blockIdx.x;
  int u = blockIdx.y * 4 + (threadIdx.x >> 6);
  int lane = threadIdx.x & 63;
  if (u >= NH + NKV) {
    int h = u - NH - NKV;
    float xv = qkv[(size_t)t * QKV_N + (NH + NKV) * HD + h * HD + lane];
    vout[(size_t)t * (NKV * HD) + h * HD + lane] = __float2bfloat16(xv);
    return;
  }
  bool isq = (u < NH);
  int h = isq ? u : (u - NH);
  size_t src = (size_t)t * QKV_N + (isq ? (h * HD) : (NH * HD + h * HD)) + lane;
  float xv = qkv[src];
  float ss = xv * xv;
#pragma unroll
  for (int off = 32; off; off >>= 1) ss += __shfl_xor(ss, off);
  float r = rsqrtf(ss * (1.f / 64.f) + EPS);
  float xn = xv * r * (isq ? qw[lane] : kw[lane]);
  float other = __shfl_xor(xn, 32);
  float rot = (lane < 32) ? -other : other;
  float res = xn * cosb[t * 64 + lane] + rot * sinb[t * 64 + lane];
  if (isq) qout[(size_t)t * (NH * HD) + h * HD + lane] = __float2bfloat16(res * 0.125f);
  else     kout[(size_t)t * (NKV * HD) + h * HD + lane] = __float2bfloat16(res);
}

// --------------------------------------------- MFMA flash attention v4
// GQA-merged + KV-split-2 (flash-decoding). Block = (16-row q-tile, kv head, chunk z).
// 4 waves = 4 q-heads sharing K/V. T14 async staging (regs loaded one tile ahead).
// l accumulated via ones-column MFMA (no sum shuffles). Partials merged by attn_merge.
__global__ __launch_bounds__(256) void attn_kernel(
    const __hip_bfloat16* __restrict__ qg, const __hip_bfloat16* __restrict__ kg,
    const __hip_bfloat16* __restrict__ vT,
    float* __restrict__ opart0, float* __restrict__ opart1,
    float* __restrict__ mpart, float* __restrict__ lpart) {
  int qt = (int)(gridDim.x - 1) - (int)blockIdx.x;   // heavy tiles first
  int kvh = blockIdx.y;
  int z = blockIdx.z;
  int tid = threadIdx.x;
  int wave = tid >> 6, lane = tid & 63;
  int quad = lane >> 4, l16 = lane & 15;
  int h = kvh * 4 + wave;

  float* opz = z ? opart1 : opart0;
  float* mp = mpart + (size_t)z * S * NH;
  float* lp = lpart + (size_t)z * S * NH;

  int nb = (qt >> 1) + 1;            // valid 32-blocks of kv
  int nt = (nb + 1) >> 1;            // 64-wide tiles
  bool halfm = (nb & 1) != 0;        // last tile only 32 valid
  int h0 = nt >> 1;
  int lo = z ? h0 : 0;
  int hi = z ? nt : h0;

  if (lo >= hi) {                    // empty chunk: zero partials
    int row = qt * 16 + (tid >> 4);
    float* od = opz + (size_t)row * (NH * HD) + kvh * 256 + (tid & 15) * 16;
    int4 zz = {0, 0, 0, 0};
#pragma unroll
    for (int i = 0; i < 4; ++i) *(int4*)(od + i * 4) = zz;
    if (tid < 64) {
      int rr = qt * 16 + (tid >> 2), hh = kvh * 4 + (tid & 3);
      mp[(size_t)rr * NH + hh] = -1e30f;
      lp[(size_t)rr * NH + hh] = 0.f;
    }
    return;
  }

  __shared__ __align__(16) int KsI[64 * 36];         // K tile [64 k][64 d + pad]
  __shared__ __align__(16) int VTI[64 * 36];         // V^T tile [64 d][64 k + pad]
  __shared__ __align__(16) int PsI[4][16 * 36];      // per-wave P [16 q][64 k + pad]

  I4B8 qf[2];
#pragma unroll
  for (int ch = 0; ch < 2; ++ch)
    qf[ch].i = *(const int4*)((const abf16*)qg +
        (size_t)(qt * 16 + l16) * (NH * HD) + h * HD + ch * 32 + quad * 8);

  I4B8 ones;
  ones.i = (int4){0x3F803F80, 0x3F803F80, 0x3F803F80, 0x3F803F80};   // 8x bf16 1.0

  float m_r[4];
  f32x4 o[4], o4;
#pragma unroll
  for (int r = 0; r < 4; ++r) m_r[r] = -1e30f;
#pragma unroll
  for (int sub = 0; sub < 4; ++sub) o[sub] = (f32x4){0.f, 0.f, 0.f, 0.f};
  o4 = (f32x4){0.f, 0.f, 0.f, 0.f};

  int sp = tid >> 3, sc = tid & 7;   // staging: 32 rows x 8 octets (x2 halves)
  const abf16* kb = (const abf16*)kg;
  const abf16* vb = (const abf16*)vT;

  // T14 prologue: load first tile into regs
  int4 rk0 = *(const int4*)(kb + (size_t)(lo * 64 + sp) * (NKV * HD) + kvh * HD + sc * 8);
  int4 rk1 = *(const int4*)(kb + (size_t)(lo * 64 + 32 + sp) * (NKV * HD) + kvh * HD + sc * 8);
  int4 rv0 = *(const int4*)(vb + (size_t)(kvh * HD + sp) * S + lo * 64 + sc * 8);
  int4 rv1 = *(const int4*)(vb + (size_t)(kvh * HD + 32 + sp) * S + lo * 64 + sc * 8);

  for (int kc = lo; kc < hi; ++kc) {
    // ---- write staged regs to LDS (prev compute done via loop-bottom barrier)
    *(int4*)&KsI[sp * 36 + sc * 4] = rk0;
    *(int4*)&KsI[(sp + 32) * 36 + sc * 4] = rk1;
    *(int4*)&VTI[sp * 36 + sc * 4] = rv0;
    *(int4*)&VTI[(sp + 32) * 36 + sc * 4] = rv1;
    __syncthreads();

    // ---- issue next tile loads (latency hides under compute below)
    if (kc + 1 < hi) {
      rk0 = *(const int4*)(kb + (size_t)((kc + 1) * 64 + sp) * (NKV * HD) + kvh * HD + sc * 8);
      rk1 = *(const int4*)(kb + (size_t)((kc + 1) * 64 + 32 + sp) * (NKV * HD) + kvh * HD + sc * 8);
      rv0 = *(const int4*)(vb + (size_t)(kvh * HD + sp) * S + (kc + 1) * 64 + sc * 8);
      rv1 = *(const int4*)(vb + (size_t)(kvh * HD + 32 + sp) * S + (kc + 1) * 64 + sc * 8);
    }

    // ---- QK^T: 16 q-rows x 64 k
    f32x4 s[4];
#pragma unroll
    for (int sub = 0; sub < 4; ++sub) s[sub] = (f32x4){0.f, 0.f, 0.f, 0.f};
    __builtin_amdgcn_s_setprio(1);
#pragma unroll
    for (int sub = 0; sub < 4; ++sub)
#pragma unroll
      for (int ch = 0; ch < 2; ++ch) {
        I4B8 ku;
        ku.i = *(const int4*)&KsI[(sub * 16 + l16) * 36 + ch * 16 + quad * 4];
        s[sub] = __builtin_amdgcn_mfma_f32_16x16x32_bf16(qf[ch].v, ku.v, s[sub], 0, 0, 0);
      }
    __builtin_amdgcn_s_setprio(0);
    if (halfm && kc == nt - 1) {
#pragma unroll
      for (int r = 0; r < 4; ++r) { s[2][r] = -1e30f; s[3][r] = -1e30f; }
    }

    // ---- online softmax: max-reduce + exp; sums come from ones-MFMA
    abf16* pw = (abf16*)PsI[wave];
#pragma unroll
    for (int r = 0; r < 4; ++r) {
      float v = fmaxf(fmaxf(s[0][r], s[1][r]), fmaxf(s[2][r], s[3][r]));
#pragma unroll
      for (int off = 1; off < 16; off <<= 1) v = fmaxf(v, __shfl_xor(v, off));
      float mx = fmaxf(m_r[r], v);
      float al = __expf(m_r[r] - mx);
      m_r[r] = mx;
      float p0 = __expf(s[0][r] - mx);
      float p1 = __expf(s[1][r] - mx);
      float p2 = __expf(s[2][r] - mx);
      float p3 = __expf(s[3][r] - mx);
      int prow = quad * 4 + r;
      pw[prow * 72 + l16]      = (bf16_t)p0;
      pw[prow * 72 + 16 + l16] = (bf16_t)p1;
      pw[prow * 72 + 32 + l16] = (bf16_t)p2;
      pw[prow * 72 + 48 + l16] = (bf16_t)p3;
      o4[r] *= al;
#pragma unroll
      for (int sub = 0; sub < 4; ++sub) o[sub][r] *= al;
    }

    // ---- PV: P(16x64) x V(64x64) + ones-column for row sums
    I4B8 pu[2];
#pragma unroll
    for (int ch = 0; ch < 2; ++ch)
      pu[ch].i = *(const int4*)&PsI[wave][l16 * 36 + ch * 16 + quad * 4];
    __builtin_amdgcn_s_setprio(1);
#pragma unroll
    for (int sub = 0; sub < 4; ++sub)
#pragma unroll
      for (int ch = 0; ch < 2; ++ch) {
        I4B8 vf;
        vf.i = *(const int4*)&VTI[(sub * 16 + l16) * 36 + ch * 16 + quad * 4];
        o[sub] = __builtin_amdgcn_mfma_f32_16x16x32_bf16(pu[ch].v, vf.v, o[sub], 0, 0, 0);
      }
#pragma unroll
    for (int ch = 0; ch < 2; ++ch)
      o4 = __builtin_amdgcn_mfma_f32_16x16x32_bf16(pu[ch].v, ones.v, o4, 0, 0, 0);
    __builtin_amdgcn_s_setprio(0);
    __syncthreads();
  }

  // epilogue: write raw partials (normalize at merge)
#pragma unroll
  for (int r = 0; r < 4; ++r) {
    int row = qt * 16 + quad * 4 + r;
    float* od = opz + (size_t)row * (NH * HD) + h * HD;
#pragma unroll
    for (int sub = 0; sub < 4; ++sub)
      od[sub * 16 + l16] = o[sub][r];
    if (l16 == 0) {
      mp[(size_t)row * NH + h] = m_r[r];
      lp[(size_t)row * NH + h] = o4[r];
    }
  }
}

// --------------------------------------------- merge KV-split partials
__global__ void attn_merge_kernel(const float* __restrict__ opart0,
                                  const float* __restrict__ opart1,
                                  const float* __restrict__ mpart,
                                  const float* __restrict__ lpart,
                                  __hip_bfloat16* __restrict__ attn) {
  int row = blockIdx.x;
  int tid = threadIdx.x;
#pragma unroll
  for (int i = 0; i < 4; ++i) {
    int c = tid + i * 256;
    int h = c >> 6;
    float m0 = mpart[(size_t)row * NH + h];
    float m1 = mpart[(size_t)(S + row) * NH + h];
    float l0 = lpart[(size_t)row * NH + h];
    float l1 = lpart[(size_t)(S + row) * NH + h];
    float M = fmaxf(m0, m1);
    float a0 = __expf(m0 - M), a1 = __expf(m1 - M);
    float l = l0 * a0 + l1 * a1;
    float v = (opart0[(size_t)row * (NH * HD) + c] * a0 +
               opart1[(size_t)row * (NH * HD) + c] * a1) / l;
    attn[(size_t)row * (NH * HD) + c] = __float2bfloat16(v);
  }
}

// ---------------------------------------------------------------- router phase A
// logits + top2 + weights only; NO atomics (they were a 64 us cross-XCD convoy).
__global__ void router_kernel(const float* __restrict__ h2, const float* __restrict__ rw,
                              int* __restrict__ topk_e, float* __restrict__ topk_w) {
  int t = blockIdx.x * 4 + (threadIdx.x >> 6);
  int lane = threadIdx.x & 63;
  float p[NE] = {};
  for (int d = lane; d < D; d += 64) {
    float hv = h2[(size_t)t * D + d];
#pragma unroll
    for (int e = 0; e < NE; ++e) p[e] += hv * rw[d * NE + e];
  }
#pragma unroll
  for (int off = 32; off; off >>= 1)
#pragma unroll
    for (int e = 0; e < NE; ++e) p[e] += __shfl_xor(p[e], off);
  if (lane == 0) {
    float mx = p[0];
#pragma unroll
    for (int e = 1; e < NE; ++e) mx = fmaxf(mx, p[e]);
    float ex[NE];
#pragma unroll
    for (int e = 0; e < NE; ++e) ex[e] = __expf(p[e] - mx);
    int e0 = 0;
#pragma unroll
    for (int e = 1; e < NE; ++e) if (ex[e] > ex[e0]) e0 = e;
    int e1 = (e0 == 0) ? 1 : 0;
#pragma unroll
    for (int e = 0; e < NE; ++e) if (e != e0 && ex[e] > ex[e1]) e1 = e;
    float w0 = ex[e0] / (ex[e0] + ex[e1]);
    float w1 = ex[e1] / (ex[e0] + ex[e1]);
    topk_e[2 * t] = e0;  topk_e[2 * t + 1] = e1;
    topk_w[2 * t] = w0;  topk_w[2 * t + 1] = w1;
  }
}

// ---------------------------------------------------------------- router phase B
// ONE block, 1024 threads. Ballot-aggregated LDS counters -> tok_list/topk_pos;
// absorbs zero_counts + scan. ~64 LDS atomics replace 4096 cross-XCD global RMWs.
__global__ __launch_bounds__(1024) void router_place_kernel(
    const int* __restrict__ topk_e, int* __restrict__ counts, int* __restrict__ offsets,
    int* __restrict__ tok_list, int* __restrict__ topk_pos) {
  __shared__ int lcnt[NE];
  int tid = threadIdx.x;
  int lane = tid & 63;
  if (tid < NE) lcnt[tid] = 0;
  __syncthreads();
#pragma unroll
  for (int r = 0; r < 2; ++r) {
    int t = r * 1024 + tid;
#pragma unroll
    for (int s = 0; s < 2; ++s) {
      int e = topk_e[2 * t + s];
      int pos = 0;
#pragma unroll
      for (int x = 0; x < NE; ++x) {
        unsigned long long mask = __ballot(e == x);
        if (mask) {
          int leader = __ffsll((unsigned long long)mask) - 1;
          int cnt = __popcll(mask);
          int base = 0;
          if (lane == leader) base = atomicAdd(&lcnt[x], cnt);
          base = __shfl(base, leader);
          if (e == x)
            pos = base + __popcll(mask & ((1ull << lane) - 1ull));
        }
      }
      topk_pos[2 * t + s] = pos;
      tok_list[e * S + pos] = t;
    }
  }
  __syncthreads();
  if (tid == 0) {
    int acc = 0;
    for (int e = 0; e < NE; ++e) { offsets[e] = acc; counts[e] = lcnt[e]; acc += lcnt[e]; }
  }
}

// ---------------------------------------------------------------- final add
__global__ void final_kernel(const float* __restrict__ x, const float* __restrict__ sout,
                             const float* __restrict__ eo,
                             const int* __restrict__ topk_e, const int* __restrict__ topk_pos,
                             const float* __restrict__ topk_w, const int* __restrict__ offsets,
                             float* __restrict__ out) {
  int t = blockIdx.x;
  int tid = threadIdx.x;
  int e0 = topk_e[2 * t], e1 = topk_e[2 * t + 1];
  size_t r0 = (size_t)offsets[e0] + topk_pos[2 * t];
  size_t r1 = (size_t)offsets[e1] + topk_pos[2 * t + 1];
  float w0 = topk_w[2 * t], w1 = topk_w[2 * t + 1];
#pragma unroll
  for (int i = 0; i < 4; ++i) {
    int d = tid + i * 256;
    size_t idx = (size_t)t * D + d;
    out[idx] = x[idx] + sout[idx] + w0 * eo[r0 * D + d] + w1 * eo[r1 * D + d];
  }
}

extern "C" void kernel_launch(void* const* d_in, const int* in_sizes, int n_in,
                              void* d_out, int out_size, void* d_ws, size_t ws_size,
                              hipStream_t stream) {
  const float* hidden  = (const float*)d_in[0];
  const float* cosb    = (const float*)d_in[1];
  const float* sinb    = (const float*)d_in[2];
  const float* w_qkv   = (const float*)d_in[3];
  const float* w_o     = (const float*)d_in[4];
  const float* q_norm  = (const float*)d_in[5];
  const float* k_norm  = (const float*)d_in[6];
  const float* in_ln   = (const float*)d_in[7];
  const float* post_ln = (const float*)d_in[8];
  const float* router_w= (const float*)d_in[9];
  const float* w_gate  = (const float*)d_in[10];
  const float* w_up    = (const float*)d_in[11];
  const float* w_down  = (const float*)d_in[12];
  const float* ws_gate = (const float*)d_in[13];
  const float* ws_up   = (const float*)d_in[14];
  const float* ws_down = (const float*)d_in[15];
  float* out = (float*)d_out;
  float* ws = (float*)d_ws;

  typedef __hip_bfloat16 hbf;
  // weights (bf16)
  hbf* wqkvT = (hbf*)(ws);                      // 1.5M el
  hbf* woT   = (hbf*)(ws +  768 * 1024);        // 1M el
  hbf* wgT   = (hbf*)(ws + 1280 * 1024);        // 8M el
  hbf* wuT   = (hbf*)(ws + 5376 * 1024);        // 8M el
  hbf* wdT   = (hbf*)(ws + 9472 * 1024);        // 8M el
  hbf* wsgT  = (hbf*)(ws + 13568 * 1024);       // 1M el
  hbf* wsuT  = (hbf*)(ws + 14080 * 1024);       // 1M el
  hbf* wsdT  = (hbf*)(ws + 14592 * 1024);       // 1M el
  // activations
  hbf*   hb      = (hbf*)(ws + 15104 * 1024);   // [15104K,16128K), dead after qkv GEMM
  float* qkv     = ws + 16128 * 1024;           // [16128K,19200K), dead after v_transpose
  hbf*   qbB     = (hbf*)(ws + 19200 * 1024);   // [19200K,20224K)
  hbf*   kbB     = (hbf*)(ws + 20224 * 1024);   // [20224K,20480K)
  hbf*   vTb     = (hbf*)(ws + 20480 * 1024);   // [20480K,20736K)  V^T [256][2048]
  hbf*   attnb16 = (hbf*)(ws + 20736 * 1024);   // [20736K,21760K)
  float* x       = ws + 22784 * 1024;           // 2M fl (written by wo GEMM, after merge)
  float* h2      = ws + 24832 * 1024;           // 2M fl
  hbf*   h2b     = (hbf*)(ws + 26880 * 1024);   // [26880K,27904K)
  hbf*   act     = (hbf*)(ws + 16128 * 1024);   // 4096x1024 bf16, aliases dead qkv
  float* eo      = ws + 18176 * 1024;           // 4096x1024 fp32, aliases dead q/k/v
  hbf*   sact    = (hbf*)(ws + 27904 * 1024);   // 2048x1024 bf16
  float* sout    = ws + 28928 * 1024;           // 2048x1024 fp32
  // attention partials (live only attn -> merge):
  float* mpart   = ws + 15104 * 1024;           // [2][S][NH]  (aliases dead hb)
  float* lpart   = mpart + 2 * S * NH;
  float* opart0  = ws + 16128 * 1024;           // [S][1024]   (aliases dead qkv)
  float* opart1  = ws + 22784 * 1024;           // [S][1024]   (aliases x, written later)
  int* counts   = (int*)(ws + 30976 * 1024);
  int* offsets  = counts + NE;
  int* tok_list = offsets + NE;
  int* topk_e   = tok_list + NE * S;
  int* topk_pos = topk_e + 2 * S;
  float* topk_w = (float*)(topk_pos + 2 * S);

  dim3 b256(256);
  transpose_cast_kernel<<<dim3(QKV_N/32, D/32, 1), b256, 0, stream>>>(w_qkv, wqkvT, D, QKV_N);
  transpose_cast_kernel<<<dim3(D/32, D/32, 1),     b256, 0, stream>>>(w_o, woT, D, D);
  transpose_cast_kernel<<<dim3(NI/32, D/32, NE),   b256, 0, stream>>>(w_gate, wgT, D, NI);
  transpose_cast_kernel<<<dim3(NI/32, D/32, NE),   b256, 0, stream>>>(w_up, wuT, D, NI);
  transpose_cast_kernel<<<dim3(D/32, NI/32, NE),   b256, 0, stream>>>(w_down, wdT, NI, D);
  transpose_cast_kernel<<<dim3(NI/32, D/32, 1),    b256, 0, stream>>>(ws_gate, wsgT, D, NI);
  transpose_cast_kernel<<<dim3(NI/32, D/32, 1),    b256, 0, stream>>>(ws_up, wsuT, D, NI);
  transpose_cast_kernel<<<dim3(D/32, NI/32, 1),    b256, 0, stream>>>(ws_down, wsdT, NI, D);
  // attention block
  rmsnorm_kernel<<<S, b256, 0, stream>>>(hidden, in_ln, nullptr, hb);
  mgemm_kernel<<<dim3(QKV_N/128, S/128, 1), b256, 0, stream>>>(hb, wqkvT, nullptr, qkv,
      S, QKV_N, D, nullptr, nullptr, nullptr, 0, nullptr, nullptr, nullptr);
  qkv_post_kernel<<<dim3(S, 5), b256, 0, stream>>>(qkv, q_norm, k_norm, cosb, sinb, qbB, kbB, nullptr);
  v_transpose_kernel<<<dim3(S/32, (NKV*HD)/32), b256, 0, stream>>>(qkv, vTb);
  attn_kernel<<<dim3(S/16, NKV, 2), b256, 0, stream>>>(qbB, kbB, vTb,
      opart0, opart1, mpart, lpart);
  attn_merge_kernel<<<S, b256, 0, stream>>>(opart0, opart1, mpart, lpart, attnb16);
  mgemm_kernel<<<dim3(D/128, S/128, 1), b256, 0, stream>>>(attnb16, woT, hidden, x,
      S, D, D, nullptr, nullptr, nullptr, 0, nullptr, nullptr, nullptr);
  // MoE block (shared expert merged as z == NE)
  rmsnorm_kernel<<<S, b256, 0, stream>>>(x, post_ln, h2, h2b);
  router_kernel<<<S/4, b256, 0, stream>>>(h2, router_w, topk_e, topk_w);
  router_place_kernel<<<1, 1024, 0, stream>>>(topk_e, counts, offsets, tok_list, topk_pos);
  mgemm_gu_kernel<<<dim3(NI/64, S/128, NE + 1), b256, 0, stream>>>(h2b, wgT, wuT, act,
      S, NI, D, counts, offsets, tok_list, wsgT, wsuT, sact);
  mgemm_kernel<<<dim3(D/128, S/128, NE + 1), b256, 0, stream>>>(act, wdT, nullptr, eo,
      S, D, NI, counts, offsets, nullptr, 1, sact, wsdT, sout);
  final_kernel<<<S, b256, 0, stream>>>(x, sout, eo, topk_e, topk_pos, topk_w, offsets, out);
}

// Round 7
// 420.522 us; speedup vs baseline: 1.3425x; 1.0533x over previous
//
#include <hip/hip_runtime.h>
#include <hip/hip_bf16.h>
#include <math.h>

#define S 2048
#define D 1024
#define NH 16
#define NKV 4
#define HD 64
#define QKV_N 1536          // (NH + 2*NKV) * HD
#define NE 8
#define NI 1024
#define EPS 1e-6f

typedef __bf16 bf16_t;
typedef __bf16 __attribute__((may_alias)) abf16;
typedef __attribute__((ext_vector_type(8))) __bf16 bf16x8;
typedef __attribute__((ext_vector_type(4))) float f32x4;
union I4B8 { int4 i; bf16x8 v; bf16_t e[8]; };

// async global->LDS, 16B per lane. LDS dest must be wave-uniform base
// (HW adds lane*16); global src is per-lane.
__device__ __forceinline__ void gll16(const void* g, void* l) {
  __builtin_amdgcn_global_load_lds(
      (const __attribute__((address_space(1))) void*)g,
      (__attribute__((address_space(3))) void*)l, 16, 0, 0);
}

// ---------------------------------------------------------------- rmsnorm(D)
__global__ void rmsnorm_kernel(const float* __restrict__ in, const float* __restrict__ w,
                               float* __restrict__ out32, __hip_bfloat16* __restrict__ out16) {
  int t = blockIdx.x;
  int tid = threadIdx.x;
  const float* row = in + (size_t)t * D;
  float v[4];
  float ss = 0.f;
#pragma unroll
  for (int i = 0; i < 4; ++i) {
    v[i] = row[tid + i * 256];
    ss += v[i] * v[i];
  }
#pragma unroll
  for (int off = 32; off; off >>= 1) ss += __shfl_xor(ss, off);
  __shared__ float wsum[4];
  int wave = tid >> 6;
  if ((tid & 63) == 0) wsum[wave] = ss;
  __syncthreads();
  float tot = wsum[0] + wsum[1] + wsum[2] + wsum[3];
  float r = rsqrtf(tot / (float)D + EPS);
#pragma unroll
  for (int i = 0; i < 4; ++i) {
    int d = tid + i * 256;
    float val = v[i] * r * w[d];
    if (out32) out32[(size_t)t * D + d] = val;
    if (out16) out16[(size_t)t * D + d] = __float2bfloat16(val);
  }
}

// ---------------------------- rmsnorm + router logits/top2 fused (MoE pre-pass)
// Deletes the separate router launch and the 16 MB h2 fp32 round-trip.
__global__ void rmsnorm_router_kernel(const float* __restrict__ in, const float* __restrict__ w,
                                      const float* __restrict__ rw,
                                      __hip_bfloat16* __restrict__ out16,
                                      int* __restrict__ topk_e, float* __restrict__ topk_w) {
  int t = blockIdx.x;
  int tid = threadIdx.x;
  const float* row = in + (size_t)t * D;
  float v[4];
  float ss = 0.f;
#pragma unroll
  for (int i = 0; i < 4; ++i) {
    v[i] = row[tid + i * 256];
    ss += v[i] * v[i];
  }
#pragma unroll
  for (int off = 32; off; off >>= 1) ss += __shfl_xor(ss, off);
  __shared__ float wsum[4];
  __shared__ float pl[4][NE];
  int wave = tid >> 6, lane = tid & 63;
  if (lane == 0) wsum[wave] = ss;
  __syncthreads();
  float tot = wsum[0] + wsum[1] + wsum[2] + wsum[3];
  float r = rsqrtf(tot / (float)D + EPS);
  float p[NE] = {};
#pragma unroll
  for (int i = 0; i < 4; ++i) {
    int d = tid + i * 256;
    float val = v[i] * r * w[d];
    out16[(size_t)t * D + d] = __float2bfloat16(val);
    const float* rwd = rw + (size_t)d * NE;
#pragma unroll
    for (int e = 0; e < NE; ++e) p[e] += val * rwd[e];
  }
#pragma unroll
  for (int off = 32; off; off >>= 1)
#pragma unroll
    for (int e = 0; e < NE; ++e) p[e] += __shfl_xor(p[e], off);
  if (lane == 0)
#pragma unroll
    for (int e = 0; e < NE; ++e) pl[wave][e] = p[e];
  __syncthreads();
  if (tid == 0) {
    float q[NE];
#pragma unroll
    for (int e = 0; e < NE; ++e) q[e] = pl[0][e] + pl[1][e] + pl[2][e] + pl[3][e];
    float mx = q[0];
#pragma unroll
    for (int e = 1; e < NE; ++e) mx = fmaxf(mx, q[e]);
    float ex[NE];
#pragma unroll
    for (int e = 0; e < NE; ++e) ex[e] = __expf(q[e] - mx);
    int e0 = 0;
#pragma unroll
    for (int e = 1; e < NE; ++e) if (ex[e] > ex[e0]) e0 = e;
    int e1 = (e0 == 0) ? 1 : 0;
#pragma unroll
    for (int e = 0; e < NE; ++e) if (e != e0 && ex[e] > ex[e1]) e1 = e;
    float w0 = ex[e0] / (ex[e0] + ex[e1]);
    float w1 = ex[e1] / (ex[e0] + ex[e1]);
    topk_e[2 * t] = e0;  topk_e[2 * t + 1] = e1;
    topk_w[2 * t] = w0;  topk_w[2 * t + 1] = w1;
  }
}

// ------------------------------------------- ALL weight transposes in ONE launch
// z: 0=wqkv, 1=wo, 2..9=w_gate[e], 10..17=w_up[e], 18..25=w_down[e],
//    26=ws_gate, 27=ws_up, 28=ws_down. All Kd=1024; Nd in {1024,1536}.
__global__ void transpose_all_kernel(
    const float* __restrict__ w_qkv, const float* __restrict__ w_o,
    const float* __restrict__ w_gate, const float* __restrict__ w_up,
    const float* __restrict__ w_down, const float* __restrict__ ws_gate,
    const float* __restrict__ ws_up, const float* __restrict__ ws_down,
    __hip_bfloat16* wqkvT, __hip_bfloat16* woT, __hip_bfloat16* wgT,
    __hip_bfloat16* wuT, __hip_bfloat16* wdT, __hip_bfloat16* wsgT,
    __hip_bfloat16* wsuT, __hip_bfloat16* wsdT) {
  __shared__ float tile[32][33];
  int z = blockIdx.z;
  const float* W; __hip_bfloat16* WT; int Kd, Nd;
  if (z == 0)       { W = w_qkv;  WT = wqkvT; Kd = D;  Nd = QKV_N; }
  else if (z == 1)  { W = w_o;    WT = woT;   Kd = D;  Nd = D; }
  else if (z < 10)  { int e = z - 2;  W = w_gate + (size_t)e * D * NI; WT = wgT + (size_t)e * D * NI; Kd = D;  Nd = NI; }
  else if (z < 18)  { int e = z - 10; W = w_up   + (size_t)e * D * NI; WT = wuT + (size_t)e * D * NI; Kd = D;  Nd = NI; }
  else if (z < 26)  { int e = z - 18; W = w_down + (size_t)e * NI * D; WT = wdT + (size_t)e * NI * D; Kd = NI; Nd = D; }
  else if (z == 26) { W = ws_gate; WT = wsgT; Kd = D;  Nd = NI; }
  else if (z == 27) { W = ws_up;   WT = wsuT; Kd = D;  Nd = NI; }
  else              { W = ws_down; WT = wsdT; Kd = NI; Nd = D; }
  int n0 = blockIdx.x * 32, k0 = blockIdx.y * 32;
  if (n0 >= Nd || k0 >= Kd) return;
  int tx = threadIdx.x & 31, ty = threadIdx.x >> 5;
#pragma unroll
  for (int i = 0; i < 4; ++i)
    tile[ty + i * 8][tx] = W[(size_t)(k0 + ty + i * 8) * Nd + n0 + tx];
  __syncthreads();
#pragma unroll
  for (int i = 0; i < 4; ++i)
    WT[(size_t)(n0 + ty + i * 8) * Kd + k0 + tx] = __float2bfloat16(tile[tx][ty + i * 8]);
}

// ------------------------------------------- MFMA bf16 GEMM, 128x128 tile
// m97 structure + 2-buffer LDS prefetch (R5-verified: beats 3-deep counted-vmcnt).
__global__ __launch_bounds__(256) void mgemm_kernel(
    const __hip_bfloat16* __restrict__ A, const __hip_bfloat16* __restrict__ BT,
    const float* __restrict__ Cadd, float* __restrict__ C,
    int M, int N, int K,
    const int* __restrict__ counts, const int* __restrict__ offsets,
    const int* __restrict__ tok, int a_comp,
    const __hip_bfloat16* __restrict__ As2, const __hip_bfloat16* __restrict__ BTs2,
    float* __restrict__ Cs2) {
  __shared__ __align__(16) bf16_t Asd[2][128 * 32];   // 2 x 8 KB
  __shared__ __align__(16) bf16_t Bsd[2][128 * 32];
  __shared__ int rowmap[128];
  int e = blockIdx.z;
  bool sh = (counts != nullptr) && (e == NE);
  int cnt = sh ? M : (counts ? counts[e] : M);
  int bm = blockIdx.y * 128;
  if (bm >= cnt) return;
  int bn = blockIdx.x * 128;
  int obase = sh ? 0 : (offsets ? offsets[e] : 0);
  const bf16_t* Ab = sh ? (const bf16_t*)As2 : (const bf16_t*)A;
  const bf16_t* BTe = sh ? (const bf16_t*)BTs2 : ((const bf16_t*)BT + (size_t)e * N * K);
  float* Cp = sh ? Cs2 : C;
  const int* toke = (!sh && tok) ? tok + e * S : nullptr;
  int acompe = sh ? 0 : a_comp;
  int tid = threadIdx.x;
  if (tid < 128) {
    int gp = bm + tid;
    int cp = gp < cnt ? gp : cnt - 1;
    rowmap[tid] = toke ? toke[cp] : (acompe ? obase + cp : cp);
  }
  __syncthreads();
  int wave = tid >> 6, lane = tid & 63;
  int quad = lane >> 4, l16 = lane & 15;
  int wm = wave >> 1, wn = wave & 1;
  int srow = tid >> 2, scol = (tid & 3) * 8;
  size_t aoff0 = (size_t)rowmap[srow] * K + scol;
  size_t aoff1 = (size_t)rowmap[64 + srow] * K + scol;
  size_t boff0 = (size_t)(bn + srow) * K + scol;
  size_t boff1 = (size_t)(bn + 64 + srow) * K + scol;
  f32x4 acc[4][4];
#pragma unroll
  for (int i = 0; i < 4; ++i)
#pragma unroll
    for (int j = 0; j < 4; ++j) acc[i][j] = (f32x4){0.f, 0.f, 0.f, 0.f};

  // prologue: stage k0=0 into buf 0
  {
    char* AsB = (char*)Asd[0] + wave * 1024;
    char* BsB = (char*)Bsd[0] + wave * 1024;
    gll16(Ab + aoff0, AsB);
    gll16(Ab + aoff1, AsB + 4096);
    gll16(BTe + boff0, BsB);
    gll16(BTe + boff1, BsB + 4096);
  }
  for (int k0 = 0; k0 < K; k0 += 32) {
    int cur = (k0 >> 5) & 1;
    __syncthreads();                         // buf[cur] staged; prev reads done
    if (k0 + 32 < K) {                       // prefetch next into buf[cur^1]
      char* AsB = (char*)Asd[cur ^ 1] + wave * 1024;
      char* BsB = (char*)Bsd[cur ^ 1] + wave * 1024;
      gll16(Ab + aoff0 + k0 + 32, AsB);
      gll16(Ab + aoff1 + k0 + 32, AsB + 4096);
      gll16(BTe + boff0 + k0 + 32, BsB);
      gll16(BTe + boff1 + k0 + 32, BsB + 4096);
    }
    I4B8 af[4], bfr[4];
#pragma unroll
    for (int i = 0; i < 4; ++i)
      af[i].i = *(const int4*)(Asd[cur] + (wm * 64 + i * 16 + l16) * 32 + quad * 8);
#pragma unroll
    for (int j = 0; j < 4; ++j)
      bfr[j].i = *(const int4*)(Bsd[cur] + (wn * 64 + j * 16 + l16) * 32 + quad * 8);
#pragma unroll
    for (int i = 0; i < 4; ++i)
#pragma unroll
      for (int j = 0; j < 4; ++j)
        acc[i][j] = __builtin_amdgcn_mfma_f32_16x16x32_bf16(af[i].v, bfr[j].v, acc[i][j], 0, 0, 0);
  }
#pragma unroll
  for (int i = 0; i < 4; ++i) {
#pragma unroll
    for (int r = 0; r < 4; ++r) {
      int trow = wm * 64 + i * 16 + quad * 4 + r;
      int gp = bm + trow;
      if (gp < cnt) {
        size_t rowb = (size_t)(obase + gp) * N;
#pragma unroll
        for (int j = 0; j < 4; ++j) {
          int col = bn + wn * 64 + j * 16 + l16;
          size_t idx = rowb + col;
          Cp[idx] = acc[i][j][r] + (Cadd ? Cadd[idx] : 0.f);
        }
      }
    }
  }
}

// ------------------------------------------- dual-B MFMA GEMM + silu, 128x64 tile
// Same 2-buffer prefetch structure as mgemm_kernel (R5-verified).
__global__ __launch_bounds__(256) void mgemm_gu_kernel(
    const __hip_bfloat16* __restrict__ A, const __hip_bfloat16* __restrict__ BTg,
    const __hip_bfloat16* __restrict__ BTu, __hip_bfloat16* __restrict__ act,
    int M, int N, int K,
    const int* __restrict__ counts, const int* __restrict__ offsets,
    const int* __restrict__ tok,
    const __hip_bfloat16* __restrict__ BTgs, const __hip_bfloat16* __restrict__ BTus,
    __hip_bfloat16* __restrict__ acts) {
  __shared__ __align__(16) bf16_t Asd[2][128 * 32];   // 2 x 8 KB
  __shared__ __align__(16) bf16_t Bgd[2][64 * 32];    // 2 x 4 KB
  __shared__ __align__(16) bf16_t Bud[2][64 * 32];    // 2 x 4 KB
  __shared__ int rowmap[128];
  int e = blockIdx.z;
  bool sh = (counts != nullptr) && (e == NE);
  int cnt = sh ? M : (counts ? counts[e] : M);
  int bm = blockIdx.y * 128;
  if (bm >= cnt) return;
  int bn = blockIdx.x * 64;
  const bf16_t* Ab = (const bf16_t*)A;
  const bf16_t* Bg = sh ? (const bf16_t*)BTgs : ((const bf16_t*)BTg + (size_t)e * N * K);
  const bf16_t* Bu = sh ? (const bf16_t*)BTus : ((const bf16_t*)BTu + (size_t)e * N * K);
  bf16_t* outp = sh ? (bf16_t*)acts : (bf16_t*)act;
  int obase = sh ? 0 : (offsets ? offsets[e] : 0);
  const int* toke = (!sh && tok) ? tok + e * S : nullptr;
  int tid = threadIdx.x;
  if (tid < 128) {
    int gp = bm + tid;
    int cp = gp < cnt ? gp : cnt - 1;
    rowmap[tid] = toke ? toke[cp] : cp;
  }
  __syncthreads();
  int wave = tid >> 6, lane = tid & 63;
  int quad = lane >> 4, l16 = lane & 15;
  int wm = wave >> 1, wn = wave & 1;
  int srow = tid >> 2, scol = (tid & 3) * 8;
  size_t aoff0 = (size_t)rowmap[srow] * K + scol;
  size_t aoff1 = (size_t)rowmap[64 + srow] * K + scol;
  size_t boff = (size_t)(bn + srow) * K + scol;
  f32x4 accg[4][2], accu[4][2];
#pragma unroll
  for (int i = 0; i < 4; ++i)
#pragma unroll
    for (int j = 0; j < 2; ++j) {
      accg[i][j] = (f32x4){0.f, 0.f, 0.f, 0.f};
      accu[i][j] = (f32x4){0.f, 0.f, 0.f, 0.f};
    }
  // prologue
  {
    char* AsB = (char*)Asd[0] + wave * 1024;
    gll16(Ab + aoff0, AsB);
    gll16(Ab + aoff1, AsB + 4096);
    gll16(Bg + boff, (char*)Bgd[0] + wave * 1024);
    gll16(Bu + boff, (char*)Bud[0] + wave * 1024);
  }
  for (int k0 = 0; k0 < K; k0 += 32) {
    int cur = (k0 >> 5) & 1;
    __syncthreads();
    if (k0 + 32 < K) {
      char* AsB = (char*)Asd[cur ^ 1] + wave * 1024;
      gll16(Ab + aoff0 + k0 + 32, AsB);
      gll16(Ab + aoff1 + k0 + 32, AsB + 4096);
      gll16(Bg + boff + k0 + 32, (char*)Bgd[cur ^ 1] + wave * 1024);
      gll16(Bu + boff + k0 + 32, (char*)Bud[cur ^ 1] + wave * 1024);
    }
    I4B8 af[4], bg[2], bu[2];
#pragma unroll
    for (int i = 0; i < 4; ++i)
      af[i].i = *(const int4*)(Asd[cur] + (wm * 64 + i * 16 + l16) * 32 + quad * 8);
#pragma unroll
    for (int j = 0; j < 2; ++j) {
      bg[j].i = *(const int4*)(Bgd[cur] + (wn * 32 + j * 16 + l16) * 32 + quad * 8);
      bu[j].i = *(const int4*)(Bud[cur] + (wn * 32 + j * 16 + l16) * 32 + quad * 8);
    }
#pragma unroll
    for (int i = 0; i < 4; ++i)
#pragma unroll
      for (int j = 0; j < 2; ++j) {
        accg[i][j] = __builtin_amdgcn_mfma_f32_16x16x32_bf16(af[i].v, bg[j].v, accg[i][j], 0, 0, 0);
        accu[i][j] = __builtin_amdgcn_mfma_f32_16x16x32_bf16(af[i].v, bu[j].v, accu[i][j], 0, 0, 0);
      }
  }
#pragma unroll
  for (int i = 0; i < 4; ++i) {
#pragma unroll
    for (int r = 0; r < 4; ++r) {
      int trow = wm * 64 + i * 16 + quad * 4 + r;
      int gp = bm + trow;
      if (gp < cnt) {
        size_t rowb = (size_t)(obase + gp) * N;
#pragma unroll
        for (int j = 0; j < 2; ++j) {
          int col = bn + wn * 32 + j * 16 + l16;
          float g = accg[i][j][r], uu = accu[i][j][r];
          float sg = g / (1.f + __expf(-g));
          outp[rowb + col] = __float2bfloat16(sg * uu);
        }
      }
    }
  }
}

// --------------------------------------------- q/k head rmsnorm + RoPE + bf16 cast
// grid (S, 6): y<5 = q/k heads; y==5 = V transpose tiles (fp32 qkv -> bf16 vT[256][2048]).
__global__ void qkv_post_kernel(const float* __restrict__ qkv,
                                const float* __restrict__ qw, const float* __restrict__ kw,
                                const float* __restrict__ cosb, const float* __restrict__ sinb,
                                __hip_bfloat16* __restrict__ qout,
                                __hip_bfloat16* __restrict__ kout,
                                __hip_bfloat16* __restrict__ vT) {
  __shared__ float tile[32][33];
  if (blockIdx.y == 5) {                     // V transpose: 512 tiles
    int bx = blockIdx.x;
    if (bx < 512) {
      int t0 = (bx & 63) * 32;
      int c0 = (bx >> 6) * 32;
      int tx = threadIdx.x & 31, ty = threadIdx.x >> 5;
#pragma unroll
      for (int i = 0; i < 4; ++i)
        tile[ty + i * 8][tx] = qkv[(size_t)(t0 + ty + i * 8) * QKV_N + (NH + NKV) * HD + c0 + tx];
      __syncthreads();
#pragma unroll
      for (int i = 0; i < 4; ++i)
        vT[(size_t)(c0 + ty + i * 8) * S + t0 + tx] = __float2bfloat16(tile[tx][ty + i * 8]);
    }
    return;
  }
  int t = blockIdx.x;
  int u = blockIdx.y * 4 + (threadIdx.x >> 6);
  int lane = threadIdx.x & 63;
  bool isq = (u < NH);
  int h = isq ? u : (u - NH);
  size_t src = (size_t)t * QKV_N + (isq ? (h * HD) : (NH * HD + h * HD)) + lane;
  float xv = qkv[src];
  float ss = xv * xv;
#pragma unroll
  for (int off = 32; off; off >>= 1) ss += __shfl_xor(ss, off);
  float r = rsqrtf(ss * (1.f / 64.f) + EPS);
  float xn = xv * r * (isq ? qw[lane] : kw[lane]);
  float other = __shfl_xor(xn, 32);
  float rot = (lane < 32) ? -other : other;
  float res = xn * cosb[t * 64 + lane] + rot * sinb[t * 64 + lane];
  if (isq) qout[(size_t)t * (NH * HD) + h * HD + lane] = __float2bfloat16(res * 0.125f);
  else     kout[(size_t)t * (NKV * HD) + h * HD + lane] = __float2bfloat16(res);
}

// --------------------------------------------- MFMA flash attention v4
// GQA-merged + KV-split-2 (flash-decoding). Block = (16-row q-tile, kv head, chunk z).
// 4 waves = 4 q-heads sharing K/V. T14 async staging (regs loaded one tile ahead).
// l accumulated via ones-column MFMA (no sum shuffles). Partials merged by attn_merge.
__global__ __launch_bounds__(256) void attn_kernel(
    const __hip_bfloat16* __restrict__ qg, const __hip_bfloat16* __restrict__ kg,
    const __hip_bfloat16* __restrict__ vT,
    float* __restrict__ opart0, float* __restrict__ opart1,
    float* __restrict__ mpart, float* __restrict__ lpart) {
  int qt = (int)(gridDim.x - 1) - (int)blockIdx.x;   // heavy tiles first
  int kvh = blockIdx.y;
  int z = blockIdx.z;
  int tid = threadIdx.x;
  int wave = tid >> 6, lane = tid & 63;
  int quad = lane >> 4, l16 = lane & 15;
  int h = kvh * 4 + wave;

  float* opz = z ? opart1 : opart0;
  float* mp = mpart + (size_t)z * S * NH;
  float* lp = lpart + (size_t)z * S * NH;

  int nb = (qt >> 1) + 1;            // valid 32-blocks of kv
  int nt = (nb + 1) >> 1;            // 64-wide tiles
  bool halfm = (nb & 1) != 0;        // last tile only 32 valid
  int h0 = nt >> 1;
  int lo = z ? h0 : 0;
  int hi = z ? nt : h0;

  if (lo >= hi) {                    // empty chunk: zero partials
    int row = qt * 16 + (tid >> 4);
    float* od = opz + (size_t)row * (NH * HD) + kvh * 256 + (tid & 15) * 16;
    int4 zz = {0, 0, 0, 0};
#pragma unroll
    for (int i = 0; i < 4; ++i) *(int4*)(od + i * 4) = zz;
    if (tid < 64) {
      int rr = qt * 16 + (tid >> 2), hh = kvh * 4 + (tid & 3);
      mp[(size_t)rr * NH + hh] = -1e30f;
      lp[(size_t)rr * NH + hh] = 0.f;
    }
    return;
  }

  __shared__ __align__(16) int KsI[64 * 36];         // K tile [64 k][64 d + pad]
  __shared__ __align__(16) int VTI[64 * 36];         // V^T tile [64 d][64 k + pad]
  __shared__ __align__(16) int PsI[4][16 * 36];      // per-wave P [16 q][64 k + pad]

  I4B8 qf[2];
#pragma unroll
  for (int ch = 0; ch < 2; ++ch)
    qf[ch].i = *(const int4*)((const abf16*)qg +
        (size_t)(qt * 16 + l16) * (NH * HD) + h * HD + ch * 32 + quad * 8);

  I4B8 ones;
  ones.i = (int4){0x3F803F80, 0x3F803F80, 0x3F803F80, 0x3F803F80};   // 8x bf16 1.0

  float m_r[4];
  f32x4 o[4], o4;
#pragma unroll
  for (int r = 0; r < 4; ++r) m_r[r] = -1e30f;
#pragma unroll
  for (int sub = 0; sub < 4; ++sub) o[sub] = (f32x4){0.f, 0.f, 0.f, 0.f};
  o4 = (f32x4){0.f, 0.f, 0.f, 0.f};

  int sp = tid >> 3, sc = tid & 7;   // staging: 32 rows x 8 octets (x2 halves)
  const abf16* kb = (const abf16*)kg;
  const abf16* vb = (const abf16*)vT;

  // T14 prologue: load first tile into regs
  int4 rk0 = *(const int4*)(kb + (size_t)(lo * 64 + sp) * (NKV * HD) + kvh * HD + sc * 8);
  int4 rk1 = *(const int4*)(kb + (size_t)(lo * 64 + 32 + sp) * (NKV * HD) + kvh * HD + sc * 8);
  int4 rv0 = *(const int4*)(vb + (size_t)(kvh * HD + sp) * S + lo * 64 + sc * 8);
  int4 rv1 = *(const int4*)(vb + (size_t)(kvh * HD + 32 + sp) * S + lo * 64 + sc * 8);

  for (int kc = lo; kc < hi; ++kc) {
    // ---- write staged regs to LDS (prev compute done via loop-bottom barrier)
    *(int4*)&KsI[sp * 36 + sc * 4] = rk0;
    *(int4*)&KsI[(sp + 32) * 36 + sc * 4] = rk1;
    *(int4*)&VTI[sp * 36 + sc * 4] = rv0;
    *(int4*)&VTI[(sp + 32) * 36 + sc * 4] = rv1;
    __syncthreads();

    // ---- issue next tile loads (latency hides under compute below)
    if (kc + 1 < hi) {
      rk0 = *(const int4*)(kb + (size_t)((kc + 1) * 64 + sp) * (NKV * HD) + kvh * HD + sc * 8);
      rk1 = *(const int4*)(kb + (size_t)((kc + 1) * 64 + 32 + sp) * (NKV * HD) + kvh * HD + sc * 8);
      rv0 = *(const int4*)(vb + (size_t)(kvh * HD + sp) * S + (kc + 1) * 64 + sc * 8);
      rv1 = *(const int4*)(vb + (size_t)(kvh * HD + 32 + sp) * S + (kc + 1) * 64 + sc * 8);
    }

    // ---- QK^T: 16 q-rows x 64 k
    f32x4 s[4];
#pragma unroll
    for (int sub = 0; sub < 4; ++sub) s[sub] = (f32x4){0.f, 0.f, 0.f, 0.f};
    __builtin_amdgcn_s_setprio(1);
#pragma unroll
    for (int sub = 0; sub < 4; ++sub)
#pragma unroll
      for (int ch = 0; ch < 2; ++ch) {
        I4B8 ku;
        ku.i = *(const int4*)&KsI[(sub * 16 + l16) * 36 + ch * 16 + quad * 4];
        s[sub] = __builtin_amdgcn_mfma_f32_16x16x32_bf16(qf[ch].v, ku.v, s[sub], 0, 0, 0);
      }
    __builtin_amdgcn_s_setprio(0);
    if (halfm && kc == nt - 1) {
#pragma unroll
      for (int r = 0; r < 4; ++r) { s[2][r] = -1e30f; s[3][r] = -1e30f; }
    }

    // ---- online softmax: max-reduce + exp; sums come from ones-MFMA
    abf16* pw = (abf16*)PsI[wave];
#pragma unroll
    for (int r = 0; r < 4; ++r) {
      float v = fmaxf(fmaxf(s[0][r], s[1][r]), fmaxf(s[2][r], s[3][r]));
#pragma unroll
      for (int off = 1; off < 16; off <<= 1) v = fmaxf(v, __shfl_xor(v, off));
      float mx = fmaxf(m_r[r], v);
      float al = __expf(m_r[r] - mx);
      m_r[r] = mx;
      float p0 = __expf(s[0][r] - mx);
      float p1 = __expf(s[1][r] - mx);
      float p2 = __expf(s[2][r] - mx);
      float p3 = __expf(s[3][r] - mx);
      int prow = quad * 4 + r;
      pw[prow * 72 + l16]      = (bf16_t)p0;
      pw[prow * 72 + 16 + l16] = (bf16_t)p1;
      pw[prow * 72 + 32 + l16] = (bf16_t)p2;
      pw[prow * 72 + 48 + l16] = (bf16_t)p3;
      o4[r] *= al;
#pragma unroll
      for (int sub = 0; sub < 4; ++sub) o[sub][r] *= al;
    }

    // ---- PV: P(16x64) x V(64x64) + ones-column for row sums
    I4B8 pu[2];
#pragma unroll
    for (int ch = 0; ch < 2; ++ch)
      pu[ch].i = *(const int4*)&PsI[wave][l16 * 36 + ch * 16 + quad * 4];
    __builtin_amdgcn_s_setprio(1);
#pragma unroll
    for (int sub = 0; sub < 4; ++sub)
#pragma unroll
      for (int ch = 0; ch < 2; ++ch) {
        I4B8 vf;
        vf.i = *(const int4*)&VTI[(sub * 16 + l16) * 36 + ch * 16 + quad * 4];
        o[sub] = __builtin_amdgcn_mfma_f32_16x16x32_bf16(pu[ch].v, vf.v, o[sub], 0, 0, 0);
      }
#pragma unroll
    for (int ch = 0; ch < 2; ++ch)
      o4 = __builtin_amdgcn_mfma_f32_16x16x32_bf16(pu[ch].v, ones.v, o4, 0, 0, 0);
    __builtin_amdgcn_s_setprio(0);
    __syncthreads();
  }

  // epilogue: write raw partials (normalize at merge)
#pragma unroll
  for (int r = 0; r < 4; ++r) {
    int row = qt * 16 + quad * 4 + r;
    float* od = opz + (size_t)row * (NH * HD) + h * HD;
#pragma unroll
    for (int sub = 0; sub < 4; ++sub)
      od[sub * 16 + l16] = o[sub][r];
    if (l16 == 0) {
      mp[(size_t)row * NH + h] = m_r[r];
      lp[(size_t)row * NH + h] = o4[r];
    }
  }
}

// --------------------------------------------- merge KV-split partials
__global__ void attn_merge_kernel(const float* __restrict__ opart0,
                                  const float* __restrict__ opart1,
                                  const float* __restrict__ mpart,
                                  const float* __restrict__ lpart,
                                  __hip_bfloat16* __restrict__ attn) {
  int row = blockIdx.x;
  int tid = threadIdx.x;
#pragma unroll
  for (int i = 0; i < 4; ++i) {
    int c = tid + i * 256;
    int h = c >> 6;
    float m0 = mpart[(size_t)row * NH + h];
    float m1 = mpart[(size_t)(S + row) * NH + h];
    float l0 = lpart[(size_t)row * NH + h];
    float l1 = lpart[(size_t)(S + row) * NH + h];
    float M = fmaxf(m0, m1);
    float a0 = __expf(m0 - M), a1 = __expf(m1 - M);
    float l = l0 * a0 + l1 * a1;
    float v = (opart0[(size_t)row * (NH * HD) + c] * a0 +
               opart1[(size_t)row * (NH * HD) + c] * a1) / l;
    attn[(size_t)row * (NH * HD) + c] = __float2bfloat16(v);
  }
}

// ---------------------------------------------------------------- router phase B
// ONE block, 1024 threads. Ballot-aggregated LDS counters -> tok_list/topk_pos.
__global__ __launch_bounds__(1024) void router_place_kernel(
    const int* __restrict__ topk_e, int* __restrict__ counts, int* __restrict__ offsets,
    int* __restrict__ tok_list, int* __restrict__ topk_pos) {
  __shared__ int lcnt[NE];
  int tid = threadIdx.x;
  int lane = tid & 63;
  if (tid < NE) lcnt[tid] = 0;
  __syncthreads();
#pragma unroll
  for (int r = 0; r < 2; ++r) {
    int t = r * 1024 + tid;
#pragma unroll
    for (int s = 0; s < 2; ++s) {
      int e = topk_e[2 * t + s];
      int pos = 0;
#pragma unroll
      for (int x = 0; x < NE; ++x) {
        unsigned long long mask = __ballot(e == x);
        if (mask) {
          int leader = __ffsll((unsigned long long)mask) - 1;
          int cnt = __popcll(mask);
          int base = 0;
          if (lane == leader) base = atomicAdd(&lcnt[x], cnt);
          base = __shfl(base, leader);
          if (e == x)
            pos = base + __popcll(mask & ((1ull << lane) - 1ull));
        }
      }
      topk_pos[2 * t + s] = pos;
      tok_list[e * S + pos] = t;
    }
  }
  __syncthreads();
  if (tid == 0) {
    int acc = 0;
    for (int e = 0; e < NE; ++e) { offsets[e] = acc; counts[e] = lcnt[e]; acc += lcnt[e]; }
  }
}

// ---------------------------------------------------------------- final add
__global__ void final_kernel(const float* __restrict__ x, const float* __restrict__ sout,
                             const float* __restrict__ eo,
                             const int* __restrict__ topk_e, const int* __restrict__ topk_pos,
                             const float* __restrict__ topk_w, const int* __restrict__ offsets,
                             float* __restrict__ out) {
  int t = blockIdx.x;
  int tid = threadIdx.x;
  int e0 = topk_e[2 * t], e1 = topk_e[2 * t + 1];
  size_t r0 = (size_t)offsets[e0] + topk_pos[2 * t];
  size_t r1 = (size_t)offsets[e1] + topk_pos[2 * t + 1];
  float w0 = topk_w[2 * t], w1 = topk_w[2 * t + 1];
#pragma unroll
  for (int i = 0; i < 4; ++i) {
    int d = tid + i * 256;
    size_t idx = (size_t)t * D + d;
    out[idx] = x[idx] + sout[idx] + w0 * eo[r0 * D + d] + w1 * eo[r1 * D + d];
  }
}

extern "C" void kernel_launch(void* const* d_in, const int* in_sizes, int n_in,
                              void* d_out, int out_size, void* d_ws, size_t ws_size,
                              hipStream_t stream) {
  const float* hidden  = (const float*)d_in[0];
  const float* cosb    = (const float*)d_in[1];
  const float* sinb    = (const float*)d_in[2];
  const float* w_qkv   = (const float*)d_in[3];
  const float* w_o     = (const float*)d_in[4];
  const float* q_norm  = (const float*)d_in[5];
  const float* k_norm  = (const float*)d_in[6];
  const float* in_ln   = (const float*)d_in[7];
  const float* post_ln = (const float*)d_in[8];
  const float* router_w= (const float*)d_in[9];
  const float* w_gate  = (const float*)d_in[10];
  const float* w_up    = (const float*)d_in[11];
  const float* w_down  = (const float*)d_in[12];
  const float* ws_gate = (const float*)d_in[13];
  const float* ws_up   = (const float*)d_in[14];
  const float* ws_down = (const float*)d_in[15];
  float* out = (float*)d_out;
  float* ws = (float*)d_ws;

  typedef __hip_bfloat16 hbf;
  // weights (bf16)
  hbf* wqkvT = (hbf*)(ws);                      // 1.5M el
  hbf* woT   = (hbf*)(ws +  768 * 1024);        // 1M el
  hbf* wgT   = (hbf*)(ws + 1280 * 1024);        // 8M el
  hbf* wuT   = (hbf*)(ws + 5376 * 1024);        // 8M el
  hbf* wdT   = (hbf*)(ws + 9472 * 1024);        // 8M el
  hbf* wsgT  = (hbf*)(ws + 13568 * 1024);       // 1M el
  hbf* wsuT  = (hbf*)(ws + 14080 * 1024);       // 1M el
  hbf* wsdT  = (hbf*)(ws + 14592 * 1024);       // 1M el
  // activations
  hbf*   hb      = (hbf*)(ws + 15104 * 1024);   // [15104K,16128K), dead after qkv GEMM
  float* qkv     = ws + 16128 * 1024;           // [16128K,19200K), dead after qkv_post
  hbf*   qbB     = (hbf*)(ws + 19200 * 1024);   // [19200K,20224K)
  hbf*   kbB     = (hbf*)(ws + 20224 * 1024);   // [20224K,20480K)
  hbf*   vTb     = (hbf*)(ws + 20480 * 1024);   // [20480K,20736K)  V^T [256][2048]
  hbf*   attnb16 = (hbf*)(ws + 20736 * 1024);   // [20736K,21760K)
  float* x       = ws + 22784 * 1024;           // 2M fl (written by wo GEMM, after merge)
  hbf*   h2b     = (hbf*)(ws + 26880 * 1024);   // [26880K,27904K)
  hbf*   act     = (hbf*)(ws + 16128 * 1024);   // 4096x1024 bf16, aliases dead qkv
  float* eo      = ws + 18176 * 1024;           // 4096x1024 fp32, aliases dead q/k/v
  hbf*   sact    = (hbf*)(ws + 27904 * 1024);   // 2048x1024 bf16
  float* sout    = ws + 28928 * 1024;           // 2048x1024 fp32
  // attention partials (live only attn -> merge):
  float* mpart   = ws + 15104 * 1024;           // [2][S][NH]  (aliases dead hb)
  float* lpart   = mpart + 2 * S * NH;
  float* opart0  = ws + 16128 * 1024;           // [S][1024]   (aliases dead qkv)
  float* opart1  = ws + 22784 * 1024;           // [S][1024]   (aliases x, written later)
  int* counts   = (int*)(ws + 30976 * 1024);
  int* offsets  = counts + NE;
  int* tok_list = offsets + NE;
  int* topk_e   = tok_list + NE * S;
  int* topk_pos = topk_e + 2 * S;
  float* topk_w = (float*)(topk_pos + 2 * S);

  dim3 b256(256);
  transpose_all_kernel<<<dim3(48, 32, 29), b256, 0, stream>>>(
      w_qkv, w_o, w_gate, w_up, w_down, ws_gate, ws_up, ws_down,
      wqkvT, woT, wgT, wuT, wdT, wsgT, wsuT, wsdT);
  // attention block
  rmsnorm_kernel<<<S, b256, 0, stream>>>(hidden, in_ln, nullptr, hb);
  mgemm_kernel<<<dim3(QKV_N/128, S/128, 1), b256, 0, stream>>>(hb, wqkvT, nullptr, qkv,
      S, QKV_N, D, nullptr, nullptr, nullptr, 0, nullptr, nullptr, nullptr);
  qkv_post_kernel<<<dim3(S, 6), b256, 0, stream>>>(qkv, q_norm, k_norm, cosb, sinb, qbB, kbB, vTb);
  attn_kernel<<<dim3(S/16, NKV, 2), b256, 0, stream>>>(qbB, kbB, vTb,
      opart0, opart1, mpart, lpart);
  attn_merge_kernel<<<S, b256, 0, stream>>>(opart0, opart1, mpart, lpart, attnb16);
  mgemm_kernel<<<dim3(D/128, S/128, 1), b256, 0, stream>>>(attnb16, woT, hidden, x,
      S, D, D, nullptr, nullptr, nullptr, 0, nullptr, nullptr, nullptr);
  // MoE block (shared expert merged as z == NE)
  rmsnorm_router_kernel<<<S, b256, 0, stream>>>(x, post_ln, router_w, h2b, topk_e, topk_w);
  router_place_kernel<<<1, 1024, 0, stream>>>(topk_e, counts, offsets, tok_list, topk_pos);
  mgemm_gu_kernel<<<dim3(NI/64, S/128, NE + 1), b256, 0, stream>>>(h2b, wgT, wuT, act,
      S, NI, D, counts, offsets, tok_list, wsgT, wsuT, sact);
  mgemm_kernel<<<dim3(D/128, S/128, NE + 1), b256, 0, stream>>>(act, wdT, nullptr, eo,
      S, D, NI, counts, offsets, nullptr, 1, sact, wsdT, sout);
  final_kernel<<<S, b256, 0, stream>>>(x, sout, eo, topk_e, topk_pos, topk_w, offsets, out);
}

// Round 8
// 419.206 us; speedup vs baseline: 1.3467x; 1.0031x over previous
//
#include <hip/hip_runtime.h>
#include <hip/hip_bf16.h>
#include <math.h>

#define S 2048
#define D 1024
#define NH 16
#define NKV 4
#define HD 64
#define QKV_N 1536          // (NH + 2*NKV) * HD
#define NE 8
#define NI 1024
#define EPS 1e-6f

typedef __bf16 bf16_t;
typedef __bf16 __attribute__((may_alias)) abf16;
typedef __attribute__((ext_vector_type(8))) __bf16 bf16x8;
typedef __attribute__((ext_vector_type(4))) float f32x4;
union I4B8 { int4 i; bf16x8 v; bf16_t e[8]; };

// async global->LDS, 16B per lane. LDS dest must be wave-uniform base
// (HW adds lane*16); global src is per-lane.
__device__ __forceinline__ void gll16(const void* g, void* l) {
  __builtin_amdgcn_global_load_lds(
      (const __attribute__((address_space(1))) void*)g,
      (__attribute__((address_space(3))) void*)l, 16, 0, 0);
}

// ---------------------------------------------------------------- rmsnorm(D)
__global__ void rmsnorm_kernel(const float* __restrict__ in, const float* __restrict__ w,
                               float* __restrict__ out32, __hip_bfloat16* __restrict__ out16) {
  int t = blockIdx.x;
  int tid = threadIdx.x;
  const float* row = in + (size_t)t * D;
  float v[4];
  float ss = 0.f;
#pragma unroll
  for (int i = 0; i < 4; ++i) {
    v[i] = row[tid + i * 256];
    ss += v[i] * v[i];
  }
#pragma unroll
  for (int off = 32; off; off >>= 1) ss += __shfl_xor(ss, off);
  __shared__ float wsum[4];
  int wave = tid >> 6;
  if ((tid & 63) == 0) wsum[wave] = ss;
  __syncthreads();
  float tot = wsum[0] + wsum[1] + wsum[2] + wsum[3];
  float r = rsqrtf(tot / (float)D + EPS);
#pragma unroll
  for (int i = 0; i < 4; ++i) {
    int d = tid + i * 256;
    float val = v[i] * r * w[d];
    if (out32) out32[(size_t)t * D + d] = val;
    if (out16) out16[(size_t)t * D + d] = __float2bfloat16(val);
  }
}

// ---------------------------- rmsnorm + router logits/top2 fused (MoE pre-pass)
__global__ void rmsnorm_router_kernel(const float* __restrict__ in, const float* __restrict__ w,
                                      const float* __restrict__ rw,
                                      __hip_bfloat16* __restrict__ out16,
                                      int* __restrict__ topk_e, float* __restrict__ topk_w) {
  int t = blockIdx.x;
  int tid = threadIdx.x;
  const float* row = in + (size_t)t * D;
  float v[4];
  float ss = 0.f;
#pragma unroll
  for (int i = 0; i < 4; ++i) {
    v[i] = row[tid + i * 256];
    ss += v[i] * v[i];
  }
#pragma unroll
  for (int off = 32; off; off >>= 1) ss += __shfl_xor(ss, off);
  __shared__ float wsum[4];
  __shared__ float pl[4][NE];
  int wave = tid >> 6, lane = tid & 63;
  if (lane == 0) wsum[wave] = ss;
  __syncthreads();
  float tot = wsum[0] + wsum[1] + wsum[2] + wsum[3];
  float r = rsqrtf(tot / (float)D + EPS);
  float p[NE] = {};
#pragma unroll
  for (int i = 0; i < 4; ++i) {
    int d = tid + i * 256;
    float val = v[i] * r * w[d];
    out16[(size_t)t * D + d] = __float2bfloat16(val);
    const float* rwd = rw + (size_t)d * NE;
#pragma unroll
    for (int e = 0; e < NE; ++e) p[e] += val * rwd[e];
  }
#pragma unroll
  for (int off = 32; off; off >>= 1)
#pragma unroll
    for (int e = 0; e < NE; ++e) p[e] += __shfl_xor(p[e], off);
  if (lane == 0)
#pragma unroll
    for (int e = 0; e < NE; ++e) pl[wave][e] = p[e];
  __syncthreads();
  if (tid == 0) {
    float q[NE];
#pragma unroll
    for (int e = 0; e < NE; ++e) q[e] = pl[0][e] + pl[1][e] + pl[2][e] + pl[3][e];
    float mx = q[0];
#pragma unroll
    for (int e = 1; e < NE; ++e) mx = fmaxf(mx, q[e]);
    float ex[NE];
#pragma unroll
    for (int e = 0; e < NE; ++e) ex[e] = __expf(q[e] - mx);
    int e0 = 0;
#pragma unroll
    for (int e = 1; e < NE; ++e) if (ex[e] > ex[e0]) e0 = e;
    int e1 = (e0 == 0) ? 1 : 0;
#pragma unroll
    for (int e = 0; e < NE; ++e) if (e != e0 && ex[e] > ex[e1]) e1 = e;
    float w0 = ex[e0] / (ex[e0] + ex[e1]);
    float w1 = ex[e1] / (ex[e0] + ex[e1]);
    topk_e[2 * t] = e0;  topk_e[2 * t + 1] = e1;
    topk_w[2 * t] = w0;  topk_w[2 * t + 1] = w1;
  }
}

// ------------------------------------------- ALL weight transposes in ONE launch
// 64x64 tiles, vectorized: float4 reads (16B/lane), dwordx4 writes (32B/thread).
// z: 0=wqkv, 1=wo, 2..9=w_gate[e], 10..17=w_up[e], 18..25=w_down[e],
//    26=ws_gate, 27=ws_up, 28=ws_down.
__global__ void transpose_all_kernel(
    const float* __restrict__ w_qkv, const float* __restrict__ w_o,
    const float* __restrict__ w_gate, const float* __restrict__ w_up,
    const float* __restrict__ w_down, const float* __restrict__ ws_gate,
    const float* __restrict__ ws_up, const float* __restrict__ ws_down,
    __hip_bfloat16* wqkvT, __hip_bfloat16* woT, __hip_bfloat16* wgT,
    __hip_bfloat16* wuT, __hip_bfloat16* wdT, __hip_bfloat16* wsgT,
    __hip_bfloat16* wsuT, __hip_bfloat16* wsdT) {
  __shared__ __align__(16) bf16_t tile[64][72];   // 9.2 KB, [k][n]
  int z = blockIdx.z;
  const float* W; __hip_bfloat16* WT; int Kd, Nd;
  if (z == 0)       { W = w_qkv;  WT = wqkvT; Kd = D;  Nd = QKV_N; }
  else if (z == 1)  { W = w_o;    WT = woT;   Kd = D;  Nd = D; }
  else if (z < 10)  { int e = z - 2;  W = w_gate + (size_t)e * D * NI; WT = wgT + (size_t)e * D * NI; Kd = D;  Nd = NI; }
  else if (z < 18)  { int e = z - 10; W = w_up   + (size_t)e * D * NI; WT = wuT + (size_t)e * D * NI; Kd = D;  Nd = NI; }
  else if (z < 26)  { int e = z - 18; W = w_down + (size_t)e * NI * D; WT = wdT + (size_t)e * NI * D; Kd = NI; Nd = D; }
  else if (z == 26) { W = ws_gate; WT = wsgT; Kd = D;  Nd = NI; }
  else if (z == 27) { W = ws_up;   WT = wsuT; Kd = D;  Nd = NI; }
  else              { W = ws_down; WT = wsdT; Kd = NI; Nd = D; }
  int n0 = blockIdx.x * 64, k0 = blockIdx.y * 64;
  if (n0 >= Nd || k0 >= Kd) return;
  int tid = threadIdx.x;
  int rk = tid >> 4;                 // 0..15
  int rc = (tid & 15) * 4;           // 0..60 step 4
#pragma unroll
  for (int it = 0; it < 4; ++it) {
    int k = it * 16 + rk;
    float4 v = *(const float4*)(W + (size_t)(k0 + k) * Nd + n0 + rc);
    union { bf16_t e[4]; int2 q; } pk4;
    pk4.e[0] = (bf16_t)v.x; pk4.e[1] = (bf16_t)v.y;
    pk4.e[2] = (bf16_t)v.z; pk4.e[3] = (bf16_t)v.w;
    *(int2*)&tile[k][rc] = pk4.q;
  }
  __syncthreads();
  int n = tid >> 2;                  // 0..63
  int kc = (tid & 3) * 16;           // 0,16,32,48
  union { bf16_t e[16]; int4 q[2]; } pk;
#pragma unroll
  for (int j = 0; j < 16; ++j) pk.e[j] = tile[kc + j][n];
  int4* outp = (int4*)(WT + (size_t)(n0 + n) * Kd + k0 + kc);
  outp[0] = pk.q[0];
  outp[1] = pk.q[1];
}

// ------------------------------------------- MFMA bf16 GEMM, 128x128 tile
// m97 structure + 2-buffer LDS prefetch (R5-verified: beats 3-deep counted-vmcnt).
__global__ __launch_bounds__(256) void mgemm_kernel(
    const __hip_bfloat16* __restrict__ A, const __hip_bfloat16* __restrict__ BT,
    const float* __restrict__ Cadd, float* __restrict__ C,
    int M, int N, int K,
    const int* __restrict__ counts, const int* __restrict__ offsets,
    const int* __restrict__ tok, int a_comp,
    const __hip_bfloat16* __restrict__ As2, const __hip_bfloat16* __restrict__ BTs2,
    float* __restrict__ Cs2) {
  __shared__ __align__(16) bf16_t Asd[2][128 * 32];   // 2 x 8 KB
  __shared__ __align__(16) bf16_t Bsd[2][128 * 32];
  __shared__ int rowmap[128];
  int e = blockIdx.z;
  bool sh = (counts != nullptr) && (e == NE);
  int cnt = sh ? M : (counts ? counts[e] : M);
  int bm = blockIdx.y * 128;
  if (bm >= cnt) return;
  int bn = blockIdx.x * 128;
  int obase = sh ? 0 : (offsets ? offsets[e] : 0);
  const bf16_t* Ab = sh ? (const bf16_t*)As2 : (const bf16_t*)A;
  const bf16_t* BTe = sh ? (const bf16_t*)BTs2 : ((const bf16_t*)BT + (size_t)e * N * K);
  float* Cp = sh ? Cs2 : C;
  const int* toke = (!sh && tok) ? tok + e * S : nullptr;
  int acompe = sh ? 0 : a_comp;
  int tid = threadIdx.x;
  if (tid < 128) {
    int gp = bm + tid;
    int cp = gp < cnt ? gp : cnt - 1;
    rowmap[tid] = toke ? toke[cp] : (acompe ? obase + cp : cp);
  }
  __syncthreads();
  int wave = tid >> 6, lane = tid & 63;
  int quad = lane >> 4, l16 = lane & 15;
  int wm = wave >> 1, wn = wave & 1;
  int srow = tid >> 2, scol = (tid & 3) * 8;
  size_t aoff0 = (size_t)rowmap[srow] * K + scol;
  size_t aoff1 = (size_t)rowmap[64 + srow] * K + scol;
  size_t boff0 = (size_t)(bn + srow) * K + scol;
  size_t boff1 = (size_t)(bn + 64 + srow) * K + scol;
  f32x4 acc[4][4];
#pragma unroll
  for (int i = 0; i < 4; ++i)
#pragma unroll
    for (int j = 0; j < 4; ++j) acc[i][j] = (f32x4){0.f, 0.f, 0.f, 0.f};

  // prologue: stage k0=0 into buf 0
  {
    char* AsB = (char*)Asd[0] + wave * 1024;
    char* BsB = (char*)Bsd[0] + wave * 1024;
    gll16(Ab + aoff0, AsB);
    gll16(Ab + aoff1, AsB + 4096);
    gll16(BTe + boff0, BsB);
    gll16(BTe + boff1, BsB + 4096);
  }
  for (int k0 = 0; k0 < K; k0 += 32) {
    int cur = (k0 >> 5) & 1;
    __syncthreads();                         // buf[cur] staged; prev reads done
    if (k0 + 32 < K) {                       // prefetch next into buf[cur^1]
      char* AsB = (char*)Asd[cur ^ 1] + wave * 1024;
      char* BsB = (char*)Bsd[cur ^ 1] + wave * 1024;
      gll16(Ab + aoff0 + k0 + 32, AsB);
      gll16(Ab + aoff1 + k0 + 32, AsB + 4096);
      gll16(BTe + boff0 + k0 + 32, BsB);
      gll16(BTe + boff1 + k0 + 32, BsB + 4096);
    }
    I4B8 af[4], bfr[4];
#pragma unroll
    for (int i = 0; i < 4; ++i)
      af[i].i = *(const int4*)(Asd[cur] + (wm * 64 + i * 16 + l16) * 32 + quad * 8);
#pragma unroll
    for (int j = 0; j < 4; ++j)
      bfr[j].i = *(const int4*)(Bsd[cur] + (wn * 64 + j * 16 + l16) * 32 + quad * 8);
#pragma unroll
    for (int i = 0; i < 4; ++i)
#pragma unroll
      for (int j = 0; j < 4; ++j)
        acc[i][j] = __builtin_amdgcn_mfma_f32_16x16x32_bf16(af[i].v, bfr[j].v, acc[i][j], 0, 0, 0);
  }
#pragma unroll
  for (int i = 0; i < 4; ++i) {
#pragma unroll
    for (int r = 0; r < 4; ++r) {
      int trow = wm * 64 + i * 16 + quad * 4 + r;
      int gp = bm + trow;
      if (gp < cnt) {
        size_t rowb = (size_t)(obase + gp) * N;
#pragma unroll
        for (int j = 0; j < 4; ++j) {
          int col = bn + wn * 64 + j * 16 + l16;
          size_t idx = rowb + col;
          Cp[idx] = acc[i][j][r] + (Cadd ? Cadd[idx] : 0.f);
        }
      }
    }
  }
}

// ------------------------------------------- dual-B MFMA GEMM + silu, 128x64 tile
// Same 2-buffer prefetch structure as mgemm_kernel (R5-verified).
__global__ __launch_bounds__(256) void mgemm_gu_kernel(
    const __hip_bfloat16* __restrict__ A, const __hip_bfloat16* __restrict__ BTg,
    const __hip_bfloat16* __restrict__ BTu, __hip_bfloat16* __restrict__ act,
    int M, int N, int K,
    const int* __restrict__ counts, const int* __restrict__ offsets,
    const int* __restrict__ tok,
    const __hip_bfloat16* __restrict__ BTgs, const __hip_bfloat16* __restrict__ BTus,
    __hip_bfloat16* __restrict__ acts) {
  __shared__ __align__(16) bf16_t Asd[2][128 * 32];   // 2 x 8 KB
  __shared__ __align__(16) bf16_t Bgd[2][64 * 32];    // 2 x 4 KB
  __shared__ __align__(16) bf16_t Bud[2][64 * 32];    // 2 x 4 KB
  __shared__ int rowmap[128];
  int e = blockIdx.z;
  bool sh = (counts != nullptr) && (e == NE);
  int cnt = sh ? M : (counts ? counts[e] : M);
  int bm = blockIdx.y * 128;
  if (bm >= cnt) return;
  int bn = blockIdx.x * 64;
  const bf16_t* Ab = (const bf16_t*)A;
  const bf16_t* Bg = sh ? (const bf16_t*)BTgs : ((const bf16_t*)BTg + (size_t)e * N * K);
  const bf16_t* Bu = sh ? (const bf16_t*)BTus : ((const bf16_t*)BTu + (size_t)e * N * K);
  bf16_t* outp = sh ? (bf16_t*)acts : (bf16_t*)act;
  int obase = sh ? 0 : (offsets ? offsets[e] : 0);
  const int* toke = (!sh && tok) ? tok + e * S : nullptr;
  int tid = threadIdx.x;
  if (tid < 128) {
    int gp = bm + tid;
    int cp = gp < cnt ? gp : cnt - 1;
    rowmap[tid] = toke ? toke[cp] : cp;
  }
  __syncthreads();
  int wave = tid >> 6, lane = tid & 63;
  int quad = lane >> 4, l16 = lane & 15;
  int wm = wave >> 1, wn = wave & 1;
  int srow = tid >> 2, scol = (tid & 3) * 8;
  size_t aoff0 = (size_t)rowmap[srow] * K + scol;
  size_t aoff1 = (size_t)rowmap[64 + srow] * K + scol;
  size_t boff = (size_t)(bn + srow) * K + scol;
  f32x4 accg[4][2], accu[4][2];
#pragma unroll
  for (int i = 0; i < 4; ++i)
#pragma unroll
    for (int j = 0; j < 2; ++j) {
      accg[i][j] = (f32x4){0.f, 0.f, 0.f, 0.f};
      accu[i][j] = (f32x4){0.f, 0.f, 0.f, 0.f};
    }
  // prologue
  {
    char* AsB = (char*)Asd[0] + wave * 1024;
    gll16(Ab + aoff0, AsB);
    gll16(Ab + aoff1, AsB + 4096);
    gll16(Bg + boff, (char*)Bgd[0] + wave * 1024);
    gll16(Bu + boff, (char*)Bud[0] + wave * 1024);
  }
  for (int k0 = 0; k0 < K; k0 += 32) {
    int cur = (k0 >> 5) & 1;
    __syncthreads();
    if (k0 + 32 < K) {
      char* AsB = (char*)Asd[cur ^ 1] + wave * 1024;
      gll16(Ab + aoff0 + k0 + 32, AsB);
      gll16(Ab + aoff1 + k0 + 32, AsB + 4096);
      gll16(Bg + boff + k0 + 32, (char*)Bgd[cur ^ 1] + wave * 1024);
      gll16(Bu + boff + k0 + 32, (char*)Bud[cur ^ 1] + wave * 1024);
    }
    I4B8 af[4], bg[2], bu[2];
#pragma unroll
    for (int i = 0; i < 4; ++i)
      af[i].i = *(const int4*)(Asd[cur] + (wm * 64 + i * 16 + l16) * 32 + quad * 8);
#pragma unroll
    for (int j = 0; j < 2; ++j) {
      bg[j].i = *(const int4*)(Bgd[cur] + (wn * 32 + j * 16 + l16) * 32 + quad * 8);
      bu[j].i = *(const int4*)(Bud[cur] + (wn * 32 + j * 16 + l16) * 32 + quad * 8);
    }
#pragma unroll
    for (int i = 0; i < 4; ++i)
#pragma unroll
      for (int j = 0; j < 2; ++j) {
        accg[i][j] = __builtin_amdgcn_mfma_f32_16x16x32_bf16(af[i].v, bg[j].v, accg[i][j], 0, 0, 0);
        accu[i][j] = __builtin_amdgcn_mfma_f32_16x16x32_bf16(af[i].v, bu[j].v, accu[i][j], 0, 0, 0);
      }
  }
#pragma unroll
  for (int i = 0; i < 4; ++i) {
#pragma unroll
    for (int r = 0; r < 4; ++r) {
      int trow = wm * 64 + i * 16 + quad * 4 + r;
      int gp = bm + trow;
      if (gp < cnt) {
        size_t rowb = (size_t)(obase + gp) * N;
#pragma unroll
        for (int j = 0; j < 2; ++j) {
          int col = bn + wn * 32 + j * 16 + l16;
          float g = accg[i][j][r], uu = accu[i][j][r];
          float sg = g / (1.f + __expf(-g));
          outp[rowb + col] = __float2bfloat16(sg * uu);
        }
      }
    }
  }
}

// --------------------------------------------- q/k head rmsnorm + RoPE + bf16 cast
// grid (S, 6): y<5 = q/k heads; y==5 = V transpose tiles (fp32 qkv -> bf16 vT[256][2048]).
__global__ void qkv_post_kernel(const float* __restrict__ qkv,
                                const float* __restrict__ qw, const float* __restrict__ kw,
                                const float* __restrict__ cosb, const float* __restrict__ sinb,
                                __hip_bfloat16* __restrict__ qout,
                                __hip_bfloat16* __restrict__ kout,
                                __hip_bfloat16* __restrict__ vT) {
  __shared__ float tile[32][33];
  if (blockIdx.y == 5) {                     // V transpose: 512 tiles
    int bx = blockIdx.x;
    if (bx < 512) {
      int t0 = (bx & 63) * 32;
      int c0 = (bx >> 6) * 32;
      int tx = threadIdx.x & 31, ty = threadIdx.x >> 5;
#pragma unroll
      for (int i = 0; i < 4; ++i)
        tile[ty + i * 8][tx] = qkv[(size_t)(t0 + ty + i * 8) * QKV_N + (NH + NKV) * HD + c0 + tx];
      __syncthreads();
#pragma unroll
      for (int i = 0; i < 4; ++i)
        vT[(size_t)(c0 + ty + i * 8) * S + t0 + tx] = __float2bfloat16(tile[tx][ty + i * 8]);
    }
    return;
  }
  int t = blockIdx.x;
  int u = blockIdx.y * 4 + (threadIdx.x >> 6);
  int lane = threadIdx.x & 63;
  bool isq = (u < NH);
  int h = isq ? u : (u - NH);
  size_t src = (size_t)t * QKV_N + (isq ? (h * HD) : (NH * HD + h * HD)) + lane;
  float xv = qkv[src];
  float ss = xv * xv;
#pragma unroll
  for (int off = 32; off; off >>= 1) ss += __shfl_xor(ss, off);
  float r = rsqrtf(ss * (1.f / 64.f) + EPS);
  float xn = xv * r * (isq ? qw[lane] : kw[lane]);
  float other = __shfl_xor(xn, 32);
  float rot = (lane < 32) ? -other : other;
  float res = xn * cosb[t * 64 + lane] + rot * sinb[t * 64 + lane];
  if (isq) qout[(size_t)t * (NH * HD) + h * HD + lane] = __float2bfloat16(res * 0.125f);
  else     kout[(size_t)t * (NKV * HD) + h * HD + lane] = __float2bfloat16(res);
}

// --------------------------------------------- MFMA flash attention v4
// GQA-merged + KV-split-2 (flash-decoding). Block = (16-row q-tile, kv head, chunk z).
// 4 waves = 4 q-heads sharing K/V. T14 async staging (regs loaded one tile ahead).
// l accumulated via ones-column MFMA (no sum shuffles). Partials merged by attn_merge.
__global__ __launch_bounds__(256) void attn_kernel(
    const __hip_bfloat16* __restrict__ qg, const __hip_bfloat16* __restrict__ kg,
    const __hip_bfloat16* __restrict__ vT,
    float* __restrict__ opart0, float* __restrict__ opart1,
    float* __restrict__ mpart, float* __restrict__ lpart) {
  int qt = (int)(gridDim.x - 1) - (int)blockIdx.x;   // heavy tiles first
  int kvh = blockIdx.y;
  int z = blockIdx.z;
  int tid = threadIdx.x;
  int wave = tid >> 6, lane = tid & 63;
  int quad = lane >> 4, l16 = lane & 15;
  int h = kvh * 4 + wave;

  float* opz = z ? opart1 : opart0;
  float* mp = mpart + (size_t)z * S * NH;
  float* lp = lpart + (size_t)z * S * NH;

  int nb = (qt >> 1) + 1;            // valid 32-blocks of kv
  int nt = (nb + 1) >> 1;            // 64-wide tiles
  bool halfm = (nb & 1) != 0;        // last tile only 32 valid
  int h0 = nt >> 1;
  int lo = z ? h0 : 0;
  int hi = z ? nt : h0;

  if (lo >= hi) {                    // empty chunk: zero partials
    int row = qt * 16 + (tid >> 4);
    float* od = opz + (size_t)row * (NH * HD) + kvh * 256 + (tid & 15) * 16;
    int4 zz = {0, 0, 0, 0};
#pragma unroll
    for (int i = 0; i < 4; ++i) *(int4*)(od + i * 4) = zz;
    if (tid < 64) {
      int rr = qt * 16 + (tid >> 2), hh = kvh * 4 + (tid & 3);
      mp[(size_t)rr * NH + hh] = -1e30f;
      lp[(size_t)rr * NH + hh] = 0.f;
    }
    return;
  }

  __shared__ __align__(16) int KsI[64 * 36];         // K tile [64 k][64 d + pad]
  __shared__ __align__(16) int VTI[64 * 36];         // V^T tile [64 d][64 k + pad]
  __shared__ __align__(16) int PsI[4][16 * 36];      // per-wave P [16 q][64 k + pad]

  I4B8 qf[2];
#pragma unroll
  for (int ch = 0; ch < 2; ++ch)
    qf[ch].i = *(const int4*)((const abf16*)qg +
        (size_t)(qt * 16 + l16) * (NH * HD) + h * HD + ch * 32 + quad * 8);

  I4B8 ones;
  ones.i = (int4){0x3F803F80, 0x3F803F80, 0x3F803F80, 0x3F803F80};   // 8x bf16 1.0

  float m_r[4];
  f32x4 o[4], o4;
#pragma unroll
  for (int r = 0; r < 4; ++r) m_r[r] = -1e30f;
#pragma unroll
  for (int sub = 0; sub < 4; ++sub) o[sub] = (f32x4){0.f, 0.f, 0.f, 0.f};
  o4 = (f32x4){0.f, 0.f, 0.f, 0.f};

  int sp = tid >> 3, sc = tid & 7;   // staging: 32 rows x 8 octets (x2 halves)
  const abf16* kb = (const abf16*)kg;
  const abf16* vb = (const abf16*)vT;

  // T14 prologue: load first tile into regs
  int4 rk0 = *(const int4*)(kb + (size_t)(lo * 64 + sp) * (NKV * HD) + kvh * HD + sc * 8);
  int4 rk1 = *(const int4*)(kb + (size_t)(lo * 64 + 32 + sp) * (NKV * HD) + kvh * HD + sc * 8);
  int4 rv0 = *(const int4*)(vb + (size_t)(kvh * HD + sp) * S + lo * 64 + sc * 8);
  int4 rv1 = *(const int4*)(vb + (size_t)(kvh * HD + 32 + sp) * S + lo * 64 + sc * 8);

  for (int kc = lo; kc < hi; ++kc) {
    // ---- write staged regs to LDS (prev compute done via loop-bottom barrier)
    *(int4*)&KsI[sp * 36 + sc * 4] = rk0;
    *(int4*)&KsI[(sp + 32) * 36 + sc * 4] = rk1;
    *(int4*)&VTI[sp * 36 + sc * 4] = rv0;
    *(int4*)&VTI[(sp + 32) * 36 + sc * 4] = rv1;
    __syncthreads();

    // ---- issue next tile loads (latency hides under compute below)
    if (kc + 1 < hi) {
      rk0 = *(const int4*)(kb + (size_t)((kc + 1) * 64 + sp) * (NKV * HD) + kvh * HD + sc * 8);
      rk1 = *(const int4*)(kb + (size_t)((kc + 1) * 64 + 32 + sp) * (NKV * HD) + kvh * HD + sc * 8);
      rv0 = *(const int4*)(vb + (size_t)(kvh * HD + sp) * S + (kc + 1) * 64 + sc * 8);
      rv1 = *(const int4*)(vb + (size_t)(kvh * HD + 32 + sp) * S + (kc + 1) * 64 + sc * 8);
    }

    // ---- QK^T: 16 q-rows x 64 k
    f32x4 s[4];
#pragma unroll
    for (int sub = 0; sub < 4; ++sub) s[sub] = (f32x4){0.f, 0.f, 0.f, 0.f};
    __builtin_amdgcn_s_setprio(1);
#pragma unroll
    for (int sub = 0; sub < 4; ++sub)
#pragma unroll
      for (int ch = 0; ch < 2; ++ch) {
        I4B8 ku;
        ku.i = *(const int4*)&KsI[(sub * 16 + l16) * 36 + ch * 16 + quad * 4];
        s[sub] = __builtin_amdgcn_mfma_f32_16x16x32_bf16(qf[ch].v, ku.v, s[sub], 0, 0, 0);
      }
    __builtin_amdgcn_s_setprio(0);
    if (halfm && kc == nt - 1) {
#pragma unroll
      for (int r = 0; r < 4; ++r) { s[2][r] = -1e30f; s[3][r] = -1e30f; }
    }

    // ---- online softmax: max-reduce + exp; sums come from ones-MFMA
    abf16* pw = (abf16*)PsI[wave];
#pragma unroll
    for (int r = 0; r < 4; ++r) {
      float v = fmaxf(fmaxf(s[0][r], s[1][r]), fmaxf(s[2][r], s[3][r]));
#pragma unroll
      for (int off = 1; off < 16; off <<= 1) v = fmaxf(v, __shfl_xor(v, off));
      float mx = fmaxf(m_r[r], v);
      float al = __expf(m_r[r] - mx);
      m_r[r] = mx;
      float p0 = __expf(s[0][r] - mx);
      float p1 = __expf(s[1][r] - mx);
      float p2 = __expf(s[2][r] - mx);
      float p3 = __expf(s[3][r] - mx);
      int prow = quad * 4 + r;
      pw[prow * 72 + l16]      = (bf16_t)p0;
      pw[prow * 72 + 16 + l16] = (bf16_t)p1;
      pw[prow * 72 + 32 + l16] = (bf16_t)p2;
      pw[prow * 72 + 48 + l16] = (bf16_t)p3;
      o4[r] *= al;
#pragma unroll
      for (int sub = 0; sub < 4; ++sub) o[sub][r] *= al;
    }

    // ---- PV: P(16x64) x V(64x64) + ones-column for row sums
    I4B8 pu[2];
#pragma unroll
    for (int ch = 0; ch < 2; ++ch)
      pu[ch].i = *(const int4*)&PsI[wave][l16 * 36 + ch * 16 + quad * 4];
    __builtin_amdgcn_s_setprio(1);
#pragma unroll
    for (int sub = 0; sub < 4; ++sub)
#pragma unroll
      for (int ch = 0; ch < 2; ++ch) {
        I4B8 vf;
        vf.i = *(const int4*)&VTI[(sub * 16 + l16) * 36 + ch * 16 + quad * 4];
        o[sub] = __builtin_amdgcn_mfma_f32_16x16x32_bf16(pu[ch].v, vf.v, o[sub], 0, 0, 0);
      }
#pragma unroll
    for (int ch = 0; ch < 2; ++ch)
      o4 = __builtin_amdgcn_mfma_f32_16x16x32_bf16(pu[ch].v, ones.v, o4, 0, 0, 0);
    __builtin_amdgcn_s_setprio(0);
    __syncthreads();
  }

  // epilogue: write raw partials (normalize at merge)
#pragma unroll
  for (int r = 0; r < 4; ++r) {
    int row = qt * 16 + quad * 4 + r;
    float* od = opz + (size_t)row * (NH * HD) + h * HD;
#pragma unroll
    for (int sub = 0; sub < 4; ++sub)
      od[sub * 16 + l16] = o[sub][r];
    if (l16 == 0) {
      mp[(size_t)row * NH + h] = m_r[r];
      lp[(size_t)row * NH + h] = o4[r];
    }
  }
}

// --------------------------------------------- merge KV-split partials
__global__ void attn_merge_kernel(const float* __restrict__ opart0,
                                  const float* __restrict__ opart1,
                                  const float* __restrict__ mpart,
                                  const float* __restrict__ lpart,
                                  __hip_bfloat16* __restrict__ attn) {
  int row = blockIdx.x;
  int tid = threadIdx.x;
#pragma unroll
  for (int i = 0; i < 4; ++i) {
    int c = tid + i * 256;
    int h = c >> 6;
    float m0 = mpart[(size_t)row * NH + h];
    float m1 = mpart[(size_t)(S + row) * NH + h];
    float l0 = lpart[(size_t)row * NH + h];
    float l1 = lpart[(size_t)(S + row) * NH + h];
    float M = fmaxf(m0, m1);
    float a0 = __expf(m0 - M), a1 = __expf(m1 - M);
    float l = l0 * a0 + l1 * a1;
    float v = (opart0[(size_t)row * (NH * HD) + c] * a0 +
               opart1[(size_t)row * (NH * HD) + c] * a1) / l;
    attn[(size_t)row * (NH * HD) + c] = __float2bfloat16(v);
  }
}

// ---------------------------------------------------------------- router phase B
// ONE block, 1024 threads. Ballot-aggregated LDS counters -> tok_list/topk_pos.
__global__ __launch_bounds__(1024) void router_place_kernel(
    const int* __restrict__ topk_e, int* __restrict__ counts, int* __restrict__ offsets,
    int* __restrict__ tok_list, int* __restrict__ topk_pos) {
  __shared__ int lcnt[NE];
  int tid = threadIdx.x;
  int lane = tid & 63;
  if (tid < NE) lcnt[tid] = 0;
  __syncthreads();
#pragma unroll
  for (int r = 0; r < 2; ++r) {
    int t = r * 1024 + tid;
#pragma unroll
    for (int s = 0; s < 2; ++s) {
      int e = topk_e[2 * t + s];
      int pos = 0;
#pragma unroll
      for (int x = 0; x < NE; ++x) {
        unsigned long long mask = __ballot(e == x);
        if (mask) {
          int leader = __ffsll((unsigned long long)mask) - 1;
          int cnt = __popcll(mask);
          int base = 0;
          if (lane == leader) base = atomicAdd(&lcnt[x], cnt);
          base = __shfl(base, leader);
          if (e == x)
            pos = base + __popcll(mask & ((1ull << lane) - 1ull));
        }
      }
      topk_pos[2 * t + s] = pos;
      tok_list[e * S + pos] = t;
    }
  }
  __syncthreads();
  if (tid == 0) {
    int acc = 0;
    for (int e = 0; e < NE; ++e) { offsets[e] = acc; counts[e] = lcnt[e]; acc += lcnt[e]; }
  }
}

// ---------------------------------------------------------------- final add
__global__ void final_kernel(const float* __restrict__ x, const float* __restrict__ sout,
                             const float* __restrict__ eo,
                             const int* __restrict__ topk_e, const int* __restrict__ topk_pos,
                             const float* __restrict__ topk_w, const int* __restrict__ offsets,
                             float* __restrict__ out) {
  int t = blockIdx.x;
  int tid = threadIdx.x;
  int e0 = topk_e[2 * t], e1 = topk_e[2 * t + 1];
  size_t r0 = (size_t)offsets[e0] + topk_pos[2 * t];
  size_t r1 = (size_t)offsets[e1] + topk_pos[2 * t + 1];
  float w0 = topk_w[2 * t], w1 = topk_w[2 * t + 1];
#pragma unroll
  for (int i = 0; i < 4; ++i) {
    int d = tid + i * 256;
    size_t idx = (size_t)t * D + d;
    out[idx] = x[idx] + sout[idx] + w0 * eo[r0 * D + d] + w1 * eo[r1 * D + d];
  }
}

extern "C" void kernel_launch(void* const* d_in, const int* in_sizes, int n_in,
                              void* d_out, int out_size, void* d_ws, size_t ws_size,
                              hipStream_t stream) {
  const float* hidden  = (const float*)d_in[0];
  const float* cosb    = (const float*)d_in[1];
  const float* sinb    = (const float*)d_in[2];
  const float* w_qkv   = (const float*)d_in[3];
  const float* w_o     = (const float*)d_in[4];
  const float* q_norm  = (const float*)d_in[5];
  const float* k_norm  = (const float*)d_in[6];
  const float* in_ln   = (const float*)d_in[7];
  const float* post_ln = (const float*)d_in[8];
  const float* router_w= (const float*)d_in[9];
  const float* w_gate  = (const float*)d_in[10];
  const float* w_up    = (const float*)d_in[11];
  const float* w_down  = (const float*)d_in[12];
  const float* ws_gate = (const float*)d_in[13];
  const float* ws_up   = (const float*)d_in[14];
  const float* ws_down = (const float*)d_in[15];
  float* out = (float*)d_out;
  float* ws = (float*)d_ws;

  typedef __hip_bfloat16 hbf;
  // weights (bf16)
  hbf* wqkvT = (hbf*)(ws);                      // 1.5M el
  hbf* woT   = (hbf*)(ws +  768 * 1024);        // 1M el
  hbf* wgT   = (hbf*)(ws + 1280 * 1024);        // 8M el
  hbf* wuT   = (hbf*)(ws + 5376 * 1024);        // 8M el
  hbf* wdT   = (hbf*)(ws + 9472 * 1024);        // 8M el
  hbf* wsgT  = (hbf*)(ws + 13568 * 1024);       // 1M el
  hbf* wsuT  = (hbf*)(ws + 14080 * 1024);       // 1M el
  hbf* wsdT  = (hbf*)(ws + 14592 * 1024);       // 1M el
  // activations
  hbf*   hb      = (hbf*)(ws + 15104 * 1024);   // [15104K,16128K), dead after qkv GEMM
  float* qkv     = ws + 16128 * 1024;           // [16128K,19200K), dead after qkv_post
  hbf*   qbB     = (hbf*)(ws + 19200 * 1024);   // [19200K,20224K)
  hbf*   kbB     = (hbf*)(ws + 20224 * 1024);   // [20224K,20480K)
  hbf*   vTb     = (hbf*)(ws + 20480 * 1024);   // [20480K,20736K)  V^T [256][2048]
  hbf*   attnb16 = (hbf*)(ws + 20736 * 1024);   // [20736K,21760K)
  float* x       = ws + 22784 * 1024;           // 2M fl (written by wo GEMM, after merge)
  hbf*   h2b     = (hbf*)(ws + 26880 * 1024);   // [26880K,27904K)
  hbf*   act     = (hbf*)(ws + 16128 * 1024);   // 4096x1024 bf16, aliases dead qkv
  float* eo      = ws + 18176 * 1024;           // 4096x1024 fp32, aliases dead q/k/v
  hbf*   sact    = (hbf*)(ws + 27904 * 1024);   // 2048x1024 bf16
  float* sout    = ws + 28928 * 1024;           // 2048x1024 fp32
  // attention partials (live only attn -> merge):
  float* mpart   = ws + 15104 * 1024;           // [2][S][NH]  (aliases dead hb)
  float* lpart   = mpart + 2 * S * NH;
  float* opart0  = ws + 16128 * 1024;           // [S][1024]   (aliases dead qkv)
  float* opart1  = ws + 22784 * 1024;           // [S][1024]   (aliases x, written later)
  int* counts   = (int*)(ws + 30976 * 1024);
  int* offsets  = counts + NE;
  int* tok_list = offsets + NE;
  int* topk_e   = tok_list + NE * S;
  int* topk_pos = topk_e + 2 * S;
  float* topk_w = (float*)(topk_pos + 2 * S);

  dim3 b256(256);
  transpose_all_kernel<<<dim3(24, 16, 29), b256, 0, stream>>>(
      w_qkv, w_o, w_gate, w_up, w_down, ws_gate, ws_up, ws_down,
      wqkvT, woT, wgT, wuT, wdT, wsgT, wsuT, wsdT);
  // attention block
  rmsnorm_kernel<<<S, b256, 0, stream>>>(hidden, in_ln, nullptr, hb);
  mgemm_kernel<<<dim3(QKV_N/128, S/128, 1), b256, 0, stream>>>(hb, wqkvT, nullptr, qkv,
      S, QKV_N, D, nullptr, nullptr, nullptr, 0, nullptr, nullptr, nullptr);
  qkv_post_kernel<<<dim3(S, 6), b256, 0, stream>>>(qkv, q_norm, k_norm, cosb, sinb, qbB, kbB, vTb);
  attn_kernel<<<dim3(S/16, NKV, 2), b256, 0, stream>>>(qbB, kbB, vTb,
      opart0, opart1, mpart, lpart);
  attn_merge_kernel<<<S, b256, 0, stream>>>(opart0, opart1, mpart, lpart, attnb16);
  mgemm_kernel<<<dim3(D/128, S/128, 1), b256, 0, stream>>>(attnb16, woT, hidden, x,
      S, D, D, nullptr, nullptr, nullptr, 0, nullptr, nullptr, nullptr);
  // MoE block (shared expert merged as z == NE)
  rmsnorm_router_kernel<<<S, b256, 0, stream>>>(x, post_ln, router_w, h2b, topk_e, topk_w);
  router_place_kernel<<<1, 1024, 0, stream>>>(topk_e, counts, offsets, tok_list, topk_pos);
  mgemm_gu_kernel<<<dim3(NI/64, S/128, NE + 1), b256, 0, stream>>>(h2b, wgT, wuT, act,
      S, NI, D, counts, offsets, tok_list, wsgT, wsuT, sact);
  mgemm_kernel<<<dim3(D/128, S/128, NE + 1), b256, 0, stream>>>(act, wdT, nullptr, eo,
      S, D, NI, counts, offsets, nullptr, 1, sact, wsdT, sout);
  final_kernel<<<S, b256, 0, stream>>>(x, sout, eo, topk_e, topk_pos, topk_w, offsets, out);
}